// Round 6
// baseline (3925.890 us; speedup 1.0000x reference)
//
#include <hip/hip_runtime.h>

// Problem constants
#define NB   1024
#define NN   65536
#define NF   64
#define ND   512
#define NDB  1024
#define NC   96

// Chunking
#define CH_A 8192      // candidate-encode chunk rows
#define BB_C 256       // scores/topk chunk of B rows
#define BB_D 128       // values-path chunk of B rows

// top-k segmentation
#define TK_SPLIT 16
#define TK_SEG   (NN / TK_SPLIT)   // 4096
#define TK_CAND  (TK_SPLIT * NC)   // 1536

typedef unsigned short ushort;
typedef __attribute__((ext_vector_type(8))) short short8;
typedef __attribute__((ext_vector_type(4))) float floatx4;

__device__ __forceinline__ ushort f2bf(float f) {   // RNE f32->bf16
    unsigned u = __float_as_uint(f);
    u += 0x7fffu + ((u >> 16) & 1u);
    return (ushort)(u >> 16);
}
__device__ __forceinline__ float bf2f(ushort h) {
    return __uint_as_float(((unsigned)h) << 16);
}
// LDS plane: [m][k] bf16, k-stride 32, 16B-chunk XOR swizzle -> conflict-free
__device__ __forceinline__ int lds_off(int m, int c) {
    return m * 32 + (((c + (m >> 1)) & 3) << 3);
}

// ---------------------------------------------------------------------------
// Split-plane MFMA GEMM (f32-emulating, 3 MFMA), NT:
//   acc = A @ B^T  with A=(Ah,Al)[M][K], B=(Bh,Bl)[N][K] bf16 planes.
// Epilogue (runtime flags):
//   scoresq != 0 : Sf[o] = scoresq[n] - 2*acc            (scores mode)
//   else         : v = acc + bias (+res planes) (relu?) -> split -> Ch/Cl
// ---------------------------------------------------------------------------
__global__ __launch_bounds__(256) void gemm_ss(
    const ushort* __restrict__ Ah_g, const ushort* __restrict__ Al_g,
    const ushort* __restrict__ Bh_g, const ushort* __restrict__ Bl_g,
    const float* __restrict__ bias,
    const ushort* __restrict__ resh, const ushort* __restrict__ resl,
    const float* __restrict__ scoresq, float* __restrict__ Sf,
    ushort* __restrict__ Ch, ushort* __restrict__ Cl,
    int M, int N, int K, int relu)
{
    __shared__ ushort Ah[128 * 32], Al[128 * 32];
    __shared__ ushort Bh[128 * 32], Bl[128 * 32];
    const int tid = threadIdx.x;
    const int lane = tid & 63, wid = tid >> 6;
    const int wm = (wid & 1) * 64, wn = (wid >> 1) * 64;
    const int lane15 = lane & 15, quad = lane >> 4;
    const int row0 = blockIdx.y * 128, col0 = blockIdx.x * 128;
    const int sm = tid >> 1, scp = (tid & 1) * 2;

    const ushort* arh = Ah_g + (size_t)(row0 + sm) * K + scp * 8;
    const ushort* arl = Al_g + (size_t)(row0 + sm) * K + scp * 8;
    const ushort* brh = Bh_g + (size_t)(col0 + sm) * K + scp * 8;
    const ushort* brl = Bl_g + (size_t)(col0 + sm) * K + scp * 8;

    floatx4 acc[4][4];
#pragma unroll
    for (int i = 0; i < 4; i++)
#pragma unroll
        for (int j = 0; j < 4; j++) acc[i][j] = (floatx4){0.f, 0.f, 0.f, 0.f};

    for (int k0 = 0; k0 < K; k0 += 32) {
        short8 a0 = *(const short8*)(arh + k0);
        short8 a1 = *(const short8*)(arh + k0 + 8);
        short8 a2 = *(const short8*)(arl + k0);
        short8 a3 = *(const short8*)(arl + k0 + 8);
        short8 b0 = *(const short8*)(brh + k0);
        short8 b1 = *(const short8*)(brh + k0 + 8);
        short8 b2 = *(const short8*)(brl + k0);
        short8 b3 = *(const short8*)(brl + k0 + 8);
        __syncthreads();
        *(short8*)(Ah + lds_off(sm, scp))     = a0;
        *(short8*)(Ah + lds_off(sm, scp + 1)) = a1;
        *(short8*)(Al + lds_off(sm, scp))     = a2;
        *(short8*)(Al + lds_off(sm, scp + 1)) = a3;
        *(short8*)(Bh + lds_off(sm, scp))     = b0;
        *(short8*)(Bh + lds_off(sm, scp + 1)) = b1;
        *(short8*)(Bl + lds_off(sm, scp))     = b2;
        *(short8*)(Bl + lds_off(sm, scp + 1)) = b3;
        __syncthreads();

        short8 ah[4], al[4], bh[4], bl[4];
#pragma unroll
        for (int t = 0; t < 4; t++) {
            const int am = wm + t * 16 + lane15;
            const int bn = wn + t * 16 + lane15;
            ah[t] = *(const short8*)(Ah + lds_off(am, quad));
            al[t] = *(const short8*)(Al + lds_off(am, quad));
            bh[t] = *(const short8*)(Bh + lds_off(bn, quad));
            bl[t] = *(const short8*)(Bl + lds_off(bn, quad));
        }
#pragma unroll
        for (int i = 0; i < 4; i++)
#pragma unroll
            for (int j = 0; j < 4; j++) {
                acc[i][j] = __builtin_amdgcn_mfma_f32_16x16x32_bf16(ah[i], bh[j], acc[i][j], 0, 0, 0);
                acc[i][j] = __builtin_amdgcn_mfma_f32_16x16x32_bf16(ah[i], bl[j], acc[i][j], 0, 0, 0);
                acc[i][j] = __builtin_amdgcn_mfma_f32_16x16x32_bf16(al[i], bh[j], acc[i][j], 0, 0, 0);
            }
    }

    // C/D layout: col=lane&15, row=quad*4+reg  [m89]
#pragma unroll
    for (int i = 0; i < 4; i++)
#pragma unroll
        for (int j = 0; j < 4; j++) {
            const int gc = col0 + wn + j * 16 + lane15;
            const int rb = row0 + wm + i * 16 + quad * 4;
            const float bv = bias ? bias[gc] : 0.f;
            const float sv = scoresq ? scoresq[gc] : 0.f;
#pragma unroll
            for (int r = 0; r < 4; r++) {
                const size_t o = (size_t)(rb + r) * N + gc;
                float v = acc[i][j][r];
                if (scoresq) {
                    Sf[o] = sv - 2.f * v;
                } else {
                    v += bv;
                    if (resh) v += bf2f(resh[o]) + bf2f(resl[o]);
                    if (relu) v = fmaxf(v, 0.f);
                    ushort h = f2bf(v);
                    Ch[o] = h;
                    Cl[o] = f2bf(v - bf2f(h));
                }
            }
        }
}

// ---------------------------------------------------------------------------
// Split-bf16 GEMM with f32 operands (x-path / predictor; small M)
// ---------------------------------------------------------------------------
__device__ __forceinline__ void load16(const float* p, float* x) {
    *(float4*)(x)      = *(const float4*)(p);
    *(float4*)(x + 4)  = *(const float4*)(p + 4);
    *(float4*)(x + 8)  = *(const float4*)(p + 8);
    *(float4*)(x + 12) = *(const float4*)(p + 12);
}
__device__ __forceinline__ void write_split(const float* x, ushort* Ph,
                                            ushort* Pl, int m, int cp) {
    short8 h0, h1, l0, l1;
#pragma unroll
    for (int i = 0; i < 8; i++) {
        ushort h = f2bf(x[i]);
        h0[i] = (short)h;
        l0[i] = (short)f2bf(x[i] - bf2f(h));
        ushort g = f2bf(x[i + 8]);
        h1[i] = (short)g;
        l1[i] = (short)f2bf(x[i + 8] - bf2f(g));
    }
    *(short8*)(Ph + lds_off(m, cp))     = h0;
    *(short8*)(Ph + lds_off(m, cp + 1)) = h1;
    *(short8*)(Pl + lds_off(m, cp))     = l0;
    *(short8*)(Pl + lds_off(m, cp + 1)) = l1;
}

__global__ __launch_bounds__(256) void gemm_split_nt(
    const float* __restrict__ A, const float* __restrict__ BT,
    const float* __restrict__ bias, const float* res,
    float* C, int M, int N, int K, int relu)
{
    __shared__ ushort Ah[128 * 32], Al[128 * 32];
    __shared__ ushort Bh[128 * 32], Bl[128 * 32];
    const int tid = threadIdx.x;
    const int lane = tid & 63, wid = tid >> 6;
    const int wm = (wid & 1) * 64, wn = (wid >> 1) * 64;
    const int lane15 = lane & 15, quad = lane >> 4;
    const int row0 = blockIdx.y * 128, col0 = blockIdx.x * 128;
    const int sm = tid >> 1, scp = (tid & 1) * 2;

    const float* arow = A + (size_t)(row0 + sm) * K + scp * 8;
    const float* brow = BT + (size_t)(col0 + sm) * K + scp * 8;

    floatx4 acc[4][4];
#pragma unroll
    for (int i = 0; i < 4; i++)
#pragma unroll
        for (int j = 0; j < 4; j++) acc[i][j] = (floatx4){0.f, 0.f, 0.f, 0.f};

    for (int k0 = 0; k0 < K; k0 += 32) {
        float xa[16], xb[16];
        load16(arow + k0, xa);
        load16(brow + k0, xb);
        __syncthreads();
        write_split(xa, Ah, Al, sm, scp);
        write_split(xb, Bh, Bl, sm, scp);
        __syncthreads();

        short8 ah[4], al[4], bh[4], bl[4];
#pragma unroll
        for (int t = 0; t < 4; t++) {
            const int am = wm + t * 16 + lane15;
            const int bn = wn + t * 16 + lane15;
            ah[t] = *(const short8*)(Ah + lds_off(am, quad));
            al[t] = *(const short8*)(Al + lds_off(am, quad));
            bh[t] = *(const short8*)(Bh + lds_off(bn, quad));
            bl[t] = *(const short8*)(Bl + lds_off(bn, quad));
        }
#pragma unroll
        for (int i = 0; i < 4; i++)
#pragma unroll
            for (int j = 0; j < 4; j++) {
                acc[i][j] = __builtin_amdgcn_mfma_f32_16x16x32_bf16(ah[i], bh[j], acc[i][j], 0, 0, 0);
                acc[i][j] = __builtin_amdgcn_mfma_f32_16x16x32_bf16(ah[i], bl[j], acc[i][j], 0, 0, 0);
                acc[i][j] = __builtin_amdgcn_mfma_f32_16x16x32_bf16(al[i], bh[j], acc[i][j], 0, 0, 0);
            }
    }

#pragma unroll
    for (int i = 0; i < 4; i++)
#pragma unroll
        for (int j = 0; j < 4; j++) {
            const int gc = col0 + wn + j * 16 + lane15;
            const int rb = row0 + wm + i * 16 + quad * 4;
            const float bv = bias ? bias[gc] : 0.f;
#pragma unroll
            for (int r = 0; r < 4; r++) {
                const size_t o = (size_t)(rb + r) * N + gc;
                float v = acc[i][j][r] + bv;
                if (res) v += res[o];
                if (relu) v = fmaxf(v, 0.f);
                C[o] = v;
            }
        }
}

// ---------------------------------------------------------------------------
// Values MLP layer 1: A row r = kx[r/96,:](f32) - ck[idx[r],:](planes)
// B = t1 hi plane. TT = bf16(relu(A @ B^T + bias))
// ---------------------------------------------------------------------------
__global__ __launch_bounds__(256) void gemm_diff_bf16(
    const float* __restrict__ kx,
    const ushort* __restrict__ ckh, const ushort* __restrict__ ckl,
    const int* __restrict__ idx, const ushort* __restrict__ BTh,
    const float* __restrict__ bias, ushort* __restrict__ TT,
    int M, int N, int K)
{
    __shared__ ushort Ah[128 * 32];
    __shared__ ushort Bh[128 * 32];
    const int tid = threadIdx.x;
    const int lane = tid & 63, wid = tid >> 6;
    const int wm = (wid & 1) * 64, wn = (wid >> 1) * 64;
    const int lane15 = lane & 15, quad = lane >> 4;
    const int row0 = blockIdx.y * 128, col0 = blockIdx.x * 128;
    const int sm = tid >> 1, scp = (tid & 1) * 2;

    const int r = row0 + sm;
    const int bidx = r / NC;
    const float*  kxp = kx  + (size_t)bidx * ND + scp * 8;
    const ushort* chp = ckh + (size_t)idx[r] * ND + scp * 8;
    const ushort* clp = ckl + (size_t)idx[r] * ND + scp * 8;
    const ushort* brh = BTh + (size_t)(col0 + sm) * K + scp * 8;

    floatx4 acc[4][4];
#pragma unroll
    for (int i = 0; i < 4; i++)
#pragma unroll
        for (int j = 0; j < 4; j++) acc[i][j] = (floatx4){0.f, 0.f, 0.f, 0.f};

    for (int k0 = 0; k0 < K; k0 += 32) {
        float xa[16];
        load16(kxp + k0, xa);
        short8 h0 = *(const short8*)(chp + k0);
        short8 h1 = *(const short8*)(chp + k0 + 8);
        short8 l0 = *(const short8*)(clp + k0);
        short8 l1 = *(const short8*)(clp + k0 + 8);
        short8 b0 = *(const short8*)(brh + k0);
        short8 b1 = *(const short8*)(brh + k0 + 8);
        short8 d0, d1;
#pragma unroll
        for (int i = 0; i < 8; i++) {
            float c0 = bf2f((ushort)h0[i]) + bf2f((ushort)l0[i]);
            float c1 = bf2f((ushort)h1[i]) + bf2f((ushort)l1[i]);
            d0[i] = (short)f2bf(xa[i] - c0);
            d1[i] = (short)f2bf(xa[i + 8] - c1);
        }
        __syncthreads();
        *(short8*)(Ah + lds_off(sm, scp))     = d0;
        *(short8*)(Ah + lds_off(sm, scp + 1)) = d1;
        *(short8*)(Bh + lds_off(sm, scp))     = b0;
        *(short8*)(Bh + lds_off(sm, scp + 1)) = b1;
        __syncthreads();

        short8 ah[4], bh[4];
#pragma unroll
        for (int t = 0; t < 4; t++) {
            ah[t] = *(const short8*)(Ah + lds_off(wm + t * 16 + lane15, quad));
            bh[t] = *(const short8*)(Bh + lds_off(wn + t * 16 + lane15, quad));
        }
#pragma unroll
        for (int i = 0; i < 4; i++)
#pragma unroll
            for (int j = 0; j < 4; j++)
                acc[i][j] = __builtin_amdgcn_mfma_f32_16x16x32_bf16(ah[i], bh[j], acc[i][j], 0, 0, 0);
    }

#pragma unroll
    for (int i = 0; i < 4; i++)
#pragma unroll
        for (int j = 0; j < 4; j++) {
            const int gc = col0 + wn + j * 16 + lane15;
            const int rb = row0 + wm + i * 16 + quad * 4;
            const float bv = bias[gc];
#pragma unroll
            for (int rr = 0; rr < 4; rr++) {
                const size_t o = (size_t)(rb + rr) * N + gc;
                TT[o] = f2bf(fmaxf(acc[i][j][rr] + bv, 0.f));
            }
        }
}

// ---------------------------------------------------------------------------
// Values MLP layer 2: A bf16 [M][K], B hi plane [N][K]: C(f32) = A @ B^T
// ---------------------------------------------------------------------------
__global__ __launch_bounds__(256) void gemm_bf16_f32(
    const ushort* __restrict__ A, const ushort* __restrict__ BTh,
    float* __restrict__ C, int M, int N, int K)
{
    __shared__ ushort Ah[128 * 32];
    __shared__ ushort Bh[128 * 32];
    const int tid = threadIdx.x;
    const int lane = tid & 63, wid = tid >> 6;
    const int wm = (wid & 1) * 64, wn = (wid >> 1) * 64;
    const int lane15 = lane & 15, quad = lane >> 4;
    const int row0 = blockIdx.y * 128, col0 = blockIdx.x * 128;
    const int sm = tid >> 1, scp = (tid & 1) * 2;

    const ushort* arow = A   + (size_t)(row0 + sm) * K + scp * 8;
    const ushort* brow = BTh + (size_t)(col0 + sm) * K + scp * 8;

    floatx4 acc[4][4];
#pragma unroll
    for (int i = 0; i < 4; i++)
#pragma unroll
        for (int j = 0; j < 4; j++) acc[i][j] = (floatx4){0.f, 0.f, 0.f, 0.f};

    for (int k0 = 0; k0 < K; k0 += 32) {
        short8 a0 = *(const short8*)(arow + k0);
        short8 a1 = *(const short8*)(arow + k0 + 8);
        short8 b0 = *(const short8*)(brow + k0);
        short8 b1 = *(const short8*)(brow + k0 + 8);
        __syncthreads();
        *(short8*)(Ah + lds_off(sm, scp))     = a0;
        *(short8*)(Ah + lds_off(sm, scp + 1)) = a1;
        *(short8*)(Bh + lds_off(sm, scp))     = b0;
        *(short8*)(Bh + lds_off(sm, scp + 1)) = b1;
        __syncthreads();

        short8 ah[4], bh[4];
#pragma unroll
        for (int t = 0; t < 4; t++) {
            ah[t] = *(const short8*)(Ah + lds_off(wm + t * 16 + lane15, quad));
            bh[t] = *(const short8*)(Bh + lds_off(wn + t * 16 + lane15, quad));
        }
#pragma unroll
        for (int i = 0; i < 4; i++)
#pragma unroll
            for (int j = 0; j < 4; j++)
                acc[i][j] = __builtin_amdgcn_mfma_f32_16x16x32_bf16(ah[i], bh[j], acc[i][j], 0, 0, 0);
    }

#pragma unroll
    for (int i = 0; i < 4; i++)
#pragma unroll
        for (int j = 0; j < 4; j++) {
            const int gc = col0 + wn + j * 16 + lane15;
            const int rb = row0 + wm + i * 16 + quad * 4;
#pragma unroll
            for (int rr = 0; rr < 4; rr++)
                C[(size_t)(rb + rr) * N + gc] = acc[i][j][rr];
        }
}

// ---------------------------------------------------------------------------
// Prep kernels
// ---------------------------------------------------------------------------
__global__ __launch_bounds__(256) void transpose_kernel(
    const float* __restrict__ W, float* __restrict__ WT, int K, int N)
{
    const int o = blockIdx.x * 256 + threadIdx.x;
    if (o < K * N) {
        const int n = o / K, k = o - n * K;
        WT[o] = W[(size_t)k * N + n];
    }
}

// W[K][N] -> bf16 hi/lo planes [N][K]
__global__ __launch_bounds__(256) void split_wt_kernel(
    const float* __restrict__ W, ushort* __restrict__ WTh,
    ushort* __restrict__ WTl, int K, int N)
{
    const int o = blockIdx.x * 256 + threadIdx.x;
    if (o < K * N) {
        const int n = o / K, k = o - n * K;
        const float x = W[(size_t)k * N + n];
        const ushort h = f2bf(x);
        WTh[o] = h;
        WTl[o] = f2bf(x - bf2f(h));
    }
}

// elementwise f32 -> hi/lo planes
__global__ __launch_bounds__(256) void split_pl_kernel(
    const float* __restrict__ X, ushort* __restrict__ Xh,
    ushort* __restrict__ Xl, int n)
{
    const int i = blockIdx.x * 256 + threadIdx.x;
    if (i < n) {
        const float x = X[i];
        const ushort h = f2bf(x);
        Xh[i] = h;
        Xl[i] = f2bf(x - bf2f(h));
    }
}

// ---------------------------------------------------------------------------
// LayerNorm rows of 512, f32 in / f32 out (x-path)
// ---------------------------------------------------------------------------
__global__ __launch_bounds__(256) void ln_kernel(
    const float* __restrict__ X, const float* __restrict__ g,
    const float* __restrict__ b, float* __restrict__ Y, int relu)
{
    const int lane = threadIdx.x & 63;
    const int row  = blockIdx.x * 4 + (threadIdx.x >> 6);
    const float* x = X + (size_t)row * ND;
    const int d = lane * 8;

    float v[8];
    load16(x + d, v);   // 8 used? load16 loads 16 -> use explicit 8
    // NOTE: lane covers 8 elems; reload properly:
    float4 v0 = *(const float4*)(x + d);
    float4 v1 = *(const float4*)(x + d + 4);
    float s = v0.x + v0.y + v0.z + v0.w + v1.x + v1.y + v1.z + v1.w;
    float q = v0.x*v0.x + v0.y*v0.y + v0.z*v0.z + v0.w*v0.w
            + v1.x*v1.x + v1.y*v1.y + v1.z*v1.z + v1.w*v1.w;
#pragma unroll
    for (int off = 32; off; off >>= 1) {
        s += __shfl_down(s, off);
        q += __shfl_down(q, off);
    }
    s = __shfl(s, 0); q = __shfl(q, 0);
    const float mean = s * (1.f / ND);
    const float var  = q * (1.f / ND) - mean * mean;
    const float rs   = rsqrtf(var + 1e-5f);

    float4 g0 = *(const float4*)(g + d);
    float4 g1 = *(const float4*)(g + d + 4);
    float4 b0 = *(const float4*)(b + d);
    float4 b1 = *(const float4*)(b + d + 4);
    float4 o0, o1;
    o0.x = (v0.x - mean) * rs * g0.x + b0.x;
    o0.y = (v0.y - mean) * rs * g0.y + b0.y;
    o0.z = (v0.z - mean) * rs * g0.z + b0.z;
    o0.w = (v0.w - mean) * rs * g0.w + b0.w;
    o1.x = (v1.x - mean) * rs * g1.x + b1.x;
    o1.y = (v1.y - mean) * rs * g1.y + b1.y;
    o1.z = (v1.z - mean) * rs * g1.z + b1.z;
    o1.w = (v1.w - mean) * rs * g1.w + b1.w;
    if (relu) {
        o0.x = fmaxf(o0.x, 0.f); o0.y = fmaxf(o0.y, 0.f);
        o0.z = fmaxf(o0.z, 0.f); o0.w = fmaxf(o0.w, 0.f);
        o1.x = fmaxf(o1.x, 0.f); o1.y = fmaxf(o1.y, 0.f);
        o1.z = fmaxf(o1.z, 0.f); o1.w = fmaxf(o1.w, 0.f);
    }
    float* y = Y + (size_t)row * ND;
    *(float4*)(y + d)     = o0;
    *(float4*)(y + d + 4) = o1;
}

// LayerNorm rows of 512, planes in / planes out (candidate encode)
__global__ __launch_bounds__(256) void ln_pl_kernel(
    const ushort* __restrict__ Xh, const ushort* __restrict__ Xl,
    const float* __restrict__ g, const float* __restrict__ b,
    ushort* __restrict__ Yh, ushort* __restrict__ Yl)
{
    const int lane = threadIdx.x & 63;
    const int row  = blockIdx.x * 4 + (threadIdx.x >> 6);
    const int d = lane * 8;
    const size_t base = (size_t)row * ND + d;

    short8 xh = *(const short8*)(Xh + base);
    short8 xl = *(const short8*)(Xl + base);
    float v[8];
#pragma unroll
    for (int i = 0; i < 8; i++) v[i] = bf2f((ushort)xh[i]) + bf2f((ushort)xl[i]);

    float s = 0.f, q = 0.f;
#pragma unroll
    for (int i = 0; i < 8; i++) { s += v[i]; q += v[i] * v[i]; }
#pragma unroll
    for (int off = 32; off; off >>= 1) {
        s += __shfl_down(s, off);
        q += __shfl_down(q, off);
    }
    s = __shfl(s, 0); q = __shfl(q, 0);
    const float mean = s * (1.f / ND);
    const float var  = q * (1.f / ND) - mean * mean;
    const float rs   = rsqrtf(var + 1e-5f);

    short8 yh, yl;
#pragma unroll
    for (int i = 0; i < 8; i++) {
        const float o = (v[i] - mean) * rs * g[d + i] + b[d + i];
        const ushort h = f2bf(o);
        yh[i] = (short)h;
        yl[i] = (short)f2bf(o - bf2f(h));
    }
    *(short8*)(Yh + base) = yh;
    *(short8*)(Yl + base) = yl;
}

// Row squared-norm from planes
__global__ __launch_bounds__(256) void sqnorm_pl_kernel(
    const ushort* __restrict__ Xh, const ushort* __restrict__ Xl,
    float* __restrict__ sq)
{
    const int lane = threadIdx.x & 63;
    const int row  = blockIdx.x * 4 + (threadIdx.x >> 6);
    const size_t base = (size_t)row * ND + lane * 8;
    short8 xh = *(const short8*)(Xh + base);
    short8 xl = *(const short8*)(Xl + base);
    float q = 0.f;
#pragma unroll
    for (int i = 0; i < 8; i++) {
        float v = bf2f((ushort)xh[i]) + bf2f((ushort)xl[i]);
        q += v * v;
    }
#pragma unroll
    for (int off = 32; off; off >>= 1) q += __shfl_down(q, off);
    if (lane == 0) sq[row] = q;
}

// ---------------------------------------------------------------------------
// Two-stage exact top-96 (LDS-resident radix select)
// ---------------------------------------------------------------------------
__device__ __forceinline__ unsigned fkey(float f)
{
    unsigned u = __float_as_uint(f);
    return (u & 0x80000000u) ? ~u : (u | 0x80000000u);
}
__device__ __forceinline__ float inv_fkey(unsigned u)
{
    return __uint_as_float((u & 0x80000000u) ? (u & 0x7FFFFFFFu) : ~u);
}

// Stage 1: per-(row, 4096-segment) exact top-96 -> key/idx candidate buffer
__global__ __launch_bounds__(256) void topk_seg(
    const float* __restrict__ S, unsigned* __restrict__ K1key,
    int* __restrict__ K1idx)
{
    const int r = blockIdx.y, seg = blockIdx.x;
    const float* p = S + (size_t)r * NN + seg * TK_SEG;
    __shared__ unsigned keys[TK_SEG];       // 16 KB
    __shared__ unsigned hist[256];
    __shared__ unsigned sh_pref;
    __shared__ int sh_krem, cA, cB;
    const int tid = threadIdx.x;

    for (int i = tid; i < TK_SEG; i += 256) keys[i] = fkey(p[i]);
    if (tid == 0) { sh_pref = 0u; sh_krem = NC; cA = 0; cB = 0; }
    __syncthreads();

    for (int level = 0; level < 4; level++) {
        const int shift = 24 - 8 * level;
        hist[tid] = 0u;
        __syncthreads();
        const unsigned pref  = sh_pref;
        const unsigned pmask = level ? (0xFFFFFFFFu << (shift + 8)) : 0u;
        for (int i = tid; i < TK_SEG; i += 256) {
            const unsigned u = keys[i];
            if ((u & pmask) == pref)
                atomicAdd(&hist[(u >> shift) & 255u], 1u);
        }
        __syncthreads();
        if (tid == 0) {
            int krem = sh_krem;
            unsigned cum = 0;
            for (int bin = 0; bin < 256; bin++) {
                const unsigned c = hist[bin];
                if (cum + c >= (unsigned)krem) {
                    sh_pref = pref | ((unsigned)bin << shift);
                    sh_krem = krem - (int)cum;
                    break;
                }
                cum += c;
            }
        }
        __syncthreads();
    }

    const unsigned T = sh_pref;
    const int need = sh_krem;
    const int cntLess = NC - need;
    const size_t obase = ((size_t)r * TK_SPLIT + seg) * NC;
    for (int i = tid; i < TK_SEG; i += 256) {
        const unsigned u = keys[i];
        if (u < T) {
            const int pos = atomicAdd(&cA, 1);
            K1key[obase + pos] = u;
            K1idx[obase + pos] = seg * TK_SEG + i;
        } else if (u == T) {
            const int pos = atomicAdd(&cB, 1);
            if (pos < need) {
                K1key[obase + cntLess + pos] = u;
                K1idx[obase + cntLess + pos] = seg * TK_SEG + i;
            }
        }
    }
}

// Stage 2: per-row exact top-96 of the 1536 stage-1 survivors
__global__ __launch_bounds__(256) void topk_merge(
    const unsigned* __restrict__ K1key, const int* __restrict__ K1idx,
    int* __restrict__ idx_out, float* __restrict__ val_out, int b0)
{
    const int r = blockIdx.x;
    const int b = b0 + r;
    __shared__ unsigned keys[TK_CAND];      // 6 KB
    __shared__ int      idxs[TK_CAND];      // 6 KB
    __shared__ unsigned hist[256];
    __shared__ unsigned sh_pref;
    __shared__ int sh_krem, cA, cB;
    const int tid = threadIdx.x;
    const size_t ibase = (size_t)r * TK_CAND;

    for (int i = tid; i < TK_CAND; i += 256) {
        keys[i] = K1key[ibase + i];
        idxs[i] = K1idx[ibase + i];
    }
    if (tid == 0) { sh_pref = 0u; sh_krem = NC; cA = 0; cB = 0; }
    __syncthreads();

    for (int level = 0; level < 4; level++) {
        const int shift = 24 - 8 * level;
        hist[tid] = 0u;
        __syncthreads();
        const unsigned pref  = sh_pref;
        const unsigned pmask = level ? (0xFFFFFFFFu << (shift + 8)) : 0u;
        for (int i = tid; i < TK_CAND; i += 256) {
            const unsigned u = keys[i];
            if ((u & pmask) == pref)
                atomicAdd(&hist[(u >> shift) & 255u], 1u);
        }
        __syncthreads();
        if (tid == 0) {
            int krem = sh_krem;
            unsigned cum = 0;
            for (int bin = 0; bin < 256; bin++) {
                const unsigned c = hist[bin];
                if (cum + c >= (unsigned)krem) {
                    sh_pref = pref | ((unsigned)bin << shift);
                    sh_krem = krem - (int)cum;
                    break;
                }
                cum += c;
            }
        }
        __syncthreads();
    }

    const unsigned T = sh_pref;
    const int need = sh_krem;
    const int cntLess = NC - need;
    for (int i = tid; i < TK_CAND; i += 256) {
        const unsigned u = keys[i];
        if (u < T) {
            const int pos = atomicAdd(&cA, 1);
            idx_out[b * NC + pos] = idxs[i];
            val_out[b * NC + pos] = inv_fkey(u);
        } else if (u == T) {
            const int pos = atomicAdd(&cB, 1);
            if (pos < need) {
                idx_out[b * NC + cntLess + pos] = idxs[i];
                val_out[b * NC + cntLess + pos] = inv_fkey(u);
            }
        }
    }
}

// ---------------------------------------------------------------------------
__global__ __launch_bounds__(128) void probs_kernel(
    const float* __restrict__ svals, float* __restrict__ probs)
{
    const int b = blockIdx.x;
    const int tid = threadIdx.x;
    __shared__ float red[128];
    const bool valid = tid < NC;
    float s = valid ? -svals[b * NC + tid] : -3.4e38f;
    red[tid] = s;
    __syncthreads();
#pragma unroll
    for (int off = 64; off; off >>= 1) {
        if (tid < off) red[tid] = fmaxf(red[tid], red[tid + off]);
        __syncthreads();
    }
    const float m = red[0];
    __syncthreads();
    float e = valid ? expf(s - m) : 0.f;
    red[tid] = e;
    __syncthreads();
#pragma unroll
    for (int off = 64; off; off >>= 1) {
        if (tid < off) red[tid] += red[tid + off];
        __syncthreads();
    }
    const float sum = red[0];
    if (valid) probs[b * NC + tid] = e / sum;
}

__global__ __launch_bounds__(256) void ctx_kernel(
    const float* __restrict__ VAL, const float* __restrict__ probs,
    const float* __restrict__ cand_y, const int* __restrict__ idx,
    const float* __restrict__ labW, const float* __restrict__ labb,
    const float* __restrict__ xin, float* __restrict__ xout, int b0)
{
    const int b_loc = blockIdx.x;
    const int b = b0 + b_loc;
    const int tid = threadIdx.x;
    __shared__ float pv[NC];
    __shared__ float red[256];
    float py_part = 0.f;
    if (tid < NC) {
        float p = probs[b * NC + tid];
        pv[tid] = p;
        py_part = p * cand_y[idx[b * NC + tid]];
    }
    red[tid] = py_part;
    __syncthreads();
#pragma unroll
    for (int off = 128; off; off >>= 1) {
        if (tid < off) red[tid] += red[tid + off];
        __syncthreads();
    }
    const float py = red[0];

    for (int d = tid; d < ND; d += 256) {
        const float* vp = VAL + (size_t)b_loc * NC * ND + d;
        float acc = 0.f;
#pragma unroll 8
        for (int c = 0; c < NC; c++) acc += pv[c] * vp[(size_t)c * ND];
        float ctx = acc + py * labW[d] + labb[d];
        xout[(size_t)b * ND + d] = xin[(size_t)b * ND + d] + ctx;
    }
}

__global__ __launch_bounds__(64) void head_kernel(
    const float* __restrict__ X, const float* __restrict__ hW,
    const float* __restrict__ hb, float* __restrict__ out)
{
    const int b = blockIdx.x;
    const int lane = threadIdx.x;
    const float* x = X + (size_t)b * ND;
    float acc = 0.f;
#pragma unroll
    for (int j = 0; j < 8; j++) {
        int d = lane + 64 * j;
        acc += x[d] * hW[d];
    }
#pragma unroll
    for (int off = 32; off; off >>= 1) acc += __shfl_down(acc, off);
    if (lane == 0) out[b] = acc + hb[0];
}

// ---------------------------------------------------------------------------
extern "C" void kernel_launch(void* const* d_in, const int* in_sizes, int n_in,
                              void* d_out, int out_size, void* d_ws, size_t ws_size,
                              hipStream_t stream)
{
    const float* x_num    = (const float*)d_in[0];
    const float* cand_num = (const float*)d_in[1];
    const float* cand_y   = (const float*)d_in[2];
    const float* lin_W    = (const float*)d_in[3];
    const float* lin_b    = (const float*)d_in[4];
    const float* e_W1     = (const float*)d_in[5];
    const float* e_b1     = (const float*)d_in[6];
    const float* e_W2     = (const float*)d_in[7];
    const float* e_b2     = (const float*)d_in[8];
    const float* mix_g    = (const float*)d_in[9];
    const float* mix_b    = (const float*)d_in[10];
    const float* K_W      = (const float*)d_in[11];
    const float* K_b      = (const float*)d_in[12];
    const float* lab_W    = (const float*)d_in[13];
    const float* lab_b    = (const float*)d_in[14];
    const float* T_W1     = (const float*)d_in[15];
    const float* T_b1     = (const float*)d_in[16];
    const float* T_W2     = (const float*)d_in[17];
    const float* p_ln_g   = (const float*)d_in[18];
    const float* p_ln_b   = (const float*)d_in[19];
    const float* p_W1     = (const float*)d_in[20];
    const float* p_b1     = (const float*)d_in[21];
    const float* p_W2     = (const float*)d_in[22];
    const float* p_b2     = (const float*)d_in[23];
    const float* h_ln_g   = (const float*)d_in[24];
    const float* h_ln_b   = (const float*)d_in[25];
    const float* h_W      = (const float*)d_in[26];
    const float* h_b      = (const float*)d_in[27];
    float* out = (float*)d_out;
    (void)in_sizes; (void)n_in; (void)out_size; (void)ws_size;

    // ---- workspace layout (~253 MB) ----
    size_t off = 0;
    auto ralloc = [&](size_t bytes) -> void* {
        void* p = (char*)d_ws + off;
        off += (bytes + 255) & ~(size_t)255;
        return p;
    };
    auto falloc = [&](size_t n) -> float*  { return (float*)ralloc(n * 4); };
    auto ualloc = [&](size_t n) -> ushort* { return (ushort*)ralloc(n * 2); };

    // f32 transposed weights (x-path / predictor)
    float* WT_lin = falloc((size_t)ND * NF);
    float* WT_e1  = falloc((size_t)NDB * ND);
    float* WT_e2  = falloc((size_t)ND * NDB);
    float* WT_kw  = falloc((size_t)ND * ND);
    float* WT_p1  = falloc((size_t)NDB * ND);
    float* WT_p2  = falloc((size_t)ND * NDB);
    // bf16 plane weights (candidate encode + values path)
    ushort* WP_lin_h = ualloc((size_t)ND * NF);
    ushort* WP_lin_l = ualloc((size_t)ND * NF);
    ushort* WP_e1_h  = ualloc((size_t)NDB * ND);
    ushort* WP_e1_l  = ualloc((size_t)NDB * ND);
    ushort* WP_e2_h  = ualloc((size_t)ND * NDB);
    ushort* WP_e2_l  = ualloc((size_t)ND * NDB);
    ushort* WP_kw_h  = ualloc((size_t)ND * ND);
    ushort* WP_kw_l  = ualloc((size_t)ND * ND);
    ushort* WP_t1_h  = ualloc((size_t)NDB * ND);
    ushort* WP_t1_l  = ualloc((size_t)NDB * ND);
    ushort* WP_t2_h  = ualloc((size_t)ND * NDB);
    ushort* WP_t2_l  = ualloc((size_t)ND * NDB);

    ushort* R_CKh = ualloc((size_t)NN * ND);      // cand_k hi plane (67 MB)
    ushort* R_CKl = ualloc((size_t)NN * ND);      // cand_k lo plane (67 MB)
    float*  R_sq  = falloc(NN);
    float*  R_Hx  = falloc((size_t)NB * ND);
    float*  R_Tx  = falloc((size_t)NB * NDB);
    float*  R_Gx  = falloc((size_t)NB * ND);
    float*  R_kx  = falloc((size_t)NB * ND);
    ushort* R_kxh = ualloc((size_t)NB * ND);
    ushort* R_kxl = ualloc((size_t)NB * ND);
    int*    R_idx = (int*)ralloc((size_t)NB * NC * 4);
    float*  R_ssel= falloc((size_t)NB * NC);
    float*  R_prob= falloc((size_t)NB * NC);
    float*  R_xupd= falloc((size_t)NB * ND);
    float*  R_lnx = falloc((size_t)NB * ND);
    float*  R_tp  = falloc((size_t)NB * NDB);
    float*  R_x2  = falloc((size_t)NB * ND);
    float*  R_lnx2= falloc((size_t)NB * ND);
    unsigned* K1key = (unsigned*)ralloc((size_t)BB_C * TK_CAND * 4);
    int*      K1idx = (int*)ralloc((size_t)BB_C * TK_CAND * 4);
    char* SCR = (char*)ralloc((size_t)70 * 1024 * 1024);   // 70 MB shared scratch

    // ---- 0. weight prep ----
    auto tr = [&](const float* W, float* WT, int K, int N) {
        transpose_kernel<<<dim3((K * N + 255) / 256), dim3(256), 0, stream>>>(W, WT, K, N);
    };
    auto sw = [&](const float* W, ushort* WTh, ushort* WTl, int K, int N) {
        split_wt_kernel<<<dim3((K * N + 255) / 256), dim3(256), 0, stream>>>(W, WTh, WTl, K, N);
    };
    tr(lin_W, WT_lin, NF, ND);
    tr(e_W1,  WT_e1,  ND, NDB);
    tr(e_W2,  WT_e2,  NDB, ND);
    tr(K_W,   WT_kw,  ND, ND);
    tr(p_W1,  WT_p1,  ND, NDB);
    tr(p_W2,  WT_p2,  NDB, ND);
    sw(lin_W, WP_lin_h, WP_lin_l, NF, ND);
    sw(e_W1,  WP_e1_h,  WP_e1_l,  ND, NDB);
    sw(e_W2,  WP_e2_h,  WP_e2_l,  NDB, ND);
    sw(K_W,   WP_kw_h,  WP_kw_l,  ND, ND);
    sw(T_W1,  WP_t1_h,  WP_t1_l,  ND, NDB);
    sw(T_W2,  WP_t2_h,  WP_t2_l,  NDB, ND);

    auto gss = [&](const ushort* Ah, const ushort* Al, const ushort* Bh,
                   const ushort* Bl, const float* bias, const ushort* resh,
                   const ushort* resl, const float* sq, float* Sf,
                   ushort* Ch, ushort* Cl, int M, int Nn, int K, int relu) {
        gemm_ss<<<dim3(Nn / 128, M / 128), dim3(256), 0, stream>>>(
            Ah, Al, Bh, Bl, bias, resh, resl, sq, Sf, Ch, Cl, M, Nn, K, relu);
    };
    auto gsplit = [&](const float* A, const float* BT, const float* bias,
                      const float* res, float* C, int M, int Nn, int K, int relu) {
        gemm_split_nt<<<dim3(Nn / 128, M / 128), dim3(256), 0, stream>>>(
            A, BT, bias, res, C, M, Nn, K, relu);
    };

    // ---- 1. candidate encode (chunked; plane operands, split-bf16 MFMA) ----
    {
        ushort* CNh = (ushort*)SCR;
        ushort* CNl = CNh + (size_t)CH_A * NF;
        ushort* Hh  = CNl + (size_t)CH_A * NF;
        ushort* Hl  = Hh  + (size_t)CH_A * ND;
        ushort* Th  = Hl  + (size_t)CH_A * ND;
        ushort* Tl  = Th  + (size_t)CH_A * NDB;
        ushort* H2h = Tl  + (size_t)CH_A * NDB;
        ushort* H2l = H2h + (size_t)CH_A * ND;
        ushort* Gh  = Th;   // overlay: T dead after e2
        ushort* Gl  = Tl;

        for (int n0 = 0; n0 < NN; n0 += CH_A) {
            split_pl_kernel<<<dim3((CH_A * NF + 255) / 256), dim3(256), 0, stream>>>(
                cand_num + (size_t)n0 * NF, CNh, CNl, CH_A * NF);
            gss(CNh, CNl, WP_lin_h, WP_lin_l, lin_b, nullptr, nullptr, nullptr,
                nullptr, Hh, Hl, CH_A, ND, NF, 0);
            gss(Hh, Hl, WP_e1_h, WP_e1_l, e_b1, nullptr, nullptr, nullptr,
                nullptr, Th, Tl, CH_A, NDB, ND, 1);
            gss(Th, Tl, WP_e2_h, WP_e2_l, e_b2, Hh, Hl, nullptr,
                nullptr, H2h, H2l, CH_A, ND, NDB, 0);
            ln_pl_kernel<<<dim3(CH_A / 4), dim3(256), 0, stream>>>(
                H2h, H2l, mix_g, mix_b, Gh, Gl);
            gss(Gh, Gl, WP_kw_h, WP_kw_l, K_b, nullptr, nullptr, nullptr,
                nullptr, R_CKh + (size_t)n0 * ND, R_CKl + (size_t)n0 * ND,
                CH_A, ND, ND, 0);
            sqnorm_pl_kernel<<<dim3(CH_A / 4), dim3(256), 0, stream>>>(
                R_CKh + (size_t)n0 * ND, R_CKl + (size_t)n0 * ND, R_sq + n0);
        }
    }

    // ---- 2. x encode (f32-operand split kernel; small) ----
    gsplit(x_num, WT_lin, lin_b, nullptr, R_Hx, NB, ND, NF, 0);
    gsplit(R_Hx, WT_e1, e_b1, nullptr, R_Tx, NB, NDB, ND, 1);
    gsplit(R_Tx, WT_e2, e_b2, R_Hx, R_Hx, NB, ND, NDB, 0);
    ln_kernel<<<dim3(NB / 4), dim3(256), 0, stream>>>(R_Hx, mix_g, mix_b, R_Gx, 0);
    gsplit(R_Gx, WT_kw, K_b, nullptr, R_kx, NB, ND, ND, 0);
    split_pl_kernel<<<dim3((NB * ND + 255) / 256), dim3(256), 0, stream>>>(
        R_kx, R_kxh, R_kxl, NB * ND);

    // ---- 3. scores + two-stage top-96 + softmax ----
    for (int b0 = 0; b0 < NB; b0 += BB_C) {
        float* S = (float*)SCR;
        gss(R_kxh + (size_t)b0 * ND, R_kxl + (size_t)b0 * ND, R_CKh, R_CKl,
            nullptr, nullptr, nullptr, R_sq, S, nullptr, nullptr,
            BB_C, NN, ND, 0);
        topk_seg<<<dim3(TK_SPLIT, BB_C), dim3(256), 0, stream>>>(S, K1key, K1idx);
        topk_merge<<<dim3(BB_C), dim3(256), 0, stream>>>(K1key, K1idx,
                                                         R_idx, R_ssel, b0);
    }
    probs_kernel<<<dim3(NB), dim3(128), 0, stream>>>(R_ssel, R_prob);

    // ---- 4. values path (plain bf16 MFMA, diff fused) ----
    for (int b0 = 0; b0 < NB; b0 += BB_D) {
        ushort* TT = (ushort*)SCR;                                  // [M,1024] bf16
        float* VAL = (float*)(SCR + (size_t)BB_D * NC * NDB * 2);   // f32 after TT
        const int M = BB_D * NC;   // 12288
        gemm_diff_bf16<<<dim3(NDB / 128, M / 128), dim3(256), 0, stream>>>(
            R_kx + (size_t)b0 * ND, R_CKh, R_CKl, R_idx + b0 * NC,
            WP_t1_h, T_b1, TT, M, NDB, ND);
        gemm_bf16_f32<<<dim3(ND / 128, M / 128), dim3(256), 0, stream>>>(
            TT, WP_t2_h, VAL, M, ND, NDB);
        ctx_kernel<<<dim3(BB_D), dim3(256), 0, stream>>>(
            VAL, R_prob, cand_y, R_idx, lab_W, lab_b, R_Hx, R_xupd, b0);
    }

    // ---- 5. predictor block + head ----
    ln_kernel<<<dim3(NB / 4), dim3(256), 0, stream>>>(R_xupd, p_ln_g, p_ln_b, R_lnx, 0);
    gsplit(R_lnx, WT_p1, p_b1, nullptr, R_tp, NB, NDB, ND, 1);
    gsplit(R_tp, WT_p2, p_b2, R_xupd, R_x2, NB, ND, NDB, 0);
    ln_kernel<<<dim3(NB / 4), dim3(256), 0, stream>>>(R_x2, h_ln_g, h_ln_b, R_lnx2, 1);
    head_kernel<<<dim3(NB), dim3(64), 0, stream>>>(R_lnx2, h_W, h_b, out);
}

// Round 7
// 3569.755 us; speedup vs baseline: 1.0998x; 1.0998x over previous
//
#include <hip/hip_runtime.h>

// Problem constants
#define NB   1024
#define NN   65536
#define NF   64
#define ND   512
#define NDB  1024
#define NC   96

// Chunking
#define CH_A 8192      // candidate-encode chunk rows
#define BB_C 256       // scores/topk chunk of B rows
#define BB_D 128       // values-path chunk of B rows

// top-k segmentation
#define TK_SPLIT 16
#define TK_SEG   (NN / TK_SPLIT)   // 4096
#define TK_CAND  (TK_SPLIT * NC)   // 1536

typedef unsigned short ushort;
typedef __attribute__((ext_vector_type(8))) short short8;
typedef __attribute__((ext_vector_type(4))) float floatx4;

__device__ __forceinline__ ushort f2bf(float f) {   // RNE f32->bf16
    unsigned u = __float_as_uint(f);
    u += 0x7fffu + ((u >> 16) & 1u);
    return (ushort)(u >> 16);
}
__device__ __forceinline__ float bf2f(ushort h) {
    return __uint_as_float(((unsigned)h) << 16);
}
// LDS plane: [m][k] bf16, k-stride 32, 16B-chunk XOR swizzle -> conflict-free
__device__ __forceinline__ int lds_off(int m, int c) {
    return m * 32 + (((c + (m >> 1)) & 3) << 3);
}

// ---------------------------------------------------------------------------
// Split-plane MFMA GEMM (f32-emulating, 3 MFMA), NT:
//   acc = A @ B^T  with A=(Ah,Al)[M][K], B=(Bh,Bl)[N][K] bf16 planes.
// Epilogue: scoresq ? Sf = scoresq[n]-2*acc : v=acc+bias(+res)(relu) -> planes
// ---------------------------------------------------------------------------
__global__ __launch_bounds__(256) void gemm_ss(
    const ushort* __restrict__ Ah_g, const ushort* __restrict__ Al_g,
    const ushort* __restrict__ Bh_g, const ushort* __restrict__ Bl_g,
    const float* __restrict__ bias,
    const ushort* __restrict__ resh, const ushort* __restrict__ resl,
    const float* __restrict__ scoresq, float* __restrict__ Sf,
    ushort* __restrict__ Ch, ushort* __restrict__ Cl,
    int M, int N, int K, int relu)
{
    __shared__ ushort Ah[128 * 32], Al[128 * 32];
    __shared__ ushort Bh[128 * 32], Bl[128 * 32];
    const int tid = threadIdx.x;
    const int lane = tid & 63, wid = tid >> 6;
    const int wm = (wid & 1) * 64, wn = (wid >> 1) * 64;
    const int lane15 = lane & 15, quad = lane >> 4;
    const int row0 = blockIdx.y * 128, col0 = blockIdx.x * 128;
    const int sm = tid >> 1, scp = (tid & 1) * 2;

    const ushort* arh = Ah_g + (size_t)(row0 + sm) * K + scp * 8;
    const ushort* arl = Al_g + (size_t)(row0 + sm) * K + scp * 8;
    const ushort* brh = Bh_g + (size_t)(col0 + sm) * K + scp * 8;
    const ushort* brl = Bl_g + (size_t)(col0 + sm) * K + scp * 8;

    floatx4 acc[4][4];
#pragma unroll
    for (int i = 0; i < 4; i++)
#pragma unroll
        for (int j = 0; j < 4; j++) acc[i][j] = (floatx4){0.f, 0.f, 0.f, 0.f};

    for (int k0 = 0; k0 < K; k0 += 32) {
        short8 a0 = *(const short8*)(arh + k0);
        short8 a1 = *(const short8*)(arh + k0 + 8);
        short8 a2 = *(const short8*)(arl + k0);
        short8 a3 = *(const short8*)(arl + k0 + 8);
        short8 b0 = *(const short8*)(brh + k0);
        short8 b1 = *(const short8*)(brh + k0 + 8);
        short8 b2 = *(const short8*)(brl + k0);
        short8 b3 = *(const short8*)(brl + k0 + 8);
        __syncthreads();
        *(short8*)(Ah + lds_off(sm, scp))     = a0;
        *(short8*)(Ah + lds_off(sm, scp + 1)) = a1;
        *(short8*)(Al + lds_off(sm, scp))     = a2;
        *(short8*)(Al + lds_off(sm, scp + 1)) = a3;
        *(short8*)(Bh + lds_off(sm, scp))     = b0;
        *(short8*)(Bh + lds_off(sm, scp + 1)) = b1;
        *(short8*)(Bl + lds_off(sm, scp))     = b2;
        *(short8*)(Bl + lds_off(sm, scp + 1)) = b3;
        __syncthreads();

        short8 ah[4], al[4], bh[4], bl[4];
#pragma unroll
        for (int t = 0; t < 4; t++) {
            const int am = wm + t * 16 + lane15;
            const int bn = wn + t * 16 + lane15;
            ah[t] = *(const short8*)(Ah + lds_off(am, quad));
            al[t] = *(const short8*)(Al + lds_off(am, quad));
            bh[t] = *(const short8*)(Bh + lds_off(bn, quad));
            bl[t] = *(const short8*)(Bl + lds_off(bn, quad));
        }
#pragma unroll
        for (int i = 0; i < 4; i++)
#pragma unroll
            for (int j = 0; j < 4; j++) {
                acc[i][j] = __builtin_amdgcn_mfma_f32_16x16x32_bf16(ah[i], bh[j], acc[i][j], 0, 0, 0);
                acc[i][j] = __builtin_amdgcn_mfma_f32_16x16x32_bf16(ah[i], bl[j], acc[i][j], 0, 0, 0);
                acc[i][j] = __builtin_amdgcn_mfma_f32_16x16x32_bf16(al[i], bh[j], acc[i][j], 0, 0, 0);
            }
    }

    // C/D layout: col=lane&15, row=quad*4+reg  [m89]
#pragma unroll
    for (int i = 0; i < 4; i++)
#pragma unroll
        for (int j = 0; j < 4; j++) {
            const int gc = col0 + wn + j * 16 + lane15;
            const int rb = row0 + wm + i * 16 + quad * 4;
            const float bv = bias ? bias[gc] : 0.f;
            const float sv = scoresq ? scoresq[gc] : 0.f;
#pragma unroll
            for (int r = 0; r < 4; r++) {
                const size_t o = (size_t)(rb + r) * N + gc;
                float v = acc[i][j][r];
                if (scoresq) {
                    Sf[o] = sv - 2.f * v;
                } else {
                    v += bv;
                    if (resh) v += bf2f(resh[o]) + bf2f(resl[o]);
                    if (relu) v = fmaxf(v, 0.f);
                    ushort h = f2bf(v);
                    Ch[o] = h;
                    Cl[o] = f2bf(v - bf2f(h));
                }
            }
        }
}

// ---------------------------------------------------------------------------
// Split-bf16 GEMM with f32 operands (x-path / predictor; small M)
// ---------------------------------------------------------------------------
__device__ __forceinline__ void load16(const float* p, float* x) {
    *(float4*)(x)      = *(const float4*)(p);
    *(float4*)(x + 4)  = *(const float4*)(p + 4);
    *(float4*)(x + 8)  = *(const float4*)(p + 8);
    *(float4*)(x + 12) = *(const float4*)(p + 12);
}
__device__ __forceinline__ void write_split(const float* x, ushort* Ph,
                                            ushort* Pl, int m, int cp) {
    short8 h0, h1, l0, l1;
#pragma unroll
    for (int i = 0; i < 8; i++) {
        ushort h = f2bf(x[i]);
        h0[i] = (short)h;
        l0[i] = (short)f2bf(x[i] - bf2f(h));
        ushort g = f2bf(x[i + 8]);
        h1[i] = (short)g;
        l1[i] = (short)f2bf(x[i + 8] - bf2f(g));
    }
    *(short8*)(Ph + lds_off(m, cp))     = h0;
    *(short8*)(Ph + lds_off(m, cp + 1)) = h1;
    *(short8*)(Pl + lds_off(m, cp))     = l0;
    *(short8*)(Pl + lds_off(m, cp + 1)) = l1;
}

__global__ __launch_bounds__(256) void gemm_split_nt(
    const float* __restrict__ A, const float* __restrict__ BT,
    const float* __restrict__ bias, const float* res,
    float* C, int M, int N, int K, int relu)
{
    __shared__ ushort Ah[128 * 32], Al[128 * 32];
    __shared__ ushort Bh[128 * 32], Bl[128 * 32];
    const int tid = threadIdx.x;
    const int lane = tid & 63, wid = tid >> 6;
    const int wm = (wid & 1) * 64, wn = (wid >> 1) * 64;
    const int lane15 = lane & 15, quad = lane >> 4;
    const int row0 = blockIdx.y * 128, col0 = blockIdx.x * 128;
    const int sm = tid >> 1, scp = (tid & 1) * 2;

    const float* arow = A + (size_t)(row0 + sm) * K + scp * 8;
    const float* brow = BT + (size_t)(col0 + sm) * K + scp * 8;

    floatx4 acc[4][4];
#pragma unroll
    for (int i = 0; i < 4; i++)
#pragma unroll
        for (int j = 0; j < 4; j++) acc[i][j] = (floatx4){0.f, 0.f, 0.f, 0.f};

    for (int k0 = 0; k0 < K; k0 += 32) {
        float xa[16], xb[16];
        load16(arow + k0, xa);
        load16(brow + k0, xb);
        __syncthreads();
        write_split(xa, Ah, Al, sm, scp);
        write_split(xb, Bh, Bl, sm, scp);
        __syncthreads();

        short8 ah[4], al[4], bh[4], bl[4];
#pragma unroll
        for (int t = 0; t < 4; t++) {
            const int am = wm + t * 16 + lane15;
            const int bn = wn + t * 16 + lane15;
            ah[t] = *(const short8*)(Ah + lds_off(am, quad));
            al[t] = *(const short8*)(Al + lds_off(am, quad));
            bh[t] = *(const short8*)(Bh + lds_off(bn, quad));
            bl[t] = *(const short8*)(Bl + lds_off(bn, quad));
        }
#pragma unroll
        for (int i = 0; i < 4; i++)
#pragma unroll
            for (int j = 0; j < 4; j++) {
                acc[i][j] = __builtin_amdgcn_mfma_f32_16x16x32_bf16(ah[i], bh[j], acc[i][j], 0, 0, 0);
                acc[i][j] = __builtin_amdgcn_mfma_f32_16x16x32_bf16(ah[i], bl[j], acc[i][j], 0, 0, 0);
                acc[i][j] = __builtin_amdgcn_mfma_f32_16x16x32_bf16(al[i], bh[j], acc[i][j], 0, 0, 0);
            }
    }

#pragma unroll
    for (int i = 0; i < 4; i++)
#pragma unroll
        for (int j = 0; j < 4; j++) {
            const int gc = col0 + wn + j * 16 + lane15;
            const int rb = row0 + wm + i * 16 + quad * 4;
            const float bv = bias ? bias[gc] : 0.f;
#pragma unroll
            for (int r = 0; r < 4; r++) {
                const size_t o = (size_t)(rb + r) * N + gc;
                float v = acc[i][j][r] + bv;
                if (res) v += res[o];
                if (relu) v = fmaxf(v, 0.f);
                C[o] = v;
            }
        }
}

// ---------------------------------------------------------------------------
// Values MLP layer 1: A row r = kx[r/96,:](f32) - ck[idx[r],:](planes)
// B = t1 hi plane. TT = bf16(relu(A @ B^T + bias))
// ---------------------------------------------------------------------------
__global__ __launch_bounds__(256) void gemm_diff_bf16(
    const float* __restrict__ kx,
    const ushort* __restrict__ ckh, const ushort* __restrict__ ckl,
    const int* __restrict__ idx, const ushort* __restrict__ BTh,
    const float* __restrict__ bias, ushort* __restrict__ TT,
    int M, int N, int K)
{
    __shared__ ushort Ah[128 * 32];
    __shared__ ushort Bh[128 * 32];
    const int tid = threadIdx.x;
    const int lane = tid & 63, wid = tid >> 6;
    const int wm = (wid & 1) * 64, wn = (wid >> 1) * 64;
    const int lane15 = lane & 15, quad = lane >> 4;
    const int row0 = blockIdx.y * 128, col0 = blockIdx.x * 128;
    const int sm = tid >> 1, scp = (tid & 1) * 2;

    const int r = row0 + sm;
    const int bidx = r / NC;
    const float*  kxp = kx  + (size_t)bidx * ND + scp * 8;
    const ushort* chp = ckh + (size_t)idx[r] * ND + scp * 8;
    const ushort* clp = ckl + (size_t)idx[r] * ND + scp * 8;
    const ushort* brh = BTh + (size_t)(col0 + sm) * K + scp * 8;

    floatx4 acc[4][4];
#pragma unroll
    for (int i = 0; i < 4; i++)
#pragma unroll
        for (int j = 0; j < 4; j++) acc[i][j] = (floatx4){0.f, 0.f, 0.f, 0.f};

    for (int k0 = 0; k0 < K; k0 += 32) {
        float xa[16];
        load16(kxp + k0, xa);
        short8 h0 = *(const short8*)(chp + k0);
        short8 h1 = *(const short8*)(chp + k0 + 8);
        short8 l0 = *(const short8*)(clp + k0);
        short8 l1 = *(const short8*)(clp + k0 + 8);
        short8 b0 = *(const short8*)(brh + k0);
        short8 b1 = *(const short8*)(brh + k0 + 8);
        short8 d0, d1;
#pragma unroll
        for (int i = 0; i < 8; i++) {
            float c0 = bf2f((ushort)h0[i]) + bf2f((ushort)l0[i]);
            float c1 = bf2f((ushort)h1[i]) + bf2f((ushort)l1[i]);
            d0[i] = (short)f2bf(xa[i] - c0);
            d1[i] = (short)f2bf(xa[i + 8] - c1);
        }
        __syncthreads();
        *(short8*)(Ah + lds_off(sm, scp))     = d0;
        *(short8*)(Ah + lds_off(sm, scp + 1)) = d1;
        *(short8*)(Bh + lds_off(sm, scp))     = b0;
        *(short8*)(Bh + lds_off(sm, scp + 1)) = b1;
        __syncthreads();

        short8 ah[4], bh[4];
#pragma unroll
        for (int t = 0; t < 4; t++) {
            ah[t] = *(const short8*)(Ah + lds_off(wm + t * 16 + lane15, quad));
            bh[t] = *(const short8*)(Bh + lds_off(wn + t * 16 + lane15, quad));
        }
#pragma unroll
        for (int i = 0; i < 4; i++)
#pragma unroll
            for (int j = 0; j < 4; j++)
                acc[i][j] = __builtin_amdgcn_mfma_f32_16x16x32_bf16(ah[i], bh[j], acc[i][j], 0, 0, 0);
    }

#pragma unroll
    for (int i = 0; i < 4; i++)
#pragma unroll
        for (int j = 0; j < 4; j++) {
            const int gc = col0 + wn + j * 16 + lane15;
            const int rb = row0 + wm + i * 16 + quad * 4;
            const float bv = bias[gc];
#pragma unroll
            for (int rr = 0; rr < 4; rr++) {
                const size_t o = (size_t)(rb + rr) * N + gc;
                TT[o] = f2bf(fmaxf(acc[i][j][rr] + bv, 0.f));
            }
        }
}

// ---------------------------------------------------------------------------
// Values MLP layer 2: A bf16 [M][K], B hi plane [N][K]: C(f32) = A @ B^T
// ---------------------------------------------------------------------------
__global__ __launch_bounds__(256) void gemm_bf16_f32(
    const ushort* __restrict__ A, const ushort* __restrict__ BTh,
    float* __restrict__ C, int M, int N, int K)
{
    __shared__ ushort Ah[128 * 32];
    __shared__ ushort Bh[128 * 32];
    const int tid = threadIdx.x;
    const int lane = tid & 63, wid = tid >> 6;
    const int wm = (wid & 1) * 64, wn = (wid >> 1) * 64;
    const int lane15 = lane & 15, quad = lane >> 4;
    const int row0 = blockIdx.y * 128, col0 = blockIdx.x * 128;
    const int sm = tid >> 1, scp = (tid & 1) * 2;

    const ushort* arow = A   + (size_t)(row0 + sm) * K + scp * 8;
    const ushort* brow = BTh + (size_t)(col0 + sm) * K + scp * 8;

    floatx4 acc[4][4];
#pragma unroll
    for (int i = 0; i < 4; i++)
#pragma unroll
        for (int j = 0; j < 4; j++) acc[i][j] = (floatx4){0.f, 0.f, 0.f, 0.f};

    for (int k0 = 0; k0 < K; k0 += 32) {
        short8 a0 = *(const short8*)(arow + k0);
        short8 a1 = *(const short8*)(arow + k0 + 8);
        short8 b0 = *(const short8*)(brow + k0);
        short8 b1 = *(const short8*)(brow + k0 + 8);
        __syncthreads();
        *(short8*)(Ah + lds_off(sm, scp))     = a0;
        *(short8*)(Ah + lds_off(sm, scp + 1)) = a1;
        *(short8*)(Bh + lds_off(sm, scp))     = b0;
        *(short8*)(Bh + lds_off(sm, scp + 1)) = b1;
        __syncthreads();

        short8 ah[4], bh[4];
#pragma unroll
        for (int t = 0; t < 4; t++) {
            ah[t] = *(const short8*)(Ah + lds_off(wm + t * 16 + lane15, quad));
            bh[t] = *(const short8*)(Bh + lds_off(wn + t * 16 + lane15, quad));
        }
#pragma unroll
        for (int i = 0; i < 4; i++)
#pragma unroll
            for (int j = 0; j < 4; j++)
                acc[i][j] = __builtin_amdgcn_mfma_f32_16x16x32_bf16(ah[i], bh[j], acc[i][j], 0, 0, 0);
    }

#pragma unroll
    for (int i = 0; i < 4; i++)
#pragma unroll
        for (int j = 0; j < 4; j++) {
            const int gc = col0 + wn + j * 16 + lane15;
            const int rb = row0 + wm + i * 16 + quad * 4;
#pragma unroll
            for (int rr = 0; rr < 4; rr++)
                C[(size_t)(rb + rr) * N + gc] = acc[i][j][rr];
        }
}

// ---------------------------------------------------------------------------
// Prep kernels
// ---------------------------------------------------------------------------
__global__ __launch_bounds__(256) void transpose_kernel(
    const float* __restrict__ W, float* __restrict__ WT, int K, int N)
{
    const int o = blockIdx.x * 256 + threadIdx.x;
    if (o < K * N) {
        const int n = o / K, k = o - n * K;
        WT[o] = W[(size_t)k * N + n];
    }
}

__global__ __launch_bounds__(256) void split_wt_kernel(
    const float* __restrict__ W, ushort* __restrict__ WTh,
    ushort* __restrict__ WTl, int K, int N)
{
    const int o = blockIdx.x * 256 + threadIdx.x;
    if (o < K * N) {
        const int n = o / K, k = o - n * K;
        const float x = W[(size_t)k * N + n];
        const ushort h = f2bf(x);
        WTh[o] = h;
        WTl[o] = f2bf(x - bf2f(h));
    }
}

__global__ __launch_bounds__(256) void split_pl_kernel(
    const float* __restrict__ X, ushort* __restrict__ Xh,
    ushort* __restrict__ Xl, int n)
{
    const int i = blockIdx.x * 256 + threadIdx.x;
    if (i < n) {
        const float x = X[i];
        const ushort h = f2bf(x);
        Xh[i] = h;
        Xl[i] = f2bf(x - bf2f(h));
    }
}

// ---------------------------------------------------------------------------
// LayerNorm rows of 512, f32 in / f32 out (x-path)
// ---------------------------------------------------------------------------
__global__ __launch_bounds__(256) void ln_kernel(
    const float* __restrict__ X, const float* __restrict__ g,
    const float* __restrict__ b, float* __restrict__ Y, int relu)
{
    const int lane = threadIdx.x & 63;
    const int row  = blockIdx.x * 4 + (threadIdx.x >> 6);
    const float* x = X + (size_t)row * ND;
    const int d = lane * 8;

    float4 v0 = *(const float4*)(x + d);
    float4 v1 = *(const float4*)(x + d + 4);
    float s = v0.x + v0.y + v0.z + v0.w + v1.x + v1.y + v1.z + v1.w;
    float q = v0.x*v0.x + v0.y*v0.y + v0.z*v0.z + v0.w*v0.w
            + v1.x*v1.x + v1.y*v1.y + v1.z*v1.z + v1.w*v1.w;
#pragma unroll
    for (int off = 32; off; off >>= 1) {
        s += __shfl_down(s, off);
        q += __shfl_down(q, off);
    }
    s = __shfl(s, 0); q = __shfl(q, 0);
    const float mean = s * (1.f / ND);
    const float var  = q * (1.f / ND) - mean * mean;
    const float rs   = rsqrtf(var + 1e-5f);

    float4 g0 = *(const float4*)(g + d);
    float4 g1 = *(const float4*)(g + d + 4);
    float4 b0 = *(const float4*)(b + d);
    float4 b1 = *(const float4*)(b + d + 4);
    float4 o0, o1;
    o0.x = (v0.x - mean) * rs * g0.x + b0.x;
    o0.y = (v0.y - mean) * rs * g0.y + b0.y;
    o0.z = (v0.z - mean) * rs * g0.z + b0.z;
    o0.w = (v0.w - mean) * rs * g0.w + b0.w;
    o1.x = (v1.x - mean) * rs * g1.x + b1.x;
    o1.y = (v1.y - mean) * rs * g1.y + b1.y;
    o1.z = (v1.z - mean) * rs * g1.z + b1.z;
    o1.w = (v1.w - mean) * rs * g1.w + b1.w;
    if (relu) {
        o0.x = fmaxf(o0.x, 0.f); o0.y = fmaxf(o0.y, 0.f);
        o0.z = fmaxf(o0.z, 0.f); o0.w = fmaxf(o0.w, 0.f);
        o1.x = fmaxf(o1.x, 0.f); o1.y = fmaxf(o1.y, 0.f);
        o1.z = fmaxf(o1.z, 0.f); o1.w = fmaxf(o1.w, 0.f);
    }
    float* y = Y + (size_t)row * ND;
    *(float4*)(y + d)     = o0;
    *(float4*)(y + d + 4) = o1;
}

// LayerNorm rows of 512, planes in / planes out (candidate encode)
__global__ __launch_bounds__(256) void ln_pl_kernel(
    const ushort* __restrict__ Xh, const ushort* __restrict__ Xl,
    const float* __restrict__ g, const float* __restrict__ b,
    ushort* __restrict__ Yh, ushort* __restrict__ Yl)
{
    const int lane = threadIdx.x & 63;
    const int row  = blockIdx.x * 4 + (threadIdx.x >> 6);
    const int d = lane * 8;
    const size_t base = (size_t)row * ND + d;

    short8 xh = *(const short8*)(Xh + base);
    short8 xl = *(const short8*)(Xl + base);
    float v[8];
#pragma unroll
    for (int i = 0; i < 8; i++) v[i] = bf2f((ushort)xh[i]) + bf2f((ushort)xl[i]);

    float s = 0.f, q = 0.f;
#pragma unroll
    for (int i = 0; i < 8; i++) { s += v[i]; q += v[i] * v[i]; }
#pragma unroll
    for (int off = 32; off; off >>= 1) {
        s += __shfl_down(s, off);
        q += __shfl_down(q, off);
    }
    s = __shfl(s, 0); q = __shfl(q, 0);
    const float mean = s * (1.f / ND);
    const float var  = q * (1.f / ND) - mean * mean;
    const float rs   = rsqrtf(var + 1e-5f);

    short8 yh, yl;
#pragma unroll
    for (int i = 0; i < 8; i++) {
        const float o = (v[i] - mean) * rs * g[d + i] + b[d + i];
        const ushort h = f2bf(o);
        yh[i] = (short)h;
        yl[i] = (short)f2bf(o - bf2f(h));
    }
    *(short8*)(Yh + base) = yh;
    *(short8*)(Yl + base) = yl;
}

__global__ __launch_bounds__(256) void sqnorm_pl_kernel(
    const ushort* __restrict__ Xh, const ushort* __restrict__ Xl,
    float* __restrict__ sq)
{
    const int lane = threadIdx.x & 63;
    const int row  = blockIdx.x * 4 + (threadIdx.x >> 6);
    const size_t base = (size_t)row * ND + lane * 8;
    short8 xh = *(const short8*)(Xh + base);
    short8 xl = *(const short8*)(Xl + base);
    float q = 0.f;
#pragma unroll
    for (int i = 0; i < 8; i++) {
        float v = bf2f((ushort)xh[i]) + bf2f((ushort)xl[i]);
        q += v * v;
    }
#pragma unroll
    for (int off = 32; off; off >>= 1) q += __shfl_down(q, off);
    if (lane == 0) sq[row] = q;
}

// ---------------------------------------------------------------------------
// Two-stage exact top-96, register-resident keys + wave match-any histogram
// (9 ballots emulate match_any over bin|valid; 1 atomic per distinct bin per
//  wave step -> immune to concentrated score distributions)
// ---------------------------------------------------------------------------
__device__ __forceinline__ unsigned fkey(float f)
{
    unsigned u = __float_as_uint(f);
    return (u & 0x80000000u) ? ~u : (u | 0x80000000u);
}
__device__ __forceinline__ float inv_fkey(unsigned u)
{
    return __uint_as_float((u & 0x80000000u) ? (u & 0x7FFFFFFFu) : ~u);
}

__device__ __forceinline__ void hist_add_matchany(
    unsigned bin9, bool valid, int lane, unsigned* hist)
{
    unsigned long long mask = ~0ull;
#pragma unroll
    for (int bit = 0; bit < 9; bit++) {
        const unsigned long long vote = __ballot((bin9 >> bit) & 1u);
        mask &= ((bin9 >> bit) & 1u) ? vote : ~vote;
    }
    const int leader = __ffsll((unsigned long long)mask) - 1;
    if (valid && lane == leader)
        atomicAdd(&hist[bin9], (unsigned)__popcll(mask));
}

// Stage 1: per-(row, 4096-segment) exact top-96 -> candidate buffer
__global__ __launch_bounds__(256) void topk_seg(
    const float* __restrict__ S, unsigned* __restrict__ K1key,
    int* __restrict__ K1idx)
{
    const int r = blockIdx.y, seg = blockIdx.x;
    const float* p = S + (size_t)r * NN + seg * TK_SEG;
    __shared__ unsigned hist[256];
    __shared__ unsigned scan[256];
    __shared__ unsigned sh_pref;
    __shared__ int sh_krem, cA, cB;
    const int tid = threadIdx.x;
    const int lane = tid & 63;

    unsigned key[16];                     // 4096 keys, 16/thread, coalesced
#pragma unroll
    for (int j = 0; j < 16; j++) key[j] = fkey(p[tid + j * 256]);

    hist[tid] = 0u;
    if (tid == 0) { sh_pref = 0u; sh_krem = NC; cA = 0; cB = 0; }
    __syncthreads();

    for (int level = 0; level < 4; level++) {
        const int shift = 24 - 8 * level;
        const unsigned pref  = sh_pref;        // read before any write below
        const int krem       = sh_krem;
        const unsigned pmask = level ? (0xFFFFFFFFu << (shift + 8)) : 0u;
#pragma unroll
        for (int j = 0; j < 16; j++) {
            const unsigned u = key[j];
            const bool valid = (u & pmask) == pref;
            const unsigned bin = valid ? ((u >> shift) & 255u) : 0x100u;
            hist_add_matchany(bin, valid, lane, hist);
        }
        __syncthreads();
        const unsigned c = hist[tid];
        scan[tid] = c;
        __syncthreads();
        for (int o2 = 1; o2 < 256; o2 <<= 1) {   // Hillis-Steele inclusive
            const unsigned v = (tid >= o2) ? scan[tid - o2] : 0u;
            __syncthreads();
            scan[tid] += v;
            __syncthreads();
        }
        const int incl = (int)scan[tid];
        const int excl = incl - (int)c;
        if (excl < krem && incl >= krem) {       // exactly one tid
            sh_pref = pref | ((unsigned)tid << shift);
            sh_krem = krem - excl;
        }
        hist[tid] = 0u;
        __syncthreads();
    }

    const unsigned T = sh_pref;
    const int need = sh_krem;
    const int cntLess = NC - need;
    const size_t obase = ((size_t)r * TK_SPLIT + seg) * NC;
#pragma unroll
    for (int j = 0; j < 16; j++) {
        const unsigned u = key[j];
        if (u < T) {
            const int pos = atomicAdd(&cA, 1);
            K1key[obase + pos] = u;
            K1idx[obase + pos] = seg * TK_SEG + tid + j * 256;
        } else if (u == T) {
            const int pos = atomicAdd(&cB, 1);
            if (pos < need) {
                K1key[obase + cntLess + pos] = u;
                K1idx[obase + cntLess + pos] = seg * TK_SEG + tid + j * 256;
            }
        }
    }
}

// Stage 2: per-row exact top-96 of the 1536 stage-1 survivors
__global__ __launch_bounds__(256) void topk_merge(
    const unsigned* __restrict__ K1key, const int* __restrict__ K1idx,
    int* __restrict__ idx_out, float* __restrict__ val_out, int b0)
{
    const int r = blockIdx.x;
    const int b = b0 + r;
    __shared__ unsigned hist[256];
    __shared__ unsigned scan[256];
    __shared__ unsigned sh_pref;
    __shared__ int sh_krem, cA, cB;
    const int tid = threadIdx.x;
    const int lane = tid & 63;
    const size_t ibase = (size_t)r * TK_CAND;

    unsigned key[6];
    int      kidx[6];
#pragma unroll
    for (int j = 0; j < 6; j++) {
        key[j]  = K1key[ibase + tid + j * 256];
        kidx[j] = K1idx[ibase + tid + j * 256];
    }

    hist[tid] = 0u;
    if (tid == 0) { sh_pref = 0u; sh_krem = NC; cA = 0; cB = 0; }
    __syncthreads();

    for (int level = 0; level < 4; level++) {
        const int shift = 24 - 8 * level;
        const unsigned pref  = sh_pref;
        const int krem       = sh_krem;
        const unsigned pmask = level ? (0xFFFFFFFFu << (shift + 8)) : 0u;
#pragma unroll
        for (int j = 0; j < 6; j++) {
            const unsigned u = key[j];
            const bool valid = (u & pmask) == pref;
            const unsigned bin = valid ? ((u >> shift) & 255u) : 0x100u;
            hist_add_matchany(bin, valid, lane, hist);
        }
        __syncthreads();
        const unsigned c = hist[tid];
        scan[tid] = c;
        __syncthreads();
        for (int o2 = 1; o2 < 256; o2 <<= 1) {
            const unsigned v = (tid >= o2) ? scan[tid - o2] : 0u;
            __syncthreads();
            scan[tid] += v;
            __syncthreads();
        }
        const int incl = (int)scan[tid];
        const int excl = incl - (int)c;
        if (excl < krem && incl >= krem) {
            sh_pref = pref | ((unsigned)tid << shift);
            sh_krem = krem - excl;
        }
        hist[tid] = 0u;
        __syncthreads();
    }

    const unsigned T = sh_pref;
    const int need = sh_krem;
    const int cntLess = NC - need;
#pragma unroll
    for (int j = 0; j < 6; j++) {
        const unsigned u = key[j];
        if (u < T) {
            const int pos = atomicAdd(&cA, 1);
            idx_out[b * NC + pos] = kidx[j];
            val_out[b * NC + pos] = inv_fkey(u);
        } else if (u == T) {
            const int pos = atomicAdd(&cB, 1);
            if (pos < need) {
                idx_out[b * NC + cntLess + pos] = kidx[j];
                val_out[b * NC + cntLess + pos] = inv_fkey(u);
            }
        }
    }
}

// ---------------------------------------------------------------------------
__global__ __launch_bounds__(128) void probs_kernel(
    const float* __restrict__ svals, float* __restrict__ probs)
{
    const int b = blockIdx.x;
    const int tid = threadIdx.x;
    __shared__ float red[128];
    const bool valid = tid < NC;
    float s = valid ? -svals[b * NC + tid] : -3.4e38f;
    red[tid] = s;
    __syncthreads();
#pragma unroll
    for (int off = 64; off; off >>= 1) {
        if (tid < off) red[tid] = fmaxf(red[tid], red[tid + off]);
        __syncthreads();
    }
    const float m = red[0];
    __syncthreads();
    float e = valid ? expf(s - m) : 0.f;
    red[tid] = e;
    __syncthreads();
#pragma unroll
    for (int off = 64; off; off >>= 1) {
        if (tid < off) red[tid] += red[tid + off];
        __syncthreads();
    }
    const float sum = red[0];
    if (valid) probs[b * NC + tid] = e / sum;
}

__global__ __launch_bounds__(256) void ctx_kernel(
    const float* __restrict__ VAL, const float* __restrict__ probs,
    const float* __restrict__ cand_y, const int* __restrict__ idx,
    const float* __restrict__ labW, const float* __restrict__ labb,
    const float* __restrict__ xin, float* __restrict__ xout, int b0)
{
    const int b_loc = blockIdx.x;
    const int b = b0 + b_loc;
    const int tid = threadIdx.x;
    __shared__ float pv[NC];
    __shared__ float red[256];
    float py_part = 0.f;
    if (tid < NC) {
        float p = probs[b * NC + tid];
        pv[tid] = p;
        py_part = p * cand_y[idx[b * NC + tid]];
    }
    red[tid] = py_part;
    __syncthreads();
#pragma unroll
    for (int off = 128; off; off >>= 1) {
        if (tid < off) red[tid] += red[tid + off];
        __syncthreads();
    }
    const float py = red[0];

    for (int d = tid; d < ND; d += 256) {
        const float* vp = VAL + (size_t)b_loc * NC * ND + d;
        float acc = 0.f;
#pragma unroll 8
        for (int c = 0; c < NC; c++) acc += pv[c] * vp[(size_t)c * ND];
        float ctx = acc + py * labW[d] + labb[d];
        xout[(size_t)b * ND + d] = xin[(size_t)b * ND + d] + ctx;
    }
}

__global__ __launch_bounds__(64) void head_kernel(
    const float* __restrict__ X, const float* __restrict__ hW,
    const float* __restrict__ hb, float* __restrict__ out)
{
    const int b = blockIdx.x;
    const int lane = threadIdx.x;
    const float* x = X + (size_t)b * ND;
    float acc = 0.f;
#pragma unroll
    for (int j = 0; j < 8; j++) {
        int d = lane + 64 * j;
        acc += x[d] * hW[d];
    }
#pragma unroll
    for (int off = 32; off; off >>= 1) acc += __shfl_down(acc, off);
    if (lane == 0) out[b] = acc + hb[0];
}

// ---------------------------------------------------------------------------
extern "C" void kernel_launch(void* const* d_in, const int* in_sizes, int n_in,
                              void* d_out, int out_size, void* d_ws, size_t ws_size,
                              hipStream_t stream)
{
    const float* x_num    = (const float*)d_in[0];
    const float* cand_num = (const float*)d_in[1];
    const float* cand_y   = (const float*)d_in[2];
    const float* lin_W    = (const float*)d_in[3];
    const float* lin_b    = (const float*)d_in[4];
    const float* e_W1     = (const float*)d_in[5];
    const float* e_b1     = (const float*)d_in[6];
    const float* e_W2     = (const float*)d_in[7];
    const float* e_b2     = (const float*)d_in[8];
    const float* mix_g    = (const float*)d_in[9];
    const float* mix_b    = (const float*)d_in[10];
    const float* K_W      = (const float*)d_in[11];
    const float* K_b      = (const float*)d_in[12];
    const float* lab_W    = (const float*)d_in[13];
    const float* lab_b    = (const float*)d_in[14];
    const float* T_W1     = (const float*)d_in[15];
    const float* T_b1     = (const float*)d_in[16];
    const float* T_W2     = (const float*)d_in[17];
    const float* p_ln_g   = (const float*)d_in[18];
    const float* p_ln_b   = (const float*)d_in[19];
    const float* p_W1     = (const float*)d_in[20];
    const float* p_b1     = (const float*)d_in[21];
    const float* p_W2     = (const float*)d_in[22];
    const float* p_b2     = (const float*)d_in[23];
    const float* h_ln_g   = (const float*)d_in[24];
    const float* h_ln_b   = (const float*)d_in[25];
    const float* h_W      = (const float*)d_in[26];
    const float* h_b      = (const float*)d_in[27];
    float* out = (float*)d_out;
    (void)in_sizes; (void)n_in; (void)out_size; (void)ws_size;

    // ---- workspace layout (~253 MB) ----
    size_t off = 0;
    auto ralloc = [&](size_t bytes) -> void* {
        void* p = (char*)d_ws + off;
        off += (bytes + 255) & ~(size_t)255;
        return p;
    };
    auto falloc = [&](size_t n) -> float*  { return (float*)ralloc(n * 4); };
    auto ualloc = [&](size_t n) -> ushort* { return (ushort*)ralloc(n * 2); };

    float* WT_lin = falloc((size_t)ND * NF);
    float* WT_e1  = falloc((size_t)NDB * ND);
    float* WT_e2  = falloc((size_t)ND * NDB);
    float* WT_kw  = falloc((size_t)ND * ND);
    float* WT_p1  = falloc((size_t)NDB * ND);
    float* WT_p2  = falloc((size_t)ND * NDB);
    ushort* WP_lin_h = ualloc((size_t)ND * NF);
    ushort* WP_lin_l = ualloc((size_t)ND * NF);
    ushort* WP_e1_h  = ualloc((size_t)NDB * ND);
    ushort* WP_e1_l  = ualloc((size_t)NDB * ND);
    ushort* WP_e2_h  = ualloc((size_t)ND * NDB);
    ushort* WP_e2_l  = ualloc((size_t)ND * NDB);
    ushort* WP_kw_h  = ualloc((size_t)ND * ND);
    ushort* WP_kw_l  = ualloc((size_t)ND * ND);
    ushort* WP_t1_h  = ualloc((size_t)NDB * ND);
    ushort* WP_t1_l  = ualloc((size_t)NDB * ND);
    ushort* WP_t2_h  = ualloc((size_t)ND * NDB);
    ushort* WP_t2_l  = ualloc((size_t)ND * NDB);

    ushort* R_CKh = ualloc((size_t)NN * ND);
    ushort* R_CKl = ualloc((size_t)NN * ND);
    float*  R_sq  = falloc(NN);
    float*  R_Hx  = falloc((size_t)NB * ND);
    float*  R_Tx  = falloc((size_t)NB * NDB);
    float*  R_Gx  = falloc((size_t)NB * ND);
    float*  R_kx  = falloc((size_t)NB * ND);
    ushort* R_kxh = ualloc((size_t)NB * ND);
    ushort* R_kxl = ualloc((size_t)NB * ND);
    int*    R_idx = (int*)ralloc((size_t)NB * NC * 4);
    float*  R_ssel= falloc((size_t)NB * NC);
    float*  R_prob= falloc((size_t)NB * NC);
    float*  R_xupd= falloc((size_t)NB * ND);
    float*  R_lnx = falloc((size_t)NB * ND);
    float*  R_tp  = falloc((size_t)NB * NDB);
    float*  R_x2  = falloc((size_t)NB * ND);
    float*  R_lnx2= falloc((size_t)NB * ND);
    unsigned* K1key = (unsigned*)ralloc((size_t)BB_C * TK_CAND * 4);
    int*      K1idx = (int*)ralloc((size_t)BB_C * TK_CAND * 4);
    char* SCR = (char*)ralloc((size_t)70 * 1024 * 1024);

    // ---- 0. weight prep ----
    auto tr = [&](const float* W, float* WT, int K, int N) {
        transpose_kernel<<<dim3((K * N + 255) / 256), dim3(256), 0, stream>>>(W, WT, K, N);
    };
    auto sw = [&](const float* W, ushort* WTh, ushort* WTl, int K, int N) {
        split_wt_kernel<<<dim3((K * N + 255) / 256), dim3(256), 0, stream>>>(W, WTh, WTl, K, N);
    };
    tr(lin_W, WT_lin, NF, ND);
    tr(e_W1,  WT_e1,  ND, NDB);
    tr(e_W2,  WT_e2,  NDB, ND);
    tr(K_W,   WT_kw,  ND, ND);
    tr(p_W1,  WT_p1,  ND, NDB);
    tr(p_W2,  WT_p2,  NDB, ND);
    sw(lin_W, WP_lin_h, WP_lin_l, NF, ND);
    sw(e_W1,  WP_e1_h,  WP_e1_l,  ND, NDB);
    sw(e_W2,  WP_e2_h,  WP_e2_l,  NDB, ND);
    sw(K_W,   WP_kw_h,  WP_kw_l,  ND, ND);
    sw(T_W1,  WP_t1_h,  WP_t1_l,  ND, NDB);
    sw(T_W2,  WP_t2_h,  WP_t2_l,  NDB, ND);

    auto gss = [&](const ushort* Ah, const ushort* Al, const ushort* Bh,
                   const ushort* Bl, const float* bias, const ushort* resh,
                   const ushort* resl, const float* sq, float* Sf,
                   ushort* Ch, ushort* Cl, int M, int Nn, int K, int relu) {
        gemm_ss<<<dim3(Nn / 128, M / 128), dim3(256), 0, stream>>>(
            Ah, Al, Bh, Bl, bias, resh, resl, sq, Sf, Ch, Cl, M, Nn, K, relu);
    };
    auto gsplit = [&](const float* A, const float* BT, const float* bias,
                      const float* res, float* C, int M, int Nn, int K, int relu) {
        gemm_split_nt<<<dim3(Nn / 128, M / 128), dim3(256), 0, stream>>>(
            A, BT, bias, res, C, M, Nn, K, relu);
    };

    // ---- 1. candidate encode (chunked; plane operands, split-bf16 MFMA) ----
    {
        ushort* CNh = (ushort*)SCR;
        ushort* CNl = CNh + (size_t)CH_A * NF;
        ushort* Hh  = CNl + (size_t)CH_A * NF;
        ushort* Hl  = Hh  + (size_t)CH_A * ND;
        ushort* Th  = Hl  + (size_t)CH_A * ND;
        ushort* Tl  = Th  + (size_t)CH_A * NDB;
        ushort* H2h = Tl  + (size_t)CH_A * NDB;
        ushort* H2l = H2h + (size_t)CH_A * ND;
        ushort* Gh  = Th;   // overlay: T dead after e2
        ushort* Gl  = Tl;

        for (int n0 = 0; n0 < NN; n0 += CH_A) {
            split_pl_kernel<<<dim3((CH_A * NF + 255) / 256), dim3(256), 0, stream>>>(
                cand_num + (size_t)n0 * NF, CNh, CNl, CH_A * NF);
            gss(CNh, CNl, WP_lin_h, WP_lin_l, lin_b, nullptr, nullptr, nullptr,
                nullptr, Hh, Hl, CH_A, ND, NF, 0);
            gss(Hh, Hl, WP_e1_h, WP_e1_l, e_b1, nullptr, nullptr, nullptr,
                nullptr, Th, Tl, CH_A, NDB, ND, 1);
            gss(Th, Tl, WP_e2_h, WP_e2_l, e_b2, Hh, Hl, nullptr,
                nullptr, H2h, H2l, CH_A, ND, NDB, 0);
            ln_pl_kernel<<<dim3(CH_A / 4), dim3(256), 0, stream>>>(
                H2h, H2l, mix_g, mix_b, Gh, Gl);
            gss(Gh, Gl, WP_kw_h, WP_kw_l, K_b, nullptr, nullptr, nullptr,
                nullptr, R_CKh + (size_t)n0 * ND, R_CKl + (size_t)n0 * ND,
                CH_A, ND, ND, 0);
            sqnorm_pl_kernel<<<dim3(CH_A / 4), dim3(256), 0, stream>>>(
                R_CKh + (size_t)n0 * ND, R_CKl + (size_t)n0 * ND, R_sq + n0);
        }
    }

    // ---- 2. x encode (f32-operand split kernel; small) ----
    gsplit(x_num, WT_lin, lin_b, nullptr, R_Hx, NB, ND, NF, 0);
    gsplit(R_Hx, WT_e1, e_b1, nullptr, R_Tx, NB, NDB, ND, 1);
    gsplit(R_Tx, WT_e2, e_b2, R_Hx, R_Hx, NB, ND, NDB, 0);
    ln_kernel<<<dim3(NB / 4), dim3(256), 0, stream>>>(R_Hx, mix_g, mix_b, R_Gx, 0);
    gsplit(R_Gx, WT_kw, K_b, nullptr, R_kx, NB, ND, ND, 0);
    split_pl_kernel<<<dim3((NB * ND + 255) / 256), dim3(256), 0, stream>>>(
        R_kx, R_kxh, R_kxl, NB * ND);

    // ---- 3. scores + two-stage top-96 + softmax ----
    for (int b0 = 0; b0 < NB; b0 += BB_C) {
        float* S = (float*)SCR;
        gss(R_kxh + (size_t)b0 * ND, R_kxl + (size_t)b0 * ND, R_CKh, R_CKl,
            nullptr, nullptr, nullptr, R_sq, S, nullptr, nullptr,
            BB_C, NN, ND, 0);
        topk_seg<<<dim3(TK_SPLIT, BB_C), dim3(256), 0, stream>>>(S, K1key, K1idx);
        topk_merge<<<dim3(BB_C), dim3(256), 0, stream>>>(K1key, K1idx,
                                                         R_idx, R_ssel, b0);
    }
    probs_kernel<<<dim3(NB), dim3(128), 0, stream>>>(R_ssel, R_prob);

    // ---- 4. values path (plain bf16 MFMA, diff fused) ----
    for (int b0 = 0; b0 < NB; b0 += BB_D) {
        ushort* TT = (ushort*)SCR;                                  // [M,1024] bf16
        float* VAL = (float*)(SCR + (size_t)BB_D * NC * NDB * 2);   // f32 after TT
        const int M = BB_D * NC;   // 12288
        gemm_diff_bf16<<<dim3(NDB / 128, M / 128), dim3(256), 0, stream>>>(
            R_kx + (size_t)b0 * ND, R_CKh, R_CKl, R_idx + b0 * NC,
            WP_t1_h, T_b1, TT, M, NDB, ND);
        gemm_bf16_f32<<<dim3(ND / 128, M / 128), dim3(256), 0, stream>>>(
            TT, WP_t2_h, VAL, M, ND, NDB);
        ctx_kernel<<<dim3(BB_D), dim3(256), 0, stream>>>(
            VAL, R_prob, cand_y, R_idx, lab_W, lab_b, R_Hx, R_xupd, b0);
    }

    // ---- 5. predictor block + head ----
    ln_kernel<<<dim3(NB / 4), dim3(256), 0, stream>>>(R_xupd, p_ln_g, p_ln_b, R_lnx, 0);
    gsplit(R_lnx, WT_p1, p_b1, nullptr, R_tp, NB, NDB, ND, 1);
    gsplit(R_tp, WT_p2, p_b2, R_xupd, R_x2, NB, ND, NDB, 0);
    ln_kernel<<<dim3(NB / 4), dim3(256), 0, stream>>>(R_x2, h_ln_g, h_ln_b, R_lnx2, 1);
    head_kernel<<<dim3(NB), dim3(64), 0, stream>>>(R_lnx2, h_W, h_b, out);
}

// Round 8
// 3237.271 us; speedup vs baseline: 1.2127x; 1.1027x over previous
//
#include <hip/hip_runtime.h>

// Problem constants
#define NB   1024
#define NN   65536
#define NF   64
#define ND   512
#define NDB  1024
#define NC   96

// Chunking
#define CH_A 8192      // candidate-encode chunk rows
#define BB_C 256       // scores/topk chunk of B rows
#define BB_D 128       // values-path chunk of B rows

// top-k segmentation
#define TK_SPLIT 16
#define TK_SEG   (NN / TK_SPLIT)   // 4096
#define TK_CAND  (TK_SPLIT * NC)   // 1536

typedef unsigned short ushort;
typedef __attribute__((ext_vector_type(8))) short short8;
typedef __attribute__((ext_vector_type(4))) float floatx4;

__device__ __forceinline__ ushort f2bf(float f) {   // RNE f32->bf16
    unsigned u = __float_as_uint(f);
    u += 0x7fffu + ((u >> 16) & 1u);
    return (ushort)(u >> 16);
}
__device__ __forceinline__ float bf2f(ushort h) {
    return __uint_as_float(((unsigned)h) << 16);
}
// LDS plane: [m][k] bf16, k-stride 32, 16B-chunk XOR swizzle -> conflict-free
__device__ __forceinline__ int lds_off(int m, int c) {
    return m * 32 + (((c + (m >> 1)) & 3) << 3);
}

// ---------------------------------------------------------------------------
// Split-plane MFMA GEMM (f32-emulating, 3 MFMA), NT:
//   acc = A @ B^T  with A=(Ah,Al)[M][K], B=(Bh,Bl)[N][K] bf16 planes.
// Epilogue: scoresq ? Sf = scoresq[n]-2*acc : v=acc+bias(+res)(relu) -> planes
// ---------------------------------------------------------------------------
__global__ __launch_bounds__(256) void gemm_ss(
    const ushort* __restrict__ Ah_g, const ushort* __restrict__ Al_g,
    const ushort* __restrict__ Bh_g, const ushort* __restrict__ Bl_g,
    const float* __restrict__ bias,
    const ushort* __restrict__ resh, const ushort* __restrict__ resl,
    const float* __restrict__ scoresq, float* __restrict__ Sf,
    ushort* __restrict__ Ch, ushort* __restrict__ Cl,
    int M, int N, int K, int relu)
{
    __shared__ ushort Ah[128 * 32], Al[128 * 32];
    __shared__ ushort Bh[128 * 32], Bl[128 * 32];
    const int tid = threadIdx.x;
    const int lane = tid & 63, wid = tid >> 6;
    const int wm = (wid & 1) * 64, wn = (wid >> 1) * 64;
    const int lane15 = lane & 15, quad = lane >> 4;
    const int row0 = blockIdx.y * 128, col0 = blockIdx.x * 128;
    const int sm = tid >> 1, scp = (tid & 1) * 2;

    const ushort* arh = Ah_g + (size_t)(row0 + sm) * K + scp * 8;
    const ushort* arl = Al_g + (size_t)(row0 + sm) * K + scp * 8;
    const ushort* brh = Bh_g + (size_t)(col0 + sm) * K + scp * 8;
    const ushort* brl = Bl_g + (size_t)(col0 + sm) * K + scp * 8;

    floatx4 acc[4][4];
#pragma unroll
    for (int i = 0; i < 4; i++)
#pragma unroll
        for (int j = 0; j < 4; j++) acc[i][j] = (floatx4){0.f, 0.f, 0.f, 0.f};

    for (int k0 = 0; k0 < K; k0 += 32) {
        short8 a0 = *(const short8*)(arh + k0);
        short8 a1 = *(const short8*)(arh + k0 + 8);
        short8 a2 = *(const short8*)(arl + k0);
        short8 a3 = *(const short8*)(arl + k0 + 8);
        short8 b0 = *(const short8*)(brh + k0);
        short8 b1 = *(const short8*)(brh + k0 + 8);
        short8 b2 = *(const short8*)(brl + k0);
        short8 b3 = *(const short8*)(brl + k0 + 8);
        __syncthreads();
        *(short8*)(Ah + lds_off(sm, scp))     = a0;
        *(short8*)(Ah + lds_off(sm, scp + 1)) = a1;
        *(short8*)(Al + lds_off(sm, scp))     = a2;
        *(short8*)(Al + lds_off(sm, scp + 1)) = a3;
        *(short8*)(Bh + lds_off(sm, scp))     = b0;
        *(short8*)(Bh + lds_off(sm, scp + 1)) = b1;
        *(short8*)(Bl + lds_off(sm, scp))     = b2;
        *(short8*)(Bl + lds_off(sm, scp + 1)) = b3;
        __syncthreads();

        short8 ah[4], al[4], bh[4], bl[4];
#pragma unroll
        for (int t = 0; t < 4; t++) {
            const int am = wm + t * 16 + lane15;
            const int bn = wn + t * 16 + lane15;
            ah[t] = *(const short8*)(Ah + lds_off(am, quad));
            al[t] = *(const short8*)(Al + lds_off(am, quad));
            bh[t] = *(const short8*)(Bh + lds_off(bn, quad));
            bl[t] = *(const short8*)(Bl + lds_off(bn, quad));
        }
#pragma unroll
        for (int i = 0; i < 4; i++)
#pragma unroll
            for (int j = 0; j < 4; j++) {
                acc[i][j] = __builtin_amdgcn_mfma_f32_16x16x32_bf16(ah[i], bh[j], acc[i][j], 0, 0, 0);
                acc[i][j] = __builtin_amdgcn_mfma_f32_16x16x32_bf16(ah[i], bl[j], acc[i][j], 0, 0, 0);
                acc[i][j] = __builtin_amdgcn_mfma_f32_16x16x32_bf16(al[i], bh[j], acc[i][j], 0, 0, 0);
            }
    }

    // C/D layout: col=lane&15, row=quad*4+reg  [m89]
#pragma unroll
    for (int i = 0; i < 4; i++)
#pragma unroll
        for (int j = 0; j < 4; j++) {
            const int gc = col0 + wn + j * 16 + lane15;
            const int rb = row0 + wm + i * 16 + quad * 4;
            const float bv = bias ? bias[gc] : 0.f;
            const float sv = scoresq ? scoresq[gc] : 0.f;
#pragma unroll
            for (int r = 0; r < 4; r++) {
                const size_t o = (size_t)(rb + r) * N + gc;
                float v = acc[i][j][r];
                if (scoresq) {
                    Sf[o] = sv - 2.f * v;
                } else {
                    v += bv;
                    if (resh) v += bf2f(resh[o]) + bf2f(resl[o]);
                    if (relu) v = fmaxf(v, 0.f);
                    ushort h = f2bf(v);
                    Ch[o] = h;
                    Cl[o] = f2bf(v - bf2f(h));
                }
            }
        }
}

// ---------------------------------------------------------------------------
// Split-bf16 GEMM with f32 operands (x-path / predictor; small M)
// ---------------------------------------------------------------------------
__device__ __forceinline__ void load16(const float* p, float* x) {
    *(float4*)(x)      = *(const float4*)(p);
    *(float4*)(x + 4)  = *(const float4*)(p + 4);
    *(float4*)(x + 8)  = *(const float4*)(p + 8);
    *(float4*)(x + 12) = *(const float4*)(p + 12);
}
__device__ __forceinline__ void write_split(const float* x, ushort* Ph,
                                            ushort* Pl, int m, int cp) {
    short8 h0, h1, l0, l1;
#pragma unroll
    for (int i = 0; i < 8; i++) {
        ushort h = f2bf(x[i]);
        h0[i] = (short)h;
        l0[i] = (short)f2bf(x[i] - bf2f(h));
        ushort g = f2bf(x[i + 8]);
        h1[i] = (short)g;
        l1[i] = (short)f2bf(x[i + 8] - bf2f(g));
    }
    *(short8*)(Ph + lds_off(m, cp))     = h0;
    *(short8*)(Ph + lds_off(m, cp + 1)) = h1;
    *(short8*)(Pl + lds_off(m, cp))     = l0;
    *(short8*)(Pl + lds_off(m, cp + 1)) = l1;
}

__global__ __launch_bounds__(256) void gemm_split_nt(
    const float* __restrict__ A, const float* __restrict__ BT,
    const float* __restrict__ bias, const float* res,
    float* C, int M, int N, int K, int relu)
{
    __shared__ ushort Ah[128 * 32], Al[128 * 32];
    __shared__ ushort Bh[128 * 32], Bl[128 * 32];
    const int tid = threadIdx.x;
    const int lane = tid & 63, wid = tid >> 6;
    const int wm = (wid & 1) * 64, wn = (wid >> 1) * 64;
    const int lane15 = lane & 15, quad = lane >> 4;
    const int row0 = blockIdx.y * 128, col0 = blockIdx.x * 128;
    const int sm = tid >> 1, scp = (tid & 1) * 2;

    const float* arow = A + (size_t)(row0 + sm) * K + scp * 8;
    const float* brow = BT + (size_t)(col0 + sm) * K + scp * 8;

    floatx4 acc[4][4];
#pragma unroll
    for (int i = 0; i < 4; i++)
#pragma unroll
        for (int j = 0; j < 4; j++) acc[i][j] = (floatx4){0.f, 0.f, 0.f, 0.f};

    for (int k0 = 0; k0 < K; k0 += 32) {
        float xa[16], xb[16];
        load16(arow + k0, xa);
        load16(brow + k0, xb);
        __syncthreads();
        write_split(xa, Ah, Al, sm, scp);
        write_split(xb, Bh, Bl, sm, scp);
        __syncthreads();

        short8 ah[4], al[4], bh[4], bl[4];
#pragma unroll
        for (int t = 0; t < 4; t++) {
            const int am = wm + t * 16 + lane15;
            const int bn = wn + t * 16 + lane15;
            ah[t] = *(const short8*)(Ah + lds_off(am, quad));
            al[t] = *(const short8*)(Al + lds_off(am, quad));
            bh[t] = *(const short8*)(Bh + lds_off(bn, quad));
            bl[t] = *(const short8*)(Bl + lds_off(bn, quad));
        }
#pragma unroll
        for (int i = 0; i < 4; i++)
#pragma unroll
            for (int j = 0; j < 4; j++) {
                acc[i][j] = __builtin_amdgcn_mfma_f32_16x16x32_bf16(ah[i], bh[j], acc[i][j], 0, 0, 0);
                acc[i][j] = __builtin_amdgcn_mfma_f32_16x16x32_bf16(ah[i], bl[j], acc[i][j], 0, 0, 0);
                acc[i][j] = __builtin_amdgcn_mfma_f32_16x16x32_bf16(al[i], bh[j], acc[i][j], 0, 0, 0);
            }
    }

#pragma unroll
    for (int i = 0; i < 4; i++)
#pragma unroll
        for (int j = 0; j < 4; j++) {
            const int gc = col0 + wn + j * 16 + lane15;
            const int rb = row0 + wm + i * 16 + quad * 4;
            const float bv = bias ? bias[gc] : 0.f;
#pragma unroll
            for (int r = 0; r < 4; r++) {
                const size_t o = (size_t)(rb + r) * N + gc;
                float v = acc[i][j][r] + bv;
                if (res) v += res[o];
                if (relu) v = fmaxf(v, 0.f);
                C[o] = v;
            }
        }
}

// ---------------------------------------------------------------------------
// Values MLP layer 1: A row r = kx[r/96,:](f32) - ck[idx[r],:](planes)
// B = t1 hi plane. TT = bf16(relu(A @ B^T + bias))
// ---------------------------------------------------------------------------
__global__ __launch_bounds__(256) void gemm_diff_bf16(
    const float* __restrict__ kx,
    const ushort* __restrict__ ckh, const ushort* __restrict__ ckl,
    const int* __restrict__ idx, const ushort* __restrict__ BTh,
    const float* __restrict__ bias, ushort* __restrict__ TT,
    int M, int N, int K)
{
    __shared__ ushort Ah[128 * 32];
    __shared__ ushort Bh[128 * 32];
    const int tid = threadIdx.x;
    const int lane = tid & 63, wid = tid >> 6;
    const int wm = (wid & 1) * 64, wn = (wid >> 1) * 64;
    const int lane15 = lane & 15, quad = lane >> 4;
    const int row0 = blockIdx.y * 128, col0 = blockIdx.x * 128;
    const int sm = tid >> 1, scp = (tid & 1) * 2;

    const int r = row0 + sm;
    const int bidx = r / NC;
    const float*  kxp = kx  + (size_t)bidx * ND + scp * 8;
    const ushort* chp = ckh + (size_t)idx[r] * ND + scp * 8;
    const ushort* clp = ckl + (size_t)idx[r] * ND + scp * 8;
    const ushort* brh = BTh + (size_t)(col0 + sm) * K + scp * 8;

    floatx4 acc[4][4];
#pragma unroll
    for (int i = 0; i < 4; i++)
#pragma unroll
        for (int j = 0; j < 4; j++) acc[i][j] = (floatx4){0.f, 0.f, 0.f, 0.f};

    for (int k0 = 0; k0 < K; k0 += 32) {
        float xa[16];
        load16(kxp + k0, xa);
        short8 h0 = *(const short8*)(chp + k0);
        short8 h1 = *(const short8*)(chp + k0 + 8);
        short8 l0 = *(const short8*)(clp + k0);
        short8 l1 = *(const short8*)(clp + k0 + 8);
        short8 b0 = *(const short8*)(brh + k0);
        short8 b1 = *(const short8*)(brh + k0 + 8);
        short8 d0, d1;
#pragma unroll
        for (int i = 0; i < 8; i++) {
            float c0 = bf2f((ushort)h0[i]) + bf2f((ushort)l0[i]);
            float c1 = bf2f((ushort)h1[i]) + bf2f((ushort)l1[i]);
            d0[i] = (short)f2bf(xa[i] - c0);
            d1[i] = (short)f2bf(xa[i + 8] - c1);
        }
        __syncthreads();
        *(short8*)(Ah + lds_off(sm, scp))     = d0;
        *(short8*)(Ah + lds_off(sm, scp + 1)) = d1;
        *(short8*)(Bh + lds_off(sm, scp))     = b0;
        *(short8*)(Bh + lds_off(sm, scp + 1)) = b1;
        __syncthreads();

        short8 ah[4], bh[4];
#pragma unroll
        for (int t = 0; t < 4; t++) {
            ah[t] = *(const short8*)(Ah + lds_off(wm + t * 16 + lane15, quad));
            bh[t] = *(const short8*)(Bh + lds_off(wn + t * 16 + lane15, quad));
        }
#pragma unroll
        for (int i = 0; i < 4; i++)
#pragma unroll
            for (int j = 0; j < 4; j++)
                acc[i][j] = __builtin_amdgcn_mfma_f32_16x16x32_bf16(ah[i], bh[j], acc[i][j], 0, 0, 0);
    }

#pragma unroll
    for (int i = 0; i < 4; i++)
#pragma unroll
        for (int j = 0; j < 4; j++) {
            const int gc = col0 + wn + j * 16 + lane15;
            const int rb = row0 + wm + i * 16 + quad * 4;
            const float bv = bias[gc];
#pragma unroll
            for (int rr = 0; rr < 4; rr++) {
                const size_t o = (size_t)(rb + rr) * N + gc;
                TT[o] = f2bf(fmaxf(acc[i][j][rr] + bv, 0.f));
            }
        }
}

// ---------------------------------------------------------------------------
// Values MLP layer 2: A bf16 [M][K], B hi plane [N][K]: C(f32) = A @ B^T
// ---------------------------------------------------------------------------
__global__ __launch_bounds__(256) void gemm_bf16_f32(
    const ushort* __restrict__ A, const ushort* __restrict__ BTh,
    float* __restrict__ C, int M, int N, int K)
{
    __shared__ ushort Ah[128 * 32];
    __shared__ ushort Bh[128 * 32];
    const int tid = threadIdx.x;
    const int lane = tid & 63, wid = tid >> 6;
    const int wm = (wid & 1) * 64, wn = (wid >> 1) * 64;
    const int lane15 = lane & 15, quad = lane >> 4;
    const int row0 = blockIdx.y * 128, col0 = blockIdx.x * 128;
    const int sm = tid >> 1, scp = (tid & 1) * 2;

    const ushort* arow = A   + (size_t)(row0 + sm) * K + scp * 8;
    const ushort* brow = BTh + (size_t)(col0 + sm) * K + scp * 8;

    floatx4 acc[4][4];
#pragma unroll
    for (int i = 0; i < 4; i++)
#pragma unroll
        for (int j = 0; j < 4; j++) acc[i][j] = (floatx4){0.f, 0.f, 0.f, 0.f};

    for (int k0 = 0; k0 < K; k0 += 32) {
        short8 a0 = *(const short8*)(arow + k0);
        short8 a1 = *(const short8*)(arow + k0 + 8);
        short8 b0 = *(const short8*)(brow + k0);
        short8 b1 = *(const short8*)(brow + k0 + 8);
        __syncthreads();
        *(short8*)(Ah + lds_off(sm, scp))     = a0;
        *(short8*)(Ah + lds_off(sm, scp + 1)) = a1;
        *(short8*)(Bh + lds_off(sm, scp))     = b0;
        *(short8*)(Bh + lds_off(sm, scp + 1)) = b1;
        __syncthreads();

        short8 ah[4], bh[4];
#pragma unroll
        for (int t = 0; t < 4; t++) {
            ah[t] = *(const short8*)(Ah + lds_off(wm + t * 16 + lane15, quad));
            bh[t] = *(const short8*)(Bh + lds_off(wn + t * 16 + lane15, quad));
        }
#pragma unroll
        for (int i = 0; i < 4; i++)
#pragma unroll
            for (int j = 0; j < 4; j++)
                acc[i][j] = __builtin_amdgcn_mfma_f32_16x16x32_bf16(ah[i], bh[j], acc[i][j], 0, 0, 0);
    }

#pragma unroll
    for (int i = 0; i < 4; i++)
#pragma unroll
        for (int j = 0; j < 4; j++) {
            const int gc = col0 + wn + j * 16 + lane15;
            const int rb = row0 + wm + i * 16 + quad * 4;
#pragma unroll
            for (int rr = 0; rr < 4; rr++)
                C[(size_t)(rb + rr) * N + gc] = acc[i][j][rr];
        }
}

// ---------------------------------------------------------------------------
// Prep kernels
// ---------------------------------------------------------------------------
__global__ __launch_bounds__(256) void transpose_kernel(
    const float* __restrict__ W, float* __restrict__ WT, int K, int N)
{
    const int o = blockIdx.x * 256 + threadIdx.x;
    if (o < K * N) {
        const int n = o / K, k = o - n * K;
        WT[o] = W[(size_t)k * N + n];
    }
}

__global__ __launch_bounds__(256) void split_wt_kernel(
    const float* __restrict__ W, ushort* __restrict__ WTh,
    ushort* __restrict__ WTl, int K, int N)
{
    const int o = blockIdx.x * 256 + threadIdx.x;
    if (o < K * N) {
        const int n = o / K, k = o - n * K;
        const float x = W[(size_t)k * N + n];
        const ushort h = f2bf(x);
        WTh[o] = h;
        WTl[o] = f2bf(x - bf2f(h));
    }
}

__global__ __launch_bounds__(256) void split_pl_kernel(
    const float* __restrict__ X, ushort* __restrict__ Xh,
    ushort* __restrict__ Xl, int n)
{
    const int i = blockIdx.x * 256 + threadIdx.x;
    if (i < n) {
        const float x = X[i];
        const ushort h = f2bf(x);
        Xh[i] = h;
        Xl[i] = f2bf(x - bf2f(h));
    }
}

// ---------------------------------------------------------------------------
// LayerNorm rows of 512, f32 in / f32 out (x-path)
// ---------------------------------------------------------------------------
__global__ __launch_bounds__(256) void ln_kernel(
    const float* __restrict__ X, const float* __restrict__ g,
    const float* __restrict__ b, float* __restrict__ Y, int relu)
{
    const int lane = threadIdx.x & 63;
    const int row  = blockIdx.x * 4 + (threadIdx.x >> 6);
    const float* x = X + (size_t)row * ND;
    const int d = lane * 8;

    float4 v0 = *(const float4*)(x + d);
    float4 v1 = *(const float4*)(x + d + 4);
    float s = v0.x + v0.y + v0.z + v0.w + v1.x + v1.y + v1.z + v1.w;
    float q = v0.x*v0.x + v0.y*v0.y + v0.z*v0.z + v0.w*v0.w
            + v1.x*v1.x + v1.y*v1.y + v1.z*v1.z + v1.w*v1.w;
#pragma unroll
    for (int off = 32; off; off >>= 1) {
        s += __shfl_down(s, off);
        q += __shfl_down(q, off);
    }
    s = __shfl(s, 0); q = __shfl(q, 0);
    const float mean = s * (1.f / ND);
    const float var  = q * (1.f / ND) - mean * mean;
    const float rs   = rsqrtf(var + 1e-5f);

    float4 g0 = *(const float4*)(g + d);
    float4 g1 = *(const float4*)(g + d + 4);
    float4 b0 = *(const float4*)(b + d);
    float4 b1 = *(const float4*)(b + d + 4);
    float4 o0, o1;
    o0.x = (v0.x - mean) * rs * g0.x + b0.x;
    o0.y = (v0.y - mean) * rs * g0.y + b0.y;
    o0.z = (v0.z - mean) * rs * g0.z + b0.z;
    o0.w = (v0.w - mean) * rs * g0.w + b0.w;
    o1.x = (v1.x - mean) * rs * g1.x + b1.x;
    o1.y = (v1.y - mean) * rs * g1.y + b1.y;
    o1.z = (v1.z - mean) * rs * g1.z + b1.z;
    o1.w = (v1.w - mean) * rs * g1.w + b1.w;
    if (relu) {
        o0.x = fmaxf(o0.x, 0.f); o0.y = fmaxf(o0.y, 0.f);
        o0.z = fmaxf(o0.z, 0.f); o0.w = fmaxf(o0.w, 0.f);
        o1.x = fmaxf(o1.x, 0.f); o1.y = fmaxf(o1.y, 0.f);
        o1.z = fmaxf(o1.z, 0.f); o1.w = fmaxf(o1.w, 0.f);
    }
    float* y = Y + (size_t)row * ND;
    *(float4*)(y + d)     = o0;
    *(float4*)(y + d + 4) = o1;
}

// LayerNorm rows of 512, planes in / planes out (candidate encode)
__global__ __launch_bounds__(256) void ln_pl_kernel(
    const ushort* __restrict__ Xh, const ushort* __restrict__ Xl,
    const float* __restrict__ g, const float* __restrict__ b,
    ushort* __restrict__ Yh, ushort* __restrict__ Yl)
{
    const int lane = threadIdx.x & 63;
    const int row  = blockIdx.x * 4 + (threadIdx.x >> 6);
    const int d = lane * 8;
    const size_t base = (size_t)row * ND + d;

    short8 xh = *(const short8*)(Xh + base);
    short8 xl = *(const short8*)(Xl + base);
    float v[8];
#pragma unroll
    for (int i = 0; i < 8; i++) v[i] = bf2f((ushort)xh[i]) + bf2f((ushort)xl[i]);

    float s = 0.f, q = 0.f;
#pragma unroll
    for (int i = 0; i < 8; i++) { s += v[i]; q += v[i] * v[i]; }
#pragma unroll
    for (int off = 32; off; off >>= 1) {
        s += __shfl_down(s, off);
        q += __shfl_down(q, off);
    }
    s = __shfl(s, 0); q = __shfl(q, 0);
    const float mean = s * (1.f / ND);
    const float var  = q * (1.f / ND) - mean * mean;
    const float rs   = rsqrtf(var + 1e-5f);

    short8 yh, yl;
#pragma unroll
    for (int i = 0; i < 8; i++) {
        const float o = (v[i] - mean) * rs * g[d + i] + b[d + i];
        const ushort h = f2bf(o);
        yh[i] = (short)h;
        yl[i] = (short)f2bf(o - bf2f(h));
    }
    *(short8*)(Yh + base) = yh;
    *(short8*)(Yl + base) = yl;
}

__global__ __launch_bounds__(256) void sqnorm_pl_kernel(
    const ushort* __restrict__ Xh, const ushort* __restrict__ Xl,
    float* __restrict__ sq)
{
    const int lane = threadIdx.x & 63;
    const int row  = blockIdx.x * 4 + (threadIdx.x >> 6);
    const size_t base = (size_t)row * ND + lane * 8;
    short8 xh = *(const short8*)(Xh + base);
    short8 xl = *(const short8*)(Xl + base);
    float q = 0.f;
#pragma unroll
    for (int i = 0; i < 8; i++) {
        float v = bf2f((ushort)xh[i]) + bf2f((ushort)xl[i]);
        q += v * v;
    }
#pragma unroll
    for (int off = 32; off; off >>= 1) q += __shfl_down(q, off);
    if (lane == 0) sq[row] = q;
}

// ---------------------------------------------------------------------------
// Two-stage exact top-96: adaptive-range radix select.
// Bins computed over the OCCUPIED key range -> spread bins -> plain LDS
// atomics are near-conflict-free regardless of score distribution.
// ---------------------------------------------------------------------------
__device__ __forceinline__ unsigned fkey(float f)
{
    unsigned u = __float_as_uint(f);
    return (u & 0x80000000u) ? ~u : (u | 0x80000000u);
}
__device__ __forceinline__ float inv_fkey(unsigned u)
{
    return __uint_as_float((u & 0x80000000u) ? (u & 0x7FFFFFFFu) : ~u);
}

struct SelState {
    unsigned lo;
    unsigned long long hi;   // exclusive
    int krem;
    int done;
    unsigned long long T;    // threshold (u64 so exclusive bound can't wrap)
    int need;                // how many keys == T to take
};

// Exact k-th-smallest selection over the block's register-held keys.
// hist/wtot are shared scratch (256 / 4 entries). All keys valid.
template <int KPT>
__device__ __forceinline__ void adaptive_select(
    const unsigned (&key)[KPT], unsigned* hist, unsigned* wtot,
    SelState* st, int tid, int kwant)
{
    const int lane = tid & 63, wid = tid >> 6;

    // block min/max
    unsigned mn = 0xFFFFFFFFu, mx = 0u;
#pragma unroll
    for (int j = 0; j < KPT; j++) {
        mn = min(mn, key[j]);
        mx = max(mx, key[j]);
    }
#pragma unroll
    for (int off = 32; off; off >>= 1) {
        mn = min(mn, (unsigned)__shfl_down((int)mn, off));
        mx = max(mx, (unsigned)__shfl_down((int)mx, off));
    }
    if (lane == 0) { hist[wid] = mn; hist[8 + wid] = mx; }
    if (tid == 0) st->done = 0;
    __syncthreads();
    if (tid == 0) {
        unsigned gmn = min(min(hist[0], hist[1]), min(hist[2], hist[3]));
        unsigned gmx = max(max(hist[8], hist[9]), max(hist[10], hist[11]));
        st->lo = gmn;
        st->hi = (unsigned long long)gmx + 1ull;
        st->krem = kwant;
    }
    __syncthreads();

    for (int iter = 0; iter < 6 && !st->done; iter++) {
        const unsigned lo = st->lo;
        const unsigned long long hi = st->hi;
        const int krem = st->krem;
        const unsigned long long span = hi - lo;
        int shift = 0;
        if (span > 256ull) {
            const int nb = 64 - __builtin_clzll(span - 1ull);
            shift = nb - 8;
        }
        hist[tid] = 0u;
        __syncthreads();
#pragma unroll
        for (int j = 0; j < KPT; j++) {
            const unsigned u = key[j];
            if (u >= lo && (unsigned long long)u < hi)
                atomicAdd(&hist[(u - lo) >> shift], 1u);
        }
        __syncthreads();
        const unsigned c = hist[tid];
        unsigned v = c;                         // wave inclusive scan
#pragma unroll
        for (int off = 1; off < 64; off <<= 1) {
            const unsigned t = (unsigned)__shfl_up((int)v, off);
            if (lane >= off) v += t;
        }
        if (lane == 63) wtot[wid] = v;
        __syncthreads();
        unsigned pre = 0;
        for (int w = 0; w < 3; w++) pre += (w < wid) ? wtot[w] : 0u;
        const int incl = (int)(v + pre);
        const int excl = incl - (int)c;
        if (excl < krem && incl >= krem) {      // exactly one tid
            const unsigned long long binlo =
                (unsigned long long)lo + ((unsigned long long)tid << shift);
            if (shift == 0) {
                st->T = binlo;                  // exact boundary value
                st->need = krem - excl;
                st->done = 1;
            } else if (incl == krem) {
                st->T = binlo + (1ull << shift); // exclusive bound, no ties
                st->need = 0;
                st->done = 1;
            } else {
                st->lo = (unsigned)binlo;
                const unsigned long long nhi = binlo + (1ull << shift);
                st->hi = nhi < hi ? nhi : hi;
                st->krem = krem - excl;
            }
        }
        __syncthreads();
    }
}

// Stage 1: per-(row, 4096-segment) exact top-96 -> candidate buffer
__global__ __launch_bounds__(256) void topk_seg(
    const float* __restrict__ S, unsigned* __restrict__ K1key,
    int* __restrict__ K1idx)
{
    const int r = blockIdx.y, seg = blockIdx.x;
    const float* p = S + (size_t)r * NN + seg * TK_SEG;
    __shared__ unsigned hist[256];
    __shared__ unsigned wtot[4];
    __shared__ SelState st;
    __shared__ int cA, cB;
    const int tid = threadIdx.x;

    unsigned key[16];                     // 4096 keys, 16/thread, coalesced
#pragma unroll
    for (int j = 0; j < 16; j++) key[j] = fkey(p[tid + j * 256]);

    if (tid == 0) { cA = 0; cB = 0; }
    adaptive_select<16>(key, hist, wtot, &st, tid, NC);

    const unsigned long long T = st.T;
    const int need = st.need;
    const int cntLess = NC - need;
    const size_t obase = ((size_t)r * TK_SPLIT + seg) * NC;
#pragma unroll
    for (int j = 0; j < 16; j++) {
        const unsigned u = key[j];
        if ((unsigned long long)u < T) {
            const int pos = atomicAdd(&cA, 1);
            K1key[obase + pos] = u;
            K1idx[obase + pos] = seg * TK_SEG + tid + j * 256;
        } else if ((unsigned long long)u == T) {
            const int pos = atomicAdd(&cB, 1);
            if (pos < need) {
                K1key[obase + cntLess + pos] = u;
                K1idx[obase + cntLess + pos] = seg * TK_SEG + tid + j * 256;
            }
        }
    }
}

// Stage 2: per-row exact top-96 of the 1536 stage-1 survivors
__global__ __launch_bounds__(256) void topk_merge(
    const unsigned* __restrict__ K1key, const int* __restrict__ K1idx,
    int* __restrict__ idx_out, float* __restrict__ val_out, int b0)
{
    const int r = blockIdx.x;
    const int b = b0 + r;
    __shared__ unsigned hist[256];
    __shared__ unsigned wtot[4];
    __shared__ SelState st;
    __shared__ int cA, cB;
    const int tid = threadIdx.x;
    const size_t ibase = (size_t)r * TK_CAND;

    unsigned key[6];
    int      kidx[6];
#pragma unroll
    for (int j = 0; j < 6; j++) {
        key[j]  = K1key[ibase + tid + j * 256];
        kidx[j] = K1idx[ibase + tid + j * 256];
    }

    if (tid == 0) { cA = 0; cB = 0; }
    adaptive_select<6>(key, hist, wtot, &st, tid, NC);

    const unsigned long long T = st.T;
    const int need = st.need;
    const int cntLess = NC - need;
#pragma unroll
    for (int j = 0; j < 6; j++) {
        const unsigned u = key[j];
        if ((unsigned long long)u < T) {
            const int pos = atomicAdd(&cA, 1);
            idx_out[b * NC + pos] = kidx[j];
            val_out[b * NC + pos] = inv_fkey(u);
        } else if ((unsigned long long)u == T) {
            const int pos = atomicAdd(&cB, 1);
            if (pos < need) {
                idx_out[b * NC + cntLess + pos] = kidx[j];
                val_out[b * NC + cntLess + pos] = inv_fkey(u);
            }
        }
    }
}

// ---------------------------------------------------------------------------
__global__ __launch_bounds__(128) void probs_kernel(
    const float* __restrict__ svals, float* __restrict__ probs)
{
    const int b = blockIdx.x;
    const int tid = threadIdx.x;
    __shared__ float red[128];
    const bool valid = tid < NC;
    float s = valid ? -svals[b * NC + tid] : -3.4e38f;
    red[tid] = s;
    __syncthreads();
#pragma unroll
    for (int off = 64; off; off >>= 1) {
        if (tid < off) red[tid] = fmaxf(red[tid], red[tid + off]);
        __syncthreads();
    }
    const float m = red[0];
    __syncthreads();
    float e = valid ? expf(s - m) : 0.f;
    red[tid] = e;
    __syncthreads();
#pragma unroll
    for (int off = 64; off; off >>= 1) {
        if (tid < off) red[tid] += red[tid + off];
        __syncthreads();
    }
    const float sum = red[0];
    if (valid) probs[b * NC + tid] = e / sum;
}

__global__ __launch_bounds__(256) void ctx_kernel(
    const float* __restrict__ VAL, const float* __restrict__ probs,
    const float* __restrict__ cand_y, const int* __restrict__ idx,
    const float* __restrict__ labW, const float* __restrict__ labb,
    const float* __restrict__ xin, float* __restrict__ xout, int b0)
{
    const int b_loc = blockIdx.x;
    const int b = b0 + b_loc;
    const int tid = threadIdx.x;
    __shared__ float pv[NC];
    __shared__ float red[256];
    float py_part = 0.f;
    if (tid < NC) {
        float p = probs[b * NC + tid];
        pv[tid] = p;
        py_part = p * cand_y[idx[b * NC + tid]];
    }
    red[tid] = py_part;
    __syncthreads();
#pragma unroll
    for (int off = 128; off; off >>= 1) {
        if (tid < off) red[tid] += red[tid + off];
        __syncthreads();
    }
    const float py = red[0];

    for (int d = tid; d < ND; d += 256) {
        const float* vp = VAL + (size_t)b_loc * NC * ND + d;
        float acc = 0.f;
#pragma unroll 8
        for (int c = 0; c < NC; c++) acc += pv[c] * vp[(size_t)c * ND];
        float ctx = acc + py * labW[d] + labb[d];
        xout[(size_t)b * ND + d] = xin[(size_t)b * ND + d] + ctx;
    }
}

__global__ __launch_bounds__(64) void head_kernel(
    const float* __restrict__ X, const float* __restrict__ hW,
    const float* __restrict__ hb, float* __restrict__ out)
{
    const int b = blockIdx.x;
    const int lane = threadIdx.x;
    const float* x = X + (size_t)b * ND;
    float acc = 0.f;
#pragma unroll
    for (int j = 0; j < 8; j++) {
        int d = lane + 64 * j;
        acc += x[d] * hW[d];
    }
#pragma unroll
    for (int off = 32; off; off >>= 1) acc += __shfl_down(acc, off);
    if (lane == 0) out[b] = acc + hb[0];
}

// ---------------------------------------------------------------------------
extern "C" void kernel_launch(void* const* d_in, const int* in_sizes, int n_in,
                              void* d_out, int out_size, void* d_ws, size_t ws_size,
                              hipStream_t stream)
{
    const float* x_num    = (const float*)d_in[0];
    const float* cand_num = (const float*)d_in[1];
    const float* cand_y   = (const float*)d_in[2];
    const float* lin_W    = (const float*)d_in[3];
    const float* lin_b    = (const float*)d_in[4];
    const float* e_W1     = (const float*)d_in[5];
    const float* e_b1     = (const float*)d_in[6];
    const float* e_W2     = (const float*)d_in[7];
    const float* e_b2     = (const float*)d_in[8];
    const float* mix_g    = (const float*)d_in[9];
    const float* mix_b    = (const float*)d_in[10];
    const float* K_W      = (const float*)d_in[11];
    const float* K_b      = (const float*)d_in[12];
    const float* lab_W    = (const float*)d_in[13];
    const float* lab_b    = (const float*)d_in[14];
    const float* T_W1     = (const float*)d_in[15];
    const float* T_b1     = (const float*)d_in[16];
    const float* T_W2     = (const float*)d_in[17];
    const float* p_ln_g   = (const float*)d_in[18];
    const float* p_ln_b   = (const float*)d_in[19];
    const float* p_W1     = (const float*)d_in[20];
    const float* p_b1     = (const float*)d_in[21];
    const float* p_W2     = (const float*)d_in[22];
    const float* p_b2     = (const float*)d_in[23];
    const float* h_ln_g   = (const float*)d_in[24];
    const float* h_ln_b   = (const float*)d_in[25];
    const float* h_W      = (const float*)d_in[26];
    const float* h_b      = (const float*)d_in[27];
    float* out = (float*)d_out;
    (void)in_sizes; (void)n_in; (void)out_size; (void)ws_size;

    // ---- workspace layout (~253 MB) ----
    size_t off = 0;
    auto ralloc = [&](size_t bytes) -> void* {
        void* p = (char*)d_ws + off;
        off += (bytes + 255) & ~(size_t)255;
        return p;
    };
    auto falloc = [&](size_t n) -> float*  { return (float*)ralloc(n * 4); };
    auto ualloc = [&](size_t n) -> ushort* { return (ushort*)ralloc(n * 2); };

    float* WT_lin = falloc((size_t)ND * NF);
    float* WT_e1  = falloc((size_t)NDB * ND);
    float* WT_e2  = falloc((size_t)ND * NDB);
    float* WT_kw  = falloc((size_t)ND * ND);
    float* WT_p1  = falloc((size_t)NDB * ND);
    float* WT_p2  = falloc((size_t)ND * NDB);
    ushort* WP_lin_h = ualloc((size_t)ND * NF);
    ushort* WP_lin_l = ualloc((size_t)ND * NF);
    ushort* WP_e1_h  = ualloc((size_t)NDB * ND);
    ushort* WP_e1_l  = ualloc((size_t)NDB * ND);
    ushort* WP_e2_h  = ualloc((size_t)ND * NDB);
    ushort* WP_e2_l  = ualloc((size_t)ND * NDB);
    ushort* WP_kw_h  = ualloc((size_t)ND * ND);
    ushort* WP_kw_l  = ualloc((size_t)ND * ND);
    ushort* WP_t1_h  = ualloc((size_t)NDB * ND);
    ushort* WP_t1_l  = ualloc((size_t)NDB * ND);
    ushort* WP_t2_h  = ualloc((size_t)ND * NDB);
    ushort* WP_t2_l  = ualloc((size_t)ND * NDB);

    ushort* R_CKh = ualloc((size_t)NN * ND);
    ushort* R_CKl = ualloc((size_t)NN * ND);
    float*  R_sq  = falloc(NN);
    float*  R_Hx  = falloc((size_t)NB * ND);
    float*  R_Tx  = falloc((size_t)NB * NDB);
    float*  R_Gx  = falloc((size_t)NB * ND);
    float*  R_kx  = falloc((size_t)NB * ND);
    ushort* R_kxh = ualloc((size_t)NB * ND);
    ushort* R_kxl = ualloc((size_t)NB * ND);
    int*    R_idx = (int*)ralloc((size_t)NB * NC * 4);
    float*  R_ssel= falloc((size_t)NB * NC);
    float*  R_prob= falloc((size_t)NB * NC);
    float*  R_xupd= falloc((size_t)NB * ND);
    float*  R_lnx = falloc((size_t)NB * ND);
    float*  R_tp  = falloc((size_t)NB * NDB);
    float*  R_x2  = falloc((size_t)NB * ND);
    float*  R_lnx2= falloc((size_t)NB * ND);
    unsigned* K1key = (unsigned*)ralloc((size_t)BB_C * TK_CAND * 4);
    int*      K1idx = (int*)ralloc((size_t)BB_C * TK_CAND * 4);
    char* SCR = (char*)ralloc((size_t)70 * 1024 * 1024);

    // ---- 0. weight prep ----
    auto tr = [&](const float* W, float* WT, int K, int N) {
        transpose_kernel<<<dim3((K * N + 255) / 256), dim3(256), 0, stream>>>(W, WT, K, N);
    };
    auto sw = [&](const float* W, ushort* WTh, ushort* WTl, int K, int N) {
        split_wt_kernel<<<dim3((K * N + 255) / 256), dim3(256), 0, stream>>>(W, WTh, WTl, K, N);
    };
    tr(lin_W, WT_lin, NF, ND);
    tr(e_W1,  WT_e1,  ND, NDB);
    tr(e_W2,  WT_e2,  NDB, ND);
    tr(K_W,   WT_kw,  ND, ND);
    tr(p_W1,  WT_p1,  ND, NDB);
    tr(p_W2,  WT_p2,  NDB, ND);
    sw(lin_W, WP_lin_h, WP_lin_l, NF, ND);
    sw(e_W1,  WP_e1_h,  WP_e1_l,  ND, NDB);
    sw(e_W2,  WP_e2_h,  WP_e2_l,  NDB, ND);
    sw(K_W,   WP_kw_h,  WP_kw_l,  ND, ND);
    sw(T_W1,  WP_t1_h,  WP_t1_l,  ND, NDB);
    sw(T_W2,  WP_t2_h,  WP_t2_l,  NDB, ND);

    auto gss = [&](const ushort* Ah, const ushort* Al, const ushort* Bh,
                   const ushort* Bl, const float* bias, const ushort* resh,
                   const ushort* resl, const float* sq, float* Sf,
                   ushort* Ch, ushort* Cl, int M, int Nn, int K, int relu) {
        gemm_ss<<<dim3(Nn / 128, M / 128), dim3(256), 0, stream>>>(
            Ah, Al, Bh, Bl, bias, resh, resl, sq, Sf, Ch, Cl, M, Nn, K, relu);
    };
    auto gsplit = [&](const float* A, const float* BT, const float* bias,
                      const float* res, float* C, int M, int Nn, int K, int relu) {
        gemm_split_nt<<<dim3(Nn / 128, M / 128), dim3(256), 0, stream>>>(
            A, BT, bias, res, C, M, Nn, K, relu);
    };

    // ---- 1. candidate encode (chunked; plane operands, split-bf16 MFMA) ----
    {
        ushort* CNh = (ushort*)SCR;
        ushort* CNl = CNh + (size_t)CH_A * NF;
        ushort* Hh  = CNl + (size_t)CH_A * NF;
        ushort* Hl  = Hh  + (size_t)CH_A * ND;
        ushort* Th  = Hl  + (size_t)CH_A * ND;
        ushort* Tl  = Th  + (size_t)CH_A * NDB;
        ushort* H2h = Tl  + (size_t)CH_A * NDB;
        ushort* H2l = H2h + (size_t)CH_A * ND;
        ushort* Gh  = Th;   // overlay: T dead after e2
        ushort* Gl  = Tl;

        for (int n0 = 0; n0 < NN; n0 += CH_A) {
            split_pl_kernel<<<dim3((CH_A * NF + 255) / 256), dim3(256), 0, stream>>>(
                cand_num + (size_t)n0 * NF, CNh, CNl, CH_A * NF);
            gss(CNh, CNl, WP_lin_h, WP_lin_l, lin_b, nullptr, nullptr, nullptr,
                nullptr, Hh, Hl, CH_A, ND, NF, 0);
            gss(Hh, Hl, WP_e1_h, WP_e1_l, e_b1, nullptr, nullptr, nullptr,
                nullptr, Th, Tl, CH_A, NDB, ND, 1);
            gss(Th, Tl, WP_e2_h, WP_e2_l, e_b2, Hh, Hl, nullptr,
                nullptr, H2h, H2l, CH_A, ND, NDB, 0);
            ln_pl_kernel<<<dim3(CH_A / 4), dim3(256), 0, stream>>>(
                H2h, H2l, mix_g, mix_b, Gh, Gl);
            gss(Gh, Gl, WP_kw_h, WP_kw_l, K_b, nullptr, nullptr, nullptr,
                nullptr, R_CKh + (size_t)n0 * ND, R_CKl + (size_t)n0 * ND,
                CH_A, ND, ND, 0);
            sqnorm_pl_kernel<<<dim3(CH_A / 4), dim3(256), 0, stream>>>(
                R_CKh + (size_t)n0 * ND, R_CKl + (size_t)n0 * ND, R_sq + n0);
        }
    }

    // ---- 2. x encode (f32-operand split kernel; small) ----
    gsplit(x_num, WT_lin, lin_b, nullptr, R_Hx, NB, ND, NF, 0);
    gsplit(R_Hx, WT_e1, e_b1, nullptr, R_Tx, NB, NDB, ND, 1);
    gsplit(R_Tx, WT_e2, e_b2, R_Hx, R_Hx, NB, ND, NDB, 0);
    ln_kernel<<<dim3(NB / 4), dim3(256), 0, stream>>>(R_Hx, mix_g, mix_b, R_Gx, 0);
    gsplit(R_Gx, WT_kw, K_b, nullptr, R_kx, NB, ND, ND, 0);
    split_pl_kernel<<<dim3((NB * ND + 255) / 256), dim3(256), 0, stream>>>(
        R_kx, R_kxh, R_kxl, NB * ND);

    // ---- 3. scores + two-stage top-96 + softmax ----
    for (int b0 = 0; b0 < NB; b0 += BB_C) {
        float* S = (float*)SCR;
        gss(R_kxh + (size_t)b0 * ND, R_kxl + (size_t)b0 * ND, R_CKh, R_CKl,
            nullptr, nullptr, nullptr, R_sq, S, nullptr, nullptr,
            BB_C, NN, ND, 0);
        topk_seg<<<dim3(TK_SPLIT, BB_C), dim3(256), 0, stream>>>(S, K1key, K1idx);
        topk_merge<<<dim3(BB_C), dim3(256), 0, stream>>>(K1key, K1idx,
                                                         R_idx, R_ssel, b0);
    }
    probs_kernel<<<dim3(NB), dim3(128), 0, stream>>>(R_ssel, R_prob);

    // ---- 4. values path (plain bf16 MFMA, diff fused) ----
    for (int b0 = 0; b0 < NB; b0 += BB_D) {
        ushort* TT = (ushort*)SCR;                                  // [M,1024] bf16
        float* VAL = (float*)(SCR + (size_t)BB_D * NC * NDB * 2);   // f32 after TT
        const int M = BB_D * NC;   // 12288
        gemm_diff_bf16<<<dim3(NDB / 128, M / 128), dim3(256), 0, stream>>>(
            R_kx + (size_t)b0 * ND, R_CKh, R_CKl, R_idx + b0 * NC,
            WP_t1_h, T_b1, TT, M, NDB, ND);
        gemm_bf16_f32<<<dim3(ND / 128, M / 128), dim3(256), 0, stream>>>(
            TT, WP_t2_h, VAL, M, ND, NDB);
        ctx_kernel<<<dim3(BB_D), dim3(256), 0, stream>>>(
            VAL, R_prob, cand_y, R_idx, lab_W, lab_b, R_Hx, R_xupd, b0);
    }

    // ---- 5. predictor block + head ----
    ln_kernel<<<dim3(NB / 4), dim3(256), 0, stream>>>(R_xupd, p_ln_g, p_ln_b, R_lnx, 0);
    gsplit(R_lnx, WT_p1, p_b1, nullptr, R_tp, NB, NDB, ND, 1);
    gsplit(R_tp, WT_p2, p_b2, R_xupd, R_x2, NB, ND, NDB, 0);
    ln_kernel<<<dim3(NB / 4), dim3(256), 0, stream>>>(R_x2, h_ln_g, h_ln_b, R_lnx2, 1);
    head_kernel<<<dim3(NB), dim3(64), 0, stream>>>(R_lnx2, h_W, h_b, out);
}

// Round 9
// 3192.020 us; speedup vs baseline: 1.2299x; 1.0142x over previous
//
#include <hip/hip_runtime.h>

// Problem constants
#define NB   1024
#define NN   65536
#define NF   64
#define ND   512
#define NDB  1024
#define NC   96

// Chunking
#define CH_A 8192      // candidate-encode chunk rows
#define BB_C 256       // scores/topk chunk of B rows
#define BB_D 128       // values-path chunk of B rows

// top-k segmentation
#define TK_SPLIT 16
#define TK_SEG   (NN / TK_SPLIT)   // 4096
#define TK_CAND  (TK_SPLIT * NC)   // 1536

typedef unsigned short ushort;
typedef __attribute__((ext_vector_type(8))) short short8;
typedef __attribute__((ext_vector_type(4))) float floatx4;

__device__ __forceinline__ ushort f2bf(float f) {   // RNE f32->bf16
    unsigned u = __float_as_uint(f);
    u += 0x7fffu + ((u >> 16) & 1u);
    return (ushort)(u >> 16);
}
__device__ __forceinline__ float bf2f(ushort h) {
    return __uint_as_float(((unsigned)h) << 16);
}
// LDS plane: [m][k] bf16, k-stride 32, 16B-chunk XOR swizzle -> conflict-free
__device__ __forceinline__ int lds_off(int m, int c) {
    return m * 32 + (((c + (m >> 1)) & 3) << 3);
}

// async global->LDS 16B (DMA; LDS dst = wave-uniform base + lane*16; our
// per-lane l pointers satisfy that identity by construction)
__device__ __forceinline__ void gload16(const ushort* g, ushort* l)
{
    void* gv = (void*)g;
    void* lv = (void*)l;
    __builtin_amdgcn_global_load_lds(
        (__attribute__((address_space(1))) void*)gv,
        (__attribute__((address_space(3))) void*)lv, 16, 0, 0);
}

// ---------------------------------------------------------------------------
// Split-plane MFMA GEMM (f32-emulating, 3 MFMA), NT:
//   acc = A @ B^T  with A=(Ah,Al)[M][K], B=(Bh,Bl)[N][K] bf16 planes.
// Staging: global_load_lds w=16; inverse-swizzled global chunk index so LDS
// content matches lds_off() layout (frag reads conflict-free, bit-identical).
// Epilogue: scoresq ? Sf = scoresq[n]-2*acc : v=acc+bias(+res)(relu) -> planes
// ---------------------------------------------------------------------------
__global__ __launch_bounds__(256) void gemm_ss(
    const ushort* __restrict__ Ah_g, const ushort* __restrict__ Al_g,
    const ushort* __restrict__ Bh_g, const ushort* __restrict__ Bl_g,
    const float* __restrict__ bias,
    const ushort* __restrict__ resh, const ushort* __restrict__ resl,
    const float* __restrict__ scoresq, float* __restrict__ Sf,
    ushort* __restrict__ Ch, ushort* __restrict__ Cl,
    int M, int N, int K, int relu)
{
    __shared__ ushort Ah[128 * 32], Al[128 * 32];
    __shared__ ushort Bh[128 * 32], Bl[128 * 32];
    const int tid = threadIdx.x;
    const int lane = tid & 63, wid = tid >> 6;
    const int wm = (wid & 1) * 64, wn = (wid >> 1) * 64;
    const int lane15 = lane & 15, quad = lane >> 4;
    const int row0 = blockIdx.y * 128, col0 = blockIdx.x * 128;

    // staging addresses: lds flat byte o = r*4096 + tid*16
    //   row m = r*64 + tid/4, lds chunk cl = tid&3,
    //   global k-chunk cp = (cl - (m>>1)) & 3   (same for r=0,1 since 32%4==0)
    const int srow = tid >> 2;
    const int scl  = tid & 3;
    const int cp   = (scl - (srow >> 1)) & 3;
    const size_t ga0 = (size_t)(row0 + srow) * K + cp * 8;
    const size_t ga1 = (size_t)(row0 + 64 + srow) * K + cp * 8;
    const size_t gb0 = (size_t)(col0 + srow) * K + cp * 8;
    const size_t gb1 = (size_t)(col0 + 64 + srow) * K + cp * 8;
    const int l0 = tid * 8;          // lds element offset, round 0
    const int l1 = 2048 + tid * 8;   // round 1

    floatx4 acc[4][4];
#pragma unroll
    for (int i = 0; i < 4; i++)
#pragma unroll
        for (int j = 0; j < 4; j++) acc[i][j] = (floatx4){0.f, 0.f, 0.f, 0.f};

    for (int k0 = 0; k0 < K; k0 += 32) {
        __syncthreads();
        gload16(Ah_g + ga0 + k0, Ah + l0);
        gload16(Ah_g + ga1 + k0, Ah + l1);
        gload16(Al_g + ga0 + k0, Al + l0);
        gload16(Al_g + ga1 + k0, Al + l1);
        gload16(Bh_g + gb0 + k0, Bh + l0);
        gload16(Bh_g + gb1 + k0, Bh + l1);
        gload16(Bl_g + gb0 + k0, Bl + l0);
        gload16(Bl_g + gb1 + k0, Bl + l1);
        __syncthreads();

        short8 ah[4], al[4], bh[4], bl[4];
#pragma unroll
        for (int t = 0; t < 4; t++) {
            const int am = wm + t * 16 + lane15;
            const int bn = wn + t * 16 + lane15;
            ah[t] = *(const short8*)(Ah + lds_off(am, quad));
            al[t] = *(const short8*)(Al + lds_off(am, quad));
            bh[t] = *(const short8*)(Bh + lds_off(bn, quad));
            bl[t] = *(const short8*)(Bl + lds_off(bn, quad));
        }
#pragma unroll
        for (int i = 0; i < 4; i++)
#pragma unroll
            for (int j = 0; j < 4; j++) {
                acc[i][j] = __builtin_amdgcn_mfma_f32_16x16x32_bf16(ah[i], bh[j], acc[i][j], 0, 0, 0);
                acc[i][j] = __builtin_amdgcn_mfma_f32_16x16x32_bf16(ah[i], bl[j], acc[i][j], 0, 0, 0);
                acc[i][j] = __builtin_amdgcn_mfma_f32_16x16x32_bf16(al[i], bh[j], acc[i][j], 0, 0, 0);
            }
    }

    // C/D layout: col=lane&15, row=quad*4+reg  [m89]
#pragma unroll
    for (int i = 0; i < 4; i++)
#pragma unroll
        for (int j = 0; j < 4; j++) {
            const int gc = col0 + wn + j * 16 + lane15;
            const int rb = row0 + wm + i * 16 + quad * 4;
            const float bv = bias ? bias[gc] : 0.f;
            const float sv = scoresq ? scoresq[gc] : 0.f;
#pragma unroll
            for (int r = 0; r < 4; r++) {
                const size_t o = (size_t)(rb + r) * N + gc;
                float v = acc[i][j][r];
                if (scoresq) {
                    Sf[o] = sv - 2.f * v;
                } else {
                    v += bv;
                    if (resh) v += bf2f(resh[o]) + bf2f(resl[o]);
                    if (relu) v = fmaxf(v, 0.f);
                    ushort h = f2bf(v);
                    Ch[o] = h;
                    Cl[o] = f2bf(v - bf2f(h));
                }
            }
        }
}

// ---------------------------------------------------------------------------
// Split-bf16 GEMM with f32 operands (x-path / predictor; small M)
// ---------------------------------------------------------------------------
__device__ __forceinline__ void load16(const float* p, float* x) {
    *(float4*)(x)      = *(const float4*)(p);
    *(float4*)(x + 4)  = *(const float4*)(p + 4);
    *(float4*)(x + 8)  = *(const float4*)(p + 8);
    *(float4*)(x + 12) = *(const float4*)(p + 12);
}
__device__ __forceinline__ void write_split(const float* x, ushort* Ph,
                                            ushort* Pl, int m, int cp2) {
    short8 h0, h1, l0, l1;
#pragma unroll
    for (int i = 0; i < 8; i++) {
        ushort h = f2bf(x[i]);
        h0[i] = (short)h;
        l0[i] = (short)f2bf(x[i] - bf2f(h));
        ushort g = f2bf(x[i + 8]);
        h1[i] = (short)g;
        l1[i] = (short)f2bf(x[i + 8] - bf2f(g));
    }
    *(short8*)(Ph + lds_off(m, cp2))     = h0;
    *(short8*)(Ph + lds_off(m, cp2 + 1)) = h1;
    *(short8*)(Pl + lds_off(m, cp2))     = l0;
    *(short8*)(Pl + lds_off(m, cp2 + 1)) = l1;
}

__global__ __launch_bounds__(256) void gemm_split_nt(
    const float* __restrict__ A, const float* __restrict__ BT,
    const float* __restrict__ bias, const float* res,
    float* C, int M, int N, int K, int relu)
{
    __shared__ ushort Ah[128 * 32], Al[128 * 32];
    __shared__ ushort Bh[128 * 32], Bl[128 * 32];
    const int tid = threadIdx.x;
    const int lane = tid & 63, wid = tid >> 6;
    const int wm = (wid & 1) * 64, wn = (wid >> 1) * 64;
    const int lane15 = lane & 15, quad = lane >> 4;
    const int row0 = blockIdx.y * 128, col0 = blockIdx.x * 128;
    const int sm = tid >> 1, scp = (tid & 1) * 2;

    const float* arow = A + (size_t)(row0 + sm) * K + scp * 8;
    const float* brow = BT + (size_t)(col0 + sm) * K + scp * 8;

    floatx4 acc[4][4];
#pragma unroll
    for (int i = 0; i < 4; i++)
#pragma unroll
        for (int j = 0; j < 4; j++) acc[i][j] = (floatx4){0.f, 0.f, 0.f, 0.f};

    for (int k0 = 0; k0 < K; k0 += 32) {
        float xa[16], xb[16];
        load16(arow + k0, xa);
        load16(brow + k0, xb);
        __syncthreads();
        write_split(xa, Ah, Al, sm, scp);
        write_split(xb, Bh, Bl, sm, scp);
        __syncthreads();

        short8 ah[4], al[4], bh[4], bl[4];
#pragma unroll
        for (int t = 0; t < 4; t++) {
            const int am = wm + t * 16 + lane15;
            const int bn = wn + t * 16 + lane15;
            ah[t] = *(const short8*)(Ah + lds_off(am, quad));
            al[t] = *(const short8*)(Al + lds_off(am, quad));
            bh[t] = *(const short8*)(Bh + lds_off(bn, quad));
            bl[t] = *(const short8*)(Bl + lds_off(bn, quad));
        }
#pragma unroll
        for (int i = 0; i < 4; i++)
#pragma unroll
            for (int j = 0; j < 4; j++) {
                acc[i][j] = __builtin_amdgcn_mfma_f32_16x16x32_bf16(ah[i], bh[j], acc[i][j], 0, 0, 0);
                acc[i][j] = __builtin_amdgcn_mfma_f32_16x16x32_bf16(ah[i], bl[j], acc[i][j], 0, 0, 0);
                acc[i][j] = __builtin_amdgcn_mfma_f32_16x16x32_bf16(al[i], bh[j], acc[i][j], 0, 0, 0);
            }
    }

#pragma unroll
    for (int i = 0; i < 4; i++)
#pragma unroll
        for (int j = 0; j < 4; j++) {
            const int gc = col0 + wn + j * 16 + lane15;
            const int rb = row0 + wm + i * 16 + quad * 4;
            const float bv = bias ? bias[gc] : 0.f;
#pragma unroll
            for (int r = 0; r < 4; r++) {
                const size_t o = (size_t)(rb + r) * N + gc;
                float v = acc[i][j][r] + bv;
                if (res) v += res[o];
                if (relu) v = fmaxf(v, 0.f);
                C[o] = v;
            }
        }
}

// ---------------------------------------------------------------------------
// Values MLP layer 1: A row r = kx[r/96,:](f32) - ck[idx[r],:](planes)
// B = t1 hi plane (global_load_lds). TT = bf16(relu(A @ B^T + bias))
// ---------------------------------------------------------------------------
__global__ __launch_bounds__(256) void gemm_diff_bf16(
    const float* __restrict__ kx,
    const ushort* __restrict__ ckh, const ushort* __restrict__ ckl,
    const int* __restrict__ idx, const ushort* __restrict__ BTh,
    const float* __restrict__ bias, ushort* __restrict__ TT,
    int M, int N, int K)
{
    __shared__ ushort Ah[128 * 32];
    __shared__ ushort Bh[128 * 32];
    const int tid = threadIdx.x;
    const int lane = tid & 63, wid = tid >> 6;
    const int wm = (wid & 1) * 64, wn = (wid >> 1) * 64;
    const int lane15 = lane & 15, quad = lane >> 4;
    const int row0 = blockIdx.y * 128, col0 = blockIdx.x * 128;
    const int sm = tid >> 1, scp = (tid & 1) * 2;

    const int r = row0 + sm;
    const int bidx = r / NC;
    const float*  kxp = kx  + (size_t)bidx * ND + scp * 8;
    const ushort* chp = ckh + (size_t)idx[r] * ND + scp * 8;
    const ushort* clp = ckl + (size_t)idx[r] * ND + scp * 8;

    const int srow = tid >> 2;
    const int scl  = tid & 3;
    const int cp   = (scl - (srow >> 1)) & 3;
    const size_t gb0 = (size_t)(col0 + srow) * K + cp * 8;
    const size_t gb1 = (size_t)(col0 + 64 + srow) * K + cp * 8;
    const int l0 = tid * 8, l1 = 2048 + tid * 8;

    floatx4 acc[4][4];
#pragma unroll
    for (int i = 0; i < 4; i++)
#pragma unroll
        for (int j = 0; j < 4; j++) acc[i][j] = (floatx4){0.f, 0.f, 0.f, 0.f};

    for (int k0 = 0; k0 < K; k0 += 32) {
        float xa[16];
        load16(kxp + k0, xa);
        short8 h0 = *(const short8*)(chp + k0);
        short8 h1 = *(const short8*)(chp + k0 + 8);
        short8 lo0 = *(const short8*)(clp + k0);
        short8 lo1 = *(const short8*)(clp + k0 + 8);
        short8 d0, d1;
#pragma unroll
        for (int i = 0; i < 8; i++) {
            float c0 = bf2f((ushort)h0[i]) + bf2f((ushort)lo0[i]);
            float c1 = bf2f((ushort)h1[i]) + bf2f((ushort)lo1[i]);
            d0[i] = (short)f2bf(xa[i] - c0);
            d1[i] = (short)f2bf(xa[i + 8] - c1);
        }
        __syncthreads();
        gload16(BTh + gb0 + k0, Bh + l0);
        gload16(BTh + gb1 + k0, Bh + l1);
        *(short8*)(Ah + lds_off(sm, scp))     = d0;
        *(short8*)(Ah + lds_off(sm, scp + 1)) = d1;
        __syncthreads();

        short8 ah[4], bh[4];
#pragma unroll
        for (int t = 0; t < 4; t++) {
            ah[t] = *(const short8*)(Ah + lds_off(wm + t * 16 + lane15, quad));
            bh[t] = *(const short8*)(Bh + lds_off(wn + t * 16 + lane15, quad));
        }
#pragma unroll
        for (int i = 0; i < 4; i++)
#pragma unroll
            for (int j = 0; j < 4; j++)
                acc[i][j] = __builtin_amdgcn_mfma_f32_16x16x32_bf16(ah[i], bh[j], acc[i][j], 0, 0, 0);
    }

#pragma unroll
    for (int i = 0; i < 4; i++)
#pragma unroll
        for (int j = 0; j < 4; j++) {
            const int gc = col0 + wn + j * 16 + lane15;
            const int rb = row0 + wm + i * 16 + quad * 4;
            const float bv = bias[gc];
#pragma unroll
            for (int rr = 0; rr < 4; rr++) {
                const size_t o = (size_t)(rb + rr) * N + gc;
                TT[o] = f2bf(fmaxf(acc[i][j][rr] + bv, 0.f));
            }
        }
}

// ---------------------------------------------------------------------------
// Values MLP layer 2: A bf16 [M][K], B hi plane [N][K]: C(f32) = A @ B^T
// Both operands via global_load_lds.
// ---------------------------------------------------------------------------
__global__ __launch_bounds__(256) void gemm_bf16_f32(
    const ushort* __restrict__ A, const ushort* __restrict__ BTh,
    float* __restrict__ C, int M, int N, int K)
{
    __shared__ ushort Ah[128 * 32];
    __shared__ ushort Bh[128 * 32];
    const int tid = threadIdx.x;
    const int lane = tid & 63, wid = tid >> 6;
    const int wm = (wid & 1) * 64, wn = (wid >> 1) * 64;
    const int lane15 = lane & 15, quad = lane >> 4;
    const int row0 = blockIdx.y * 128, col0 = blockIdx.x * 128;

    const int srow = tid >> 2;
    const int scl  = tid & 3;
    const int cp   = (scl - (srow >> 1)) & 3;
    const size_t ga0 = (size_t)(row0 + srow) * K + cp * 8;
    const size_t ga1 = (size_t)(row0 + 64 + srow) * K + cp * 8;
    const size_t gb0 = (size_t)(col0 + srow) * K + cp * 8;
    const size_t gb1 = (size_t)(col0 + 64 + srow) * K + cp * 8;
    const int l0 = tid * 8, l1 = 2048 + tid * 8;

    floatx4 acc[4][4];
#pragma unroll
    for (int i = 0; i < 4; i++)
#pragma unroll
        for (int j = 0; j < 4; j++) acc[i][j] = (floatx4){0.f, 0.f, 0.f, 0.f};

    for (int k0 = 0; k0 < K; k0 += 32) {
        __syncthreads();
        gload16(A + ga0 + k0, Ah + l0);
        gload16(A + ga1 + k0, Ah + l1);
        gload16(BTh + gb0 + k0, Bh + l0);
        gload16(BTh + gb1 + k0, Bh + l1);
        __syncthreads();

        short8 ah[4], bh[4];
#pragma unroll
        for (int t = 0; t < 4; t++) {
            ah[t] = *(const short8*)(Ah + lds_off(wm + t * 16 + lane15, quad));
            bh[t] = *(const short8*)(Bh + lds_off(wn + t * 16 + lane15, quad));
        }
#pragma unroll
        for (int i = 0; i < 4; i++)
#pragma unroll
            for (int j = 0; j < 4; j++)
                acc[i][j] = __builtin_amdgcn_mfma_f32_16x16x32_bf16(ah[i], bh[j], acc[i][j], 0, 0, 0);
    }

#pragma unroll
    for (int i = 0; i < 4; i++)
#pragma unroll
        for (int j = 0; j < 4; j++) {
            const int gc = col0 + wn + j * 16 + lane15;
            const int rb = row0 + wm + i * 16 + quad * 4;
#pragma unroll
            for (int rr = 0; rr < 4; rr++)
                C[(size_t)(rb + rr) * N + gc] = acc[i][j][rr];
        }
}

// ---------------------------------------------------------------------------
// Prep kernels
// ---------------------------------------------------------------------------
__global__ __launch_bounds__(256) void transpose_kernel(
    const float* __restrict__ W, float* __restrict__ WT, int K, int N)
{
    const int o = blockIdx.x * 256 + threadIdx.x;
    if (o < K * N) {
        const int n = o / K, k = o - n * K;
        WT[o] = W[(size_t)k * N + n];
    }
}

__global__ __launch_bounds__(256) void split_wt_kernel(
    const float* __restrict__ W, ushort* __restrict__ WTh,
    ushort* __restrict__ WTl, int K, int N)
{
    const int o = blockIdx.x * 256 + threadIdx.x;
    if (o < K * N) {
        const int n = o / K, k = o - n * K;
        const float x = W[(size_t)k * N + n];
        const ushort h = f2bf(x);
        WTh[o] = h;
        WTl[o] = f2bf(x - bf2f(h));
    }
}

__global__ __launch_bounds__(256) void split_pl_kernel(
    const float* __restrict__ X, ushort* __restrict__ Xh,
    ushort* __restrict__ Xl, int n)
{
    const int i = blockIdx.x * 256 + threadIdx.x;
    if (i < n) {
        const float x = X[i];
        const ushort h = f2bf(x);
        Xh[i] = h;
        Xl[i] = f2bf(x - bf2f(h));
    }
}

// ---------------------------------------------------------------------------
// LayerNorm rows of 512, f32 in / f32 out (x-path)
// ---------------------------------------------------------------------------
__global__ __launch_bounds__(256) void ln_kernel(
    const float* __restrict__ X, const float* __restrict__ g,
    const float* __restrict__ b, float* __restrict__ Y, int relu)
{
    const int lane = threadIdx.x & 63;
    const int row  = blockIdx.x * 4 + (threadIdx.x >> 6);
    const float* x = X + (size_t)row * ND;
    const int d = lane * 8;

    float4 v0 = *(const float4*)(x + d);
    float4 v1 = *(const float4*)(x + d + 4);
    float s = v0.x + v0.y + v0.z + v0.w + v1.x + v1.y + v1.z + v1.w;
    float q = v0.x*v0.x + v0.y*v0.y + v0.z*v0.z + v0.w*v0.w
            + v1.x*v1.x + v1.y*v1.y + v1.z*v1.z + v1.w*v1.w;
#pragma unroll
    for (int off = 32; off; off >>= 1) {
        s += __shfl_down(s, off);
        q += __shfl_down(q, off);
    }
    s = __shfl(s, 0); q = __shfl(q, 0);
    const float mean = s * (1.f / ND);
    const float var  = q * (1.f / ND) - mean * mean;
    const float rs   = rsqrtf(var + 1e-5f);

    float4 g0 = *(const float4*)(g + d);
    float4 g1 = *(const float4*)(g + d + 4);
    float4 b0 = *(const float4*)(b + d);
    float4 b1 = *(const float4*)(b + d + 4);
    float4 o0, o1;
    o0.x = (v0.x - mean) * rs * g0.x + b0.x;
    o0.y = (v0.y - mean) * rs * g0.y + b0.y;
    o0.z = (v0.z - mean) * rs * g0.z + b0.z;
    o0.w = (v0.w - mean) * rs * g0.w + b0.w;
    o1.x = (v1.x - mean) * rs * g1.x + b1.x;
    o1.y = (v1.y - mean) * rs * g1.y + b1.y;
    o1.z = (v1.z - mean) * rs * g1.z + b1.z;
    o1.w = (v1.w - mean) * rs * g1.w + b1.w;
    if (relu) {
        o0.x = fmaxf(o0.x, 0.f); o0.y = fmaxf(o0.y, 0.f);
        o0.z = fmaxf(o0.z, 0.f); o0.w = fmaxf(o0.w, 0.f);
        o1.x = fmaxf(o1.x, 0.f); o1.y = fmaxf(o1.y, 0.f);
        o1.z = fmaxf(o1.z, 0.f); o1.w = fmaxf(o1.w, 0.f);
    }
    float* y = Y + (size_t)row * ND;
    *(float4*)(y + d)     = o0;
    *(float4*)(y + d + 4) = o1;
}

// LayerNorm rows of 512, planes in / planes out (candidate encode)
__global__ __launch_bounds__(256) void ln_pl_kernel(
    const ushort* __restrict__ Xh, const ushort* __restrict__ Xl,
    const float* __restrict__ g, const float* __restrict__ b,
    ushort* __restrict__ Yh, ushort* __restrict__ Yl)
{
    const int lane = threadIdx.x & 63;
    const int row  = blockIdx.x * 4 + (threadIdx.x >> 6);
    const int d = lane * 8;
    const size_t base = (size_t)row * ND + d;

    short8 xh = *(const short8*)(Xh + base);
    short8 xl = *(const short8*)(Xl + base);
    float v[8];
#pragma unroll
    for (int i = 0; i < 8; i++) v[i] = bf2f((ushort)xh[i]) + bf2f((ushort)xl[i]);

    float s = 0.f, q = 0.f;
#pragma unroll
    for (int i = 0; i < 8; i++) { s += v[i]; q += v[i] * v[i]; }
#pragma unroll
    for (int off = 32; off; off >>= 1) {
        s += __shfl_down(s, off);
        q += __shfl_down(q, off);
    }
    s = __shfl(s, 0); q = __shfl(q, 0);
    const float mean = s * (1.f / ND);
    const float var  = q * (1.f / ND) - mean * mean;
    const float rs   = rsqrtf(var + 1e-5f);

    short8 yh, yl;
#pragma unroll
    for (int i = 0; i < 8; i++) {
        const float o = (v[i] - mean) * rs * g[d + i] + b[d + i];
        const ushort h = f2bf(o);
        yh[i] = (short)h;
        yl[i] = (short)f2bf(o - bf2f(h));
    }
    *(short8*)(Yh + base) = yh;
    *(short8*)(Yl + base) = yl;
}

__global__ __launch_bounds__(256) void sqnorm_pl_kernel(
    const ushort* __restrict__ Xh, const ushort* __restrict__ Xl,
    float* __restrict__ sq)
{
    const int lane = threadIdx.x & 63;
    const int row  = blockIdx.x * 4 + (threadIdx.x >> 6);
    const size_t base = (size_t)row * ND + lane * 8;
    short8 xh = *(const short8*)(Xh + base);
    short8 xl = *(const short8*)(Xl + base);
    float q = 0.f;
#pragma unroll
    for (int i = 0; i < 8; i++) {
        float v = bf2f((ushort)xh[i]) + bf2f((ushort)xl[i]);
        q += v * v;
    }
#pragma unroll
    for (int off = 32; off; off >>= 1) q += __shfl_down(q, off);
    if (lane == 0) sq[row] = q;
}

// ---------------------------------------------------------------------------
// Two-stage exact top-96: adaptive-range radix select.
// ---------------------------------------------------------------------------
__device__ __forceinline__ unsigned fkey(float f)
{
    unsigned u = __float_as_uint(f);
    return (u & 0x80000000u) ? ~u : (u | 0x80000000u);
}
__device__ __forceinline__ float inv_fkey(unsigned u)
{
    return __uint_as_float((u & 0x80000000u) ? (u & 0x7FFFFFFFu) : ~u);
}

struct SelState {
    unsigned lo;
    unsigned long long hi;   // exclusive
    int krem;
    int done;
    unsigned long long T;    // threshold
    int need;                // how many keys == T to take
};

template <int KPT>
__device__ __forceinline__ void adaptive_select(
    const unsigned (&key)[KPT], unsigned* hist, unsigned* wtot,
    SelState* st, int tid, int kwant)
{
    const int lane = tid & 63, wid = tid >> 6;

    unsigned mn = 0xFFFFFFFFu, mx = 0u;
#pragma unroll
    for (int j = 0; j < KPT; j++) {
        mn = min(mn, key[j]);
        mx = max(mx, key[j]);
    }
#pragma unroll
    for (int off = 32; off; off >>= 1) {
        mn = min(mn, (unsigned)__shfl_down((int)mn, off));
        mx = max(mx, (unsigned)__shfl_down((int)mx, off));
    }
    if (lane == 0) { hist[wid] = mn; hist[8 + wid] = mx; }
    if (tid == 0) st->done = 0;
    __syncthreads();
    if (tid == 0) {
        unsigned gmn = min(min(hist[0], hist[1]), min(hist[2], hist[3]));
        unsigned gmx = max(max(hist[8], hist[9]), max(hist[10], hist[11]));
        st->lo = gmn;
        st->hi = (unsigned long long)gmx + 1ull;
        st->krem = kwant;
    }
    __syncthreads();

    for (int iter = 0; iter < 6 && !st->done; iter++) {
        const unsigned lo = st->lo;
        const unsigned long long hi = st->hi;
        const int krem = st->krem;
        const unsigned long long span = hi - lo;
        int shift = 0;
        if (span > 256ull) {
            const int nb = 64 - __builtin_clzll(span - 1ull);
            shift = nb - 8;
        }
        hist[tid] = 0u;
        __syncthreads();
#pragma unroll
        for (int j = 0; j < KPT; j++) {
            const unsigned u = key[j];
            if (u >= lo && (unsigned long long)u < hi)
                atomicAdd(&hist[(u - lo) >> shift], 1u);
        }
        __syncthreads();
        const unsigned c = hist[tid];
        unsigned v = c;
#pragma unroll
        for (int off = 1; off < 64; off <<= 1) {
            const unsigned t = (unsigned)__shfl_up((int)v, off);
            if (lane >= off) v += t;
        }
        if (lane == 63) wtot[wid] = v;
        __syncthreads();
        unsigned pre = 0;
        for (int w = 0; w < 3; w++) pre += (w < wid) ? wtot[w] : 0u;
        const int incl = (int)(v + pre);
        const int excl = incl - (int)c;
        if (excl < krem && incl >= krem) {
            const unsigned long long binlo =
                (unsigned long long)lo + ((unsigned long long)tid << shift);
            if (shift == 0) {
                st->T = binlo;
                st->need = krem - excl;
                st->done = 1;
            } else if (incl == krem) {
                st->T = binlo + (1ull << shift);
                st->need = 0;
                st->done = 1;
            } else {
                st->lo = (unsigned)binlo;
                const unsigned long long nhi = binlo + (1ull << shift);
                st->hi = nhi < hi ? nhi : hi;
                st->krem = krem - excl;
            }
        }
        __syncthreads();
    }
}

__global__ __launch_bounds__(256) void topk_seg(
    const float* __restrict__ S, unsigned* __restrict__ K1key,
    int* __restrict__ K1idx)
{
    const int r = blockIdx.y, seg = blockIdx.x;
    const float* p = S + (size_t)r * NN + seg * TK_SEG;
    __shared__ unsigned hist[256];
    __shared__ unsigned wtot[4];
    __shared__ SelState st;
    __shared__ int cA, cB;
    const int tid = threadIdx.x;

    unsigned key[16];
#pragma unroll
    for (int j = 0; j < 16; j++) key[j] = fkey(p[tid + j * 256]);

    if (tid == 0) { cA = 0; cB = 0; }
    adaptive_select<16>(key, hist, wtot, &st, tid, NC);

    const unsigned long long T = st.T;
    const int need = st.need;
    const int cntLess = NC - need;
    const size_t obase = ((size_t)r * TK_SPLIT + seg) * NC;
#pragma unroll
    for (int j = 0; j < 16; j++) {
        const unsigned u = key[j];
        if ((unsigned long long)u < T) {
            const int pos = atomicAdd(&cA, 1);
            K1key[obase + pos] = u;
            K1idx[obase + pos] = seg * TK_SEG + tid + j * 256;
        } else if ((unsigned long long)u == T) {
            const int pos = atomicAdd(&cB, 1);
            if (pos < need) {
                K1key[obase + cntLess + pos] = u;
                K1idx[obase + cntLess + pos] = seg * TK_SEG + tid + j * 256;
            }
        }
    }
}

__global__ __launch_bounds__(256) void topk_merge(
    const unsigned* __restrict__ K1key, const int* __restrict__ K1idx,
    int* __restrict__ idx_out, float* __restrict__ val_out, int b0)
{
    const int r = blockIdx.x;
    const int b = b0 + r;
    __shared__ unsigned hist[256];
    __shared__ unsigned wtot[4];
    __shared__ SelState st;
    __shared__ int cA, cB;
    const int tid = threadIdx.x;
    const size_t ibase = (size_t)r * TK_CAND;

    unsigned key[6];
    int      kidx[6];
#pragma unroll
    for (int j = 0; j < 6; j++) {
        key[j]  = K1key[ibase + tid + j * 256];
        kidx[j] = K1idx[ibase + tid + j * 256];
    }

    if (tid == 0) { cA = 0; cB = 0; }
    adaptive_select<6>(key, hist, wtot, &st, tid, NC);

    const unsigned long long T = st.T;
    const int need = st.need;
    const int cntLess = NC - need;
#pragma unroll
    for (int j = 0; j < 6; j++) {
        const unsigned u = key[j];
        if ((unsigned long long)u < T) {
            const int pos = atomicAdd(&cA, 1);
            idx_out[b * NC + pos] = kidx[j];
            val_out[b * NC + pos] = inv_fkey(u);
        } else if ((unsigned long long)u == T) {
            const int pos = atomicAdd(&cB, 1);
            if (pos < need) {
                idx_out[b * NC + cntLess + pos] = kidx[j];
                val_out[b * NC + cntLess + pos] = inv_fkey(u);
            }
        }
    }
}

// ---------------------------------------------------------------------------
__global__ __launch_bounds__(128) void probs_kernel(
    const float* __restrict__ svals, float* __restrict__ probs)
{
    const int b = blockIdx.x;
    const int tid = threadIdx.x;
    __shared__ float red[128];
    const bool valid = tid < NC;
    float s = valid ? -svals[b * NC + tid] : -3.4e38f;
    red[tid] = s;
    __syncthreads();
#pragma unroll
    for (int off = 64; off; off >>= 1) {
        if (tid < off) red[tid] = fmaxf(red[tid], red[tid + off]);
        __syncthreads();
    }
    const float m = red[0];
    __syncthreads();
    float e = valid ? expf(s - m) : 0.f;
    red[tid] = e;
    __syncthreads();
#pragma unroll
    for (int off = 64; off; off >>= 1) {
        if (tid < off) red[tid] += red[tid + off];
        __syncthreads();
    }
    const float sum = red[0];
    if (valid) probs[b * NC + tid] = e / sum;
}

__global__ __launch_bounds__(256) void ctx_kernel(
    const float* __restrict__ VAL, const float* __restrict__ probs,
    const float* __restrict__ cand_y, const int* __restrict__ idx,
    const float* __restrict__ labW, const float* __restrict__ labb,
    const float* __restrict__ xin, float* __restrict__ xout, int b0)
{
    const int b_loc = blockIdx.x;
    const int b = b0 + b_loc;
    const int tid = threadIdx.x;
    __shared__ float pv[NC];
    __shared__ float red[256];
    float py_part = 0.f;
    if (tid < NC) {
        float p = probs[b * NC + tid];
        pv[tid] = p;
        py_part = p * cand_y[idx[b * NC + tid]];
    }
    red[tid] = py_part;
    __syncthreads();
#pragma unroll
    for (int off = 128; off; off >>= 1) {
        if (tid < off) red[tid] += red[tid + off];
        __syncthreads();
    }
    const float py = red[0];

    for (int d = tid; d < ND; d += 256) {
        const float* vp = VAL + (size_t)b_loc * NC * ND + d;
        float acc = 0.f;
#pragma unroll 8
        for (int c = 0; c < NC; c++) acc += pv[c] * vp[(size_t)c * ND];
        float ctx = acc + py * labW[d] + labb[d];
        xout[(size_t)b * ND + d] = xin[(size_t)b * ND + d] + ctx;
    }
}

__global__ __launch_bounds__(64) void head_kernel(
    const float* __restrict__ X, const float* __restrict__ hW,
    const float* __restrict__ hb, float* __restrict__ out)
{
    const int b = blockIdx.x;
    const int lane = threadIdx.x;
    const float* x = X + (size_t)b * ND;
    float acc = 0.f;
#pragma unroll
    for (int j = 0; j < 8; j++) {
        int d = lane + 64 * j;
        acc += x[d] * hW[d];
    }
#pragma unroll
    for (int off = 32; off; off >>= 1) acc += __shfl_down(acc, off);
    if (lane == 0) out[b] = acc + hb[0];
}

// ---------------------------------------------------------------------------
extern "C" void kernel_launch(void* const* d_in, const int* in_sizes, int n_in,
                              void* d_out, int out_size, void* d_ws, size_t ws_size,
                              hipStream_t stream)
{
    const float* x_num    = (const float*)d_in[0];
    const float* cand_num = (const float*)d_in[1];
    const float* cand_y   = (const float*)d_in[2];
    const float* lin_W    = (const float*)d_in[3];
    const float* lin_b    = (const float*)d_in[4];
    const float* e_W1     = (const float*)d_in[5];
    const float* e_b1     = (const float*)d_in[6];
    const float* e_W2     = (const float*)d_in[7];
    const float* e_b2     = (const float*)d_in[8];
    const float* mix_g    = (const float*)d_in[9];
    const float* mix_b    = (const float*)d_in[10];
    const float* K_W      = (const float*)d_in[11];
    const float* K_b      = (const float*)d_in[12];
    const float* lab_W    = (const float*)d_in[13];
    const float* lab_b    = (const float*)d_in[14];
    const float* T_W1     = (const float*)d_in[15];
    const float* T_b1     = (const float*)d_in[16];
    const float* T_W2     = (const float*)d_in[17];
    const float* p_ln_g   = (const float*)d_in[18];
    const float* p_ln_b   = (const float*)d_in[19];
    const float* p_W1     = (const float*)d_in[20];
    const float* p_b1     = (const float*)d_in[21];
    const float* p_W2     = (const float*)d_in[22];
    const float* p_b2     = (const float*)d_in[23];
    const float* h_ln_g   = (const float*)d_in[24];
    const float* h_ln_b   = (const float*)d_in[25];
    const float* h_W      = (const float*)d_in[26];
    const float* h_b      = (const float*)d_in[27];
    float* out = (float*)d_out;
    (void)in_sizes; (void)n_in; (void)out_size; (void)ws_size;

    // ---- workspace layout (~253 MB) ----
    size_t off = 0;
    auto ralloc = [&](size_t bytes) -> void* {
        void* p = (char*)d_ws + off;
        off += (bytes + 255) & ~(size_t)255;
        return p;
    };
    auto falloc = [&](size_t n) -> float*  { return (float*)ralloc(n * 4); };
    auto ualloc = [&](size_t n) -> ushort* { return (ushort*)ralloc(n * 2); };

    float* WT_lin = falloc((size_t)ND * NF);
    float* WT_e1  = falloc((size_t)NDB * ND);
    float* WT_e2  = falloc((size_t)ND * NDB);
    float* WT_kw  = falloc((size_t)ND * ND);
    float* WT_p1  = falloc((size_t)NDB * ND);
    float* WT_p2  = falloc((size_t)ND * NDB);
    ushort* WP_lin_h = ualloc((size_t)ND * NF);
    ushort* WP_lin_l = ualloc((size_t)ND * NF);
    ushort* WP_e1_h  = ualloc((size_t)NDB * ND);
    ushort* WP_e1_l  = ualloc((size_t)NDB * ND);
    ushort* WP_e2_h  = ualloc((size_t)ND * NDB);
    ushort* WP_e2_l  = ualloc((size_t)ND * NDB);
    ushort* WP_kw_h  = ualloc((size_t)ND * ND);
    ushort* WP_kw_l  = ualloc((size_t)ND * ND);
    ushort* WP_t1_h  = ualloc((size_t)NDB * ND);
    ushort* WP_t1_l  = ualloc((size_t)NDB * ND);
    ushort* WP_t2_h  = ualloc((size_t)ND * NDB);
    ushort* WP_t2_l  = ualloc((size_t)ND * NDB);

    ushort* R_CKh = ualloc((size_t)NN * ND);
    ushort* R_CKl = ualloc((size_t)NN * ND);
    float*  R_sq  = falloc(NN);
    float*  R_Hx  = falloc((size_t)NB * ND);
    float*  R_Tx  = falloc((size_t)NB * NDB);
    float*  R_Gx  = falloc((size_t)NB * ND);
    float*  R_kx  = falloc((size_t)NB * ND);
    ushort* R_kxh = ualloc((size_t)NB * ND);
    ushort* R_kxl = ualloc((size_t)NB * ND);
    int*    R_idx = (int*)ralloc((size_t)NB * NC * 4);
    float*  R_ssel= falloc((size_t)NB * NC);
    float*  R_prob= falloc((size_t)NB * NC);
    float*  R_xupd= falloc((size_t)NB * ND);
    float*  R_lnx = falloc((size_t)NB * ND);
    float*  R_tp  = falloc((size_t)NB * NDB);
    float*  R_x2  = falloc((size_t)NB * ND);
    float*  R_lnx2= falloc((size_t)NB * ND);
    unsigned* K1key = (unsigned*)ralloc((size_t)BB_C * TK_CAND * 4);
    int*      K1idx = (int*)ralloc((size_t)BB_C * TK_CAND * 4);
    char* SCR = (char*)ralloc((size_t)70 * 1024 * 1024);

    // ---- 0. weight prep ----
    auto tr = [&](const float* W, float* WT, int K, int N) {
        transpose_kernel<<<dim3((K * N + 255) / 256), dim3(256), 0, stream>>>(W, WT, K, N);
    };
    auto sw = [&](const float* W, ushort* WTh, ushort* WTl, int K, int N) {
        split_wt_kernel<<<dim3((K * N + 255) / 256), dim3(256), 0, stream>>>(W, WTh, WTl, K, N);
    };
    tr(lin_W, WT_lin, NF, ND);
    tr(e_W1,  WT_e1,  ND, NDB);
    tr(e_W2,  WT_e2,  NDB, ND);
    tr(K_W,   WT_kw,  ND, ND);
    tr(p_W1,  WT_p1,  ND, NDB);
    tr(p_W2,  WT_p2,  NDB, ND);
    sw(lin_W, WP_lin_h, WP_lin_l, NF, ND);
    sw(e_W1,  WP_e1_h,  WP_e1_l,  ND, NDB);
    sw(e_W2,  WP_e2_h,  WP_e2_l,  NDB, ND);
    sw(K_W,   WP_kw_h,  WP_kw_l,  ND, ND);
    sw(T_W1,  WP_t1_h,  WP_t1_l,  ND, NDB);
    sw(T_W2,  WP_t2_h,  WP_t2_l,  NDB, ND);

    auto gss = [&](const ushort* Ah, const ushort* Al, const ushort* Bh,
                   const ushort* Bl, const float* bias, const ushort* resh,
                   const ushort* resl, const float* sq, float* Sf,
                   ushort* Ch, ushort* Cl, int M, int Nn, int K, int relu) {
        gemm_ss<<<dim3(Nn / 128, M / 128), dim3(256), 0, stream>>>(
            Ah, Al, Bh, Bl, bias, resh, resl, sq, Sf, Ch, Cl, M, Nn, K, relu);
    };
    auto gsplit = [&](const float* A, const float* BT, const float* bias,
                      const float* res, float* C, int M, int Nn, int K, int relu) {
        gemm_split_nt<<<dim3(Nn / 128, M / 128), dim3(256), 0, stream>>>(
            A, BT, bias, res, C, M, Nn, K, relu);
    };

    // ---- 1. candidate encode (chunked; plane operands, split-bf16 MFMA) ----
    {
        ushort* CNh = (ushort*)SCR;
        ushort* CNl = CNh + (size_t)CH_A * NF;
        ushort* Hh  = CNl + (size_t)CH_A * NF;
        ushort* Hl  = Hh  + (size_t)CH_A * ND;
        ushort* Th  = Hl  + (size_t)CH_A * ND;
        ushort* Tl  = Th  + (size_t)CH_A * NDB;
        ushort* H2h = Tl  + (size_t)CH_A * NDB;
        ushort* H2l = H2h + (size_t)CH_A * ND;
        ushort* Gh  = Th;   // overlay: T dead after e2
        ushort* Gl  = Tl;

        for (int n0 = 0; n0 < NN; n0 += CH_A) {
            split_pl_kernel<<<dim3((CH_A * NF + 255) / 256), dim3(256), 0, stream>>>(
                cand_num + (size_t)n0 * NF, CNh, CNl, CH_A * NF);
            gss(CNh, CNl, WP_lin_h, WP_lin_l, lin_b, nullptr, nullptr, nullptr,
                nullptr, Hh, Hl, CH_A, ND, NF, 0);
            gss(Hh, Hl, WP_e1_h, WP_e1_l, e_b1, nullptr, nullptr, nullptr,
                nullptr, Th, Tl, CH_A, NDB, ND, 1);
            gss(Th, Tl, WP_e2_h, WP_e2_l, e_b2, Hh, Hl, nullptr,
                nullptr, H2h, H2l, CH_A, ND, NDB, 0);
            ln_pl_kernel<<<dim3(CH_A / 4), dim3(256), 0, stream>>>(
                H2h, H2l, mix_g, mix_b, Gh, Gl);
            gss(Gh, Gl, WP_kw_h, WP_kw_l, K_b, nullptr, nullptr, nullptr,
                nullptr, R_CKh + (size_t)n0 * ND, R_CKl + (size_t)n0 * ND,
                CH_A, ND, ND, 0);
            sqnorm_pl_kernel<<<dim3(CH_A / 4), dim3(256), 0, stream>>>(
                R_CKh + (size_t)n0 * ND, R_CKl + (size_t)n0 * ND, R_sq + n0);
        }
    }

    // ---- 2. x encode (f32-operand split kernel; small) ----
    gsplit(x_num, WT_lin, lin_b, nullptr, R_Hx, NB, ND, NF, 0);
    gsplit(R_Hx, WT_e1, e_b1, nullptr, R_Tx, NB, NDB, ND, 1);
    gsplit(R_Tx, WT_e2, e_b2, R_Hx, R_Hx, NB, ND, NDB, 0);
    ln_kernel<<<dim3(NB / 4), dim3(256), 0, stream>>>(R_Hx, mix_g, mix_b, R_Gx, 0);
    gsplit(R_Gx, WT_kw, K_b, nullptr, R_kx, NB, ND, ND, 0);
    split_pl_kernel<<<dim3((NB * ND + 255) / 256), dim3(256), 0, stream>>>(
        R_kx, R_kxh, R_kxl, NB * ND);

    // ---- 3. scores + two-stage top-96 + softmax ----
    for (int b0 = 0; b0 < NB; b0 += BB_C) {
        float* S = (float*)SCR;
        gss(R_kxh + (size_t)b0 * ND, R_kxl + (size_t)b0 * ND, R_CKh, R_CKl,
            nullptr, nullptr, nullptr, R_sq, S, nullptr, nullptr,
            BB_C, NN, ND, 0);
        topk_seg<<<dim3(TK_SPLIT, BB_C), dim3(256), 0, stream>>>(S, K1key, K1idx);
        topk_merge<<<dim3(BB_C), dim3(256), 0, stream>>>(K1key, K1idx,
                                                         R_idx, R_ssel, b0);
    }
    probs_kernel<<<dim3(NB), dim3(128), 0, stream>>>(R_ssel, R_prob);

    // ---- 4. values path (plain bf16 MFMA, diff fused) ----
    for (int b0 = 0; b0 < NB; b0 += BB_D) {
        ushort* TT = (ushort*)SCR;                                  // [M,1024] bf16
        float* VAL = (float*)(SCR + (size_t)BB_D * NC * NDB * 2);   // f32 after TT
        const int M = BB_D * NC;   // 12288
        gemm_diff_bf16<<<dim3(NDB / 128, M / 128), dim3(256), 0, stream>>>(
            R_kx + (size_t)b0 * ND, R_CKh, R_CKl, R_idx + b0 * NC,
            WP_t1_h, T_b1, TT, M, NDB, ND);
        gemm_bf16_f32<<<dim3(ND / 128, M / 128), dim3(256), 0, stream>>>(
            TT, WP_t2_h, VAL, M, ND, NDB);
        ctx_kernel<<<dim3(BB_D), dim3(256), 0, stream>>>(
            VAL, R_prob, cand_y, R_idx, lab_W, lab_b, R_Hx, R_xupd, b0);
    }

    // ---- 5. predictor block + head ----
    ln_kernel<<<dim3(NB / 4), dim3(256), 0, stream>>>(R_xupd, p_ln_g, p_ln_b, R_lnx, 0);
    gsplit(R_lnx, WT_p1, p_b1, nullptr, R_tp, NB, NDB, ND, 1);
    gsplit(R_tp, WT_p2, p_b2, R_xupd, R_x2, NB, ND, NDB, 0);
    ln_kernel<<<dim3(NB / 4), dim3(256), 0, stream>>>(R_x2, h_ln_g, h_ln_b, R_lnx2, 1);
    head_kernel<<<dim3(NB), dim3(64), 0, stream>>>(R_lnx2, h_W, h_b, out);
}

// Round 10
// 3032.847 us; speedup vs baseline: 1.2945x; 1.0525x over previous
//
#include <hip/hip_runtime.h>

// Problem constants
#define NB   1024
#define NN   65536
#define NF   64
#define ND   512
#define NDB  1024
#define NC   96

// Chunking
#define CH_A 8192      // candidate-encode chunk rows
#define BB_C 256       // scores/topk chunk of B rows
#define BB_D 128       // values-path chunk of B rows

// top-k segmentation
#define TK_SPLIT 16
#define TK_SEG   (NN / TK_SPLIT)   // 4096
#define TK_CAND  (TK_SPLIT * NC)   // 1536

typedef unsigned short ushort;
typedef __attribute__((ext_vector_type(8))) short short8;
typedef __attribute__((ext_vector_type(4))) float floatx4;

__device__ __forceinline__ ushort f2bf(float f) {   // RNE f32->bf16
    unsigned u = __float_as_uint(f);
    u += 0x7fffu + ((u >> 16) & 1u);
    return (ushort)(u >> 16);
}
__device__ __forceinline__ float bf2f(ushort h) {
    return __uint_as_float(((unsigned)h) << 16);
}
// LDS plane: [m][k] bf16, k-stride 32, 16B-chunk XOR swizzle -> conflict-free
__device__ __forceinline__ int lds_off(int m, int c) {
    return m * 32 + (((c + (m >> 1)) & 3) << 3);
}

// async global->LDS 16B
__device__ __forceinline__ void gload16(const ushort* g, ushort* l)
{
    void* gv = (void*)g;
    void* lv = (void*)l;
    __builtin_amdgcn_global_load_lds(
        (__attribute__((address_space(1))) void*)gv,
        (__attribute__((address_space(3))) void*)lv, 16, 0, 0);
}

// ---------------------------------------------------------------------------
// Split-plane MFMA GEMM (f32-emulating, 3 MFMA), NT, 128x128 tile.
// Staging: global_load_lds w=16, inverse-swizzled global chunk index.
// Epilogue: scoresq ? Sf = scoresq[n]-2*acc : v=acc+bias(+res)(relu) -> planes
// ---------------------------------------------------------------------------
__global__ __launch_bounds__(256) void gemm_ss(
    const ushort* __restrict__ Ah_g, const ushort* __restrict__ Al_g,
    const ushort* __restrict__ Bh_g, const ushort* __restrict__ Bl_g,
    const float* __restrict__ bias,
    const ushort* __restrict__ resh, const ushort* __restrict__ resl,
    const float* __restrict__ scoresq, float* __restrict__ Sf,
    ushort* __restrict__ Ch, ushort* __restrict__ Cl,
    int M, int N, int K, int relu)
{
    __shared__ ushort Ah[128 * 32], Al[128 * 32];
    __shared__ ushort Bh[128 * 32], Bl[128 * 32];
    const int tid = threadIdx.x;
    const int lane = tid & 63, wid = tid >> 6;
    const int wm = (wid & 1) * 64, wn = (wid >> 1) * 64;
    const int lane15 = lane & 15, quad = lane >> 4;
    const int row0 = blockIdx.y * 128, col0 = blockIdx.x * 128;

    const int srow = tid >> 2;
    const int scl  = tid & 3;
    const int cp   = (scl - (srow >> 1)) & 3;
    const size_t ga0 = (size_t)(row0 + srow) * K + cp * 8;
    const size_t ga1 = (size_t)(row0 + 64 + srow) * K + cp * 8;
    const size_t gb0 = (size_t)(col0 + srow) * K + cp * 8;
    const size_t gb1 = (size_t)(col0 + 64 + srow) * K + cp * 8;
    const int l0 = tid * 8;
    const int l1 = 2048 + tid * 8;

    floatx4 acc[4][4];
#pragma unroll
    for (int i = 0; i < 4; i++)
#pragma unroll
        for (int j = 0; j < 4; j++) acc[i][j] = (floatx4){0.f, 0.f, 0.f, 0.f};

    for (int k0 = 0; k0 < K; k0 += 32) {
        __syncthreads();
        gload16(Ah_g + ga0 + k0, Ah + l0);
        gload16(Ah_g + ga1 + k0, Ah + l1);
        gload16(Al_g + ga0 + k0, Al + l0);
        gload16(Al_g + ga1 + k0, Al + l1);
        gload16(Bh_g + gb0 + k0, Bh + l0);
        gload16(Bh_g + gb1 + k0, Bh + l1);
        gload16(Bl_g + gb0 + k0, Bl + l0);
        gload16(Bl_g + gb1 + k0, Bl + l1);
        __syncthreads();

        short8 ah[4], al[4], bh[4], bl[4];
#pragma unroll
        for (int t = 0; t < 4; t++) {
            const int am = wm + t * 16 + lane15;
            const int bn = wn + t * 16 + lane15;
            ah[t] = *(const short8*)(Ah + lds_off(am, quad));
            al[t] = *(const short8*)(Al + lds_off(am, quad));
            bh[t] = *(const short8*)(Bh + lds_off(bn, quad));
            bl[t] = *(const short8*)(Bl + lds_off(bn, quad));
        }
#pragma unroll
        for (int i = 0; i < 4; i++)
#pragma unroll
            for (int j = 0; j < 4; j++) {
                acc[i][j] = __builtin_amdgcn_mfma_f32_16x16x32_bf16(ah[i], bh[j], acc[i][j], 0, 0, 0);
                acc[i][j] = __builtin_amdgcn_mfma_f32_16x16x32_bf16(ah[i], bl[j], acc[i][j], 0, 0, 0);
                acc[i][j] = __builtin_amdgcn_mfma_f32_16x16x32_bf16(al[i], bh[j], acc[i][j], 0, 0, 0);
            }
    }

    // C/D layout: col=lane&15, row=quad*4+reg  [m89]
#pragma unroll
    for (int i = 0; i < 4; i++)
#pragma unroll
        for (int j = 0; j < 4; j++) {
            const int gc = col0 + wn + j * 16 + lane15;
            const int rb = row0 + wm + i * 16 + quad * 4;
            const float bv = bias ? bias[gc] : 0.f;
            const float sv = scoresq ? scoresq[gc] : 0.f;
#pragma unroll
            for (int r = 0; r < 4; r++) {
                const size_t o = (size_t)(rb + r) * N + gc;
                float v = acc[i][j][r];
                if (scoresq) {
                    Sf[o] = sv - 2.f * v;
                } else {
                    v += bv;
                    if (resh) v += bf2f(resh[o]) + bf2f(resl[o]);
                    if (relu) v = fmaxf(v, 0.f);
                    ushort h = f2bf(v);
                    Ch[o] = h;
                    Cl[o] = f2bf(v - bf2f(h));
                }
            }
        }
}

// ---------------------------------------------------------------------------
// Small-M split-plane GEMM: 64x64 tile (4-8x more blocks for M<=1024 shapes).
// Same plane math; flexible epilogue: bias, res (planes or f32), relu,
// out planes and/or f32.
// ---------------------------------------------------------------------------
__global__ __launch_bounds__(256) void gemm_ss_small(
    const ushort* __restrict__ Ah_g, const ushort* __restrict__ Al_g,
    const ushort* __restrict__ Bh_g, const ushort* __restrict__ Bl_g,
    const float* __restrict__ bias,
    const ushort* __restrict__ resh, const ushort* __restrict__ resl,
    const float* __restrict__ resf,
    ushort* __restrict__ Ch, ushort* __restrict__ Cl,
    float* __restrict__ outf,
    int M, int N, int K, int relu)
{
    __shared__ ushort Ah[64 * 32], Al[64 * 32];
    __shared__ ushort Bh[64 * 32], Bl[64 * 32];
    const int tid = threadIdx.x;
    const int lane = tid & 63, wid = tid >> 6;
    const int wm = (wid & 1) * 32, wn = (wid >> 1) * 32;
    const int lane15 = lane & 15, quad = lane >> 4;
    const int row0 = blockIdx.y * 64, col0 = blockIdx.x * 64;

    const int srow = tid >> 2;          // 0..63
    const int scl  = tid & 3;
    const int cp   = (scl - (srow >> 1)) & 3;
    const size_t ga = (size_t)(row0 + srow) * K + cp * 8;
    const size_t gb = (size_t)(col0 + srow) * K + cp * 8;
    const int l = tid * 8;

    floatx4 acc[2][2];
#pragma unroll
    for (int i = 0; i < 2; i++)
#pragma unroll
        for (int j = 0; j < 2; j++) acc[i][j] = (floatx4){0.f, 0.f, 0.f, 0.f};

    for (int k0 = 0; k0 < K; k0 += 32) {
        __syncthreads();
        gload16(Ah_g + ga + k0, Ah + l);
        gload16(Al_g + ga + k0, Al + l);
        gload16(Bh_g + gb + k0, Bh + l);
        gload16(Bl_g + gb + k0, Bl + l);
        __syncthreads();

        short8 ah[2], al[2], bh[2], bl[2];
#pragma unroll
        for (int t = 0; t < 2; t++) {
            const int am = wm + t * 16 + lane15;
            const int bn = wn + t * 16 + lane15;
            ah[t] = *(const short8*)(Ah + lds_off(am, quad));
            al[t] = *(const short8*)(Al + lds_off(am, quad));
            bh[t] = *(const short8*)(Bh + lds_off(bn, quad));
            bl[t] = *(const short8*)(Bl + lds_off(bn, quad));
        }
#pragma unroll
        for (int i = 0; i < 2; i++)
#pragma unroll
            for (int j = 0; j < 2; j++) {
                acc[i][j] = __builtin_amdgcn_mfma_f32_16x16x32_bf16(ah[i], bh[j], acc[i][j], 0, 0, 0);
                acc[i][j] = __builtin_amdgcn_mfma_f32_16x16x32_bf16(ah[i], bl[j], acc[i][j], 0, 0, 0);
                acc[i][j] = __builtin_amdgcn_mfma_f32_16x16x32_bf16(al[i], bh[j], acc[i][j], 0, 0, 0);
            }
    }

#pragma unroll
    for (int i = 0; i < 2; i++)
#pragma unroll
        for (int j = 0; j < 2; j++) {
            const int gc = col0 + wn + j * 16 + lane15;
            const int rb = row0 + wm + i * 16 + quad * 4;
            const float bv = bias ? bias[gc] : 0.f;
#pragma unroll
            for (int r = 0; r < 2 * 2; r++) { }
#pragma unroll
            for (int r = 0; r < 4; r++) {
                const size_t o = (size_t)(rb + r) * N + gc;
                float v = acc[i][j][r] + bv;
                if (resh) v += bf2f(resh[o]) + bf2f(resl[o]);
                if (resf) v += resf[o];
                if (relu) v = fmaxf(v, 0.f);
                if (outf) outf[o] = v;
                if (Ch) {
                    ushort h = f2bf(v);
                    Ch[o] = h;
                    Cl[o] = f2bf(v - bf2f(h));
                }
            }
        }
}

// ---------------------------------------------------------------------------
// Values MLP layer 1: A row r = (kx planes)[r/96,:] - ck[idx[r],:](planes)
// B = t1 hi plane (global_load_lds). TT = bf16(relu(A @ B^T + bias))
// ---------------------------------------------------------------------------
__global__ __launch_bounds__(256) void gemm_diff_bf16(
    const ushort* __restrict__ kxh_g, const ushort* __restrict__ kxl_g,
    const ushort* __restrict__ ckh, const ushort* __restrict__ ckl,
    const int* __restrict__ idx, const ushort* __restrict__ BTh,
    const float* __restrict__ bias, ushort* __restrict__ TT,
    int M, int N, int K)
{
    __shared__ ushort Ah[128 * 32];
    __shared__ ushort Bh[128 * 32];
    const int tid = threadIdx.x;
    const int lane = tid & 63, wid = tid >> 6;
    const int wm = (wid & 1) * 64, wn = (wid >> 1) * 64;
    const int lane15 = lane & 15, quad = lane >> 4;
    const int row0 = blockIdx.y * 128, col0 = blockIdx.x * 128;
    const int sm = tid >> 1, scp = (tid & 1) * 2;

    const int r = row0 + sm;
    const int bidx = r / NC;
    const ushort* kxph = kxh_g + (size_t)bidx * ND + scp * 8;
    const ushort* kxpl = kxl_g + (size_t)bidx * ND + scp * 8;
    const ushort* chp  = ckh + (size_t)idx[r] * ND + scp * 8;
    const ushort* clp  = ckl + (size_t)idx[r] * ND + scp * 8;

    const int srow = tid >> 2;
    const int scl  = tid & 3;
    const int cp   = (scl - (srow >> 1)) & 3;
    const size_t gb0 = (size_t)(col0 + srow) * K + cp * 8;
    const size_t gb1 = (size_t)(col0 + 64 + srow) * K + cp * 8;
    const int l0 = tid * 8, l1 = 2048 + tid * 8;

    floatx4 acc[4][4];
#pragma unroll
    for (int i = 0; i < 4; i++)
#pragma unroll
        for (int j = 0; j < 4; j++) acc[i][j] = (floatx4){0.f, 0.f, 0.f, 0.f};

    for (int k0 = 0; k0 < K; k0 += 32) {
        short8 xh0 = *(const short8*)(kxph + k0);
        short8 xh1 = *(const short8*)(kxph + k0 + 8);
        short8 xl0 = *(const short8*)(kxpl + k0);
        short8 xl1 = *(const short8*)(kxpl + k0 + 8);
        short8 h0 = *(const short8*)(chp + k0);
        short8 h1 = *(const short8*)(chp + k0 + 8);
        short8 lo0 = *(const short8*)(clp + k0);
        short8 lo1 = *(const short8*)(clp + k0 + 8);
        short8 d0, d1;
#pragma unroll
        for (int i = 0; i < 8; i++) {
            float a0 = bf2f((ushort)xh0[i]) + bf2f((ushort)xl0[i]);
            float a1 = bf2f((ushort)xh1[i]) + bf2f((ushort)xl1[i]);
            float c0 = bf2f((ushort)h0[i]) + bf2f((ushort)lo0[i]);
            float c1 = bf2f((ushort)h1[i]) + bf2f((ushort)lo1[i]);
            d0[i] = (short)f2bf(a0 - c0);
            d1[i] = (short)f2bf(a1 - c1);
        }
        __syncthreads();
        gload16(BTh + gb0 + k0, Bh + l0);
        gload16(BTh + gb1 + k0, Bh + l1);
        *(short8*)(Ah + lds_off(sm, scp))     = d0;
        *(short8*)(Ah + lds_off(sm, scp + 1)) = d1;
        __syncthreads();

        short8 ah[4], bh[4];
#pragma unroll
        for (int t = 0; t < 4; t++) {
            ah[t] = *(const short8*)(Ah + lds_off(wm + t * 16 + lane15, quad));
            bh[t] = *(const short8*)(Bh + lds_off(wn + t * 16 + lane15, quad));
        }
#pragma unroll
        for (int i = 0; i < 4; i++)
#pragma unroll
            for (int j = 0; j < 4; j++)
                acc[i][j] = __builtin_amdgcn_mfma_f32_16x16x32_bf16(ah[i], bh[j], acc[i][j], 0, 0, 0);
    }

#pragma unroll
    for (int i = 0; i < 4; i++)
#pragma unroll
        for (int j = 0; j < 4; j++) {
            const int gc = col0 + wn + j * 16 + lane15;
            const int rb = row0 + wm + i * 16 + quad * 4;
            const float bv = bias[gc];
#pragma unroll
            for (int rr = 0; rr < 4; rr++) {
                const size_t o = (size_t)(rb + rr) * N + gc;
                TT[o] = f2bf(fmaxf(acc[i][j][rr] + bv, 0.f));
            }
        }
}

// ---------------------------------------------------------------------------
// Values MLP layer 2: A bf16 [M][K], B hi plane [N][K]: C(f32) = A @ B^T
// ---------------------------------------------------------------------------
__global__ __launch_bounds__(256) void gemm_bf16_f32(
    const ushort* __restrict__ A, const ushort* __restrict__ BTh,
    float* __restrict__ C, int M, int N, int K)
{
    __shared__ ushort Ah[128 * 32];
    __shared__ ushort Bh[128 * 32];
    const int tid = threadIdx.x;
    const int lane = tid & 63, wid = tid >> 6;
    const int wm = (wid & 1) * 64, wn = (wid >> 1) * 64;
    const int lane15 = lane & 15, quad = lane >> 4;
    const int row0 = blockIdx.y * 128, col0 = blockIdx.x * 128;

    const int srow = tid >> 2;
    const int scl  = tid & 3;
    const int cp   = (scl - (srow >> 1)) & 3;
    const size_t ga0 = (size_t)(row0 + srow) * K + cp * 8;
    const size_t ga1 = (size_t)(row0 + 64 + srow) * K + cp * 8;
    const size_t gb0 = (size_t)(col0 + srow) * K + cp * 8;
    const size_t gb1 = (size_t)(col0 + 64 + srow) * K + cp * 8;
    const int l0 = tid * 8, l1 = 2048 + tid * 8;

    floatx4 acc[4][4];
#pragma unroll
    for (int i = 0; i < 4; i++)
#pragma unroll
        for (int j = 0; j < 4; j++) acc[i][j] = (floatx4){0.f, 0.f, 0.f, 0.f};

    for (int k0 = 0; k0 < K; k0 += 32) {
        __syncthreads();
        gload16(A + ga0 + k0, Ah + l0);
        gload16(A + ga1 + k0, Ah + l1);
        gload16(BTh + gb0 + k0, Bh + l0);
        gload16(BTh + gb1 + k0, Bh + l1);
        __syncthreads();

        short8 ah[4], bh[4];
#pragma unroll
        for (int t = 0; t < 4; t++) {
            ah[t] = *(const short8*)(Ah + lds_off(wm + t * 16 + lane15, quad));
            bh[t] = *(const short8*)(Bh + lds_off(wn + t * 16 + lane15, quad));
        }
#pragma unroll
        for (int i = 0; i < 4; i++)
#pragma unroll
            for (int j = 0; j < 4; j++)
                acc[i][j] = __builtin_amdgcn_mfma_f32_16x16x32_bf16(ah[i], bh[j], acc[i][j], 0, 0, 0);
    }

#pragma unroll
    for (int i = 0; i < 4; i++)
#pragma unroll
        for (int j = 0; j < 4; j++) {
            const int gc = col0 + wn + j * 16 + lane15;
            const int rb = row0 + wm + i * 16 + quad * 4;
#pragma unroll
            for (int rr = 0; rr < 4; rr++)
                C[(size_t)(rb + rr) * N + gc] = acc[i][j][rr];
        }
}

// ---------------------------------------------------------------------------
// Prep kernels
// ---------------------------------------------------------------------------
// W[K][N] -> bf16 hi/lo planes [N][K]
__global__ __launch_bounds__(256) void split_wt_kernel(
    const float* __restrict__ W, ushort* __restrict__ WTh,
    ushort* __restrict__ WTl, int K, int N)
{
    const int o = blockIdx.x * 256 + threadIdx.x;
    if (o < K * N) {
        const int n = o / K, k = o - n * K;
        const float x = W[(size_t)k * N + n];
        const ushort h = f2bf(x);
        WTh[o] = h;
        WTl[o] = f2bf(x - bf2f(h));
    }
}

__global__ __launch_bounds__(256) void split_pl_kernel(
    const float* __restrict__ X, ushort* __restrict__ Xh,
    ushort* __restrict__ Xl, int n)
{
    const int i = blockIdx.x * 256 + threadIdx.x;
    if (i < n) {
        const float x = X[i];
        const ushort h = f2bf(x);
        Xh[i] = h;
        Xl[i] = f2bf(x - bf2f(h));
    }
}

// ---------------------------------------------------------------------------
// LayerNorm rows of 512, f32 in / f32 out
// ---------------------------------------------------------------------------
__global__ __launch_bounds__(256) void ln_kernel(
    const float* __restrict__ X, const float* __restrict__ g,
    const float* __restrict__ b, float* __restrict__ Y, int relu)
{
    const int lane = threadIdx.x & 63;
    const int row  = blockIdx.x * 4 + (threadIdx.x >> 6);
    const float* x = X + (size_t)row * ND;
    const int d = lane * 8;

    float4 v0 = *(const float4*)(x + d);
    float4 v1 = *(const float4*)(x + d + 4);
    float s = v0.x + v0.y + v0.z + v0.w + v1.x + v1.y + v1.z + v1.w;
    float q = v0.x*v0.x + v0.y*v0.y + v0.z*v0.z + v0.w*v0.w
            + v1.x*v1.x + v1.y*v1.y + v1.z*v1.z + v1.w*v1.w;
#pragma unroll
    for (int off = 32; off; off >>= 1) {
        s += __shfl_down(s, off);
        q += __shfl_down(q, off);
    }
    s = __shfl(s, 0); q = __shfl(q, 0);
    const float mean = s * (1.f / ND);
    const float var  = q * (1.f / ND) - mean * mean;
    const float rs   = rsqrtf(var + 1e-5f);

    float4 g0 = *(const float4*)(g + d);
    float4 g1 = *(const float4*)(g + d + 4);
    float4 b0 = *(const float4*)(b + d);
    float4 b1 = *(const float4*)(b + d + 4);
    float4 o0, o1;
    o0.x = (v0.x - mean) * rs * g0.x + b0.x;
    o0.y = (v0.y - mean) * rs * g0.y + b0.y;
    o0.z = (v0.z - mean) * rs * g0.z + b0.z;
    o0.w = (v0.w - mean) * rs * g0.w + b0.w;
    o1.x = (v1.x - mean) * rs * g1.x + b1.x;
    o1.y = (v1.y - mean) * rs * g1.y + b1.y;
    o1.z = (v1.z - mean) * rs * g1.z + b1.z;
    o1.w = (v1.w - mean) * rs * g1.w + b1.w;
    if (relu) {
        o0.x = fmaxf(o0.x, 0.f); o0.y = fmaxf(o0.y, 0.f);
        o0.z = fmaxf(o0.z, 0.f); o0.w = fmaxf(o0.w, 0.f);
        o1.x = fmaxf(o1.x, 0.f); o1.y = fmaxf(o1.y, 0.f);
        o1.z = fmaxf(o1.z, 0.f); o1.w = fmaxf(o1.w, 0.f);
    }
    float* y = Y + (size_t)row * ND;
    *(float4*)(y + d)     = o0;
    *(float4*)(y + d + 4) = o1;
}

// LayerNorm rows of 512, planes in / planes out
__global__ __launch_bounds__(256) void ln_pl_kernel(
    const ushort* __restrict__ Xh, const ushort* __restrict__ Xl,
    const float* __restrict__ g, const float* __restrict__ b,
    ushort* __restrict__ Yh, ushort* __restrict__ Yl)
{
    const int lane = threadIdx.x & 63;
    const int row  = blockIdx.x * 4 + (threadIdx.x >> 6);
    const int d = lane * 8;
    const size_t base = (size_t)row * ND + d;

    short8 xh = *(const short8*)(Xh + base);
    short8 xl = *(const short8*)(Xl + base);
    float v[8];
#pragma unroll
    for (int i = 0; i < 8; i++) v[i] = bf2f((ushort)xh[i]) + bf2f((ushort)xl[i]);

    float s = 0.f, q = 0.f;
#pragma unroll
    for (int i = 0; i < 8; i++) { s += v[i]; q += v[i] * v[i]; }
#pragma unroll
    for (int off = 32; off; off >>= 1) {
        s += __shfl_down(s, off);
        q += __shfl_down(q, off);
    }
    s = __shfl(s, 0); q = __shfl(q, 0);
    const float mean = s * (1.f / ND);
    const float var  = q * (1.f / ND) - mean * mean;
    const float rs   = rsqrtf(var + 1e-5f);

    short8 yh, yl;
#pragma unroll
    for (int i = 0; i < 8; i++) {
        const float o = (v[i] - mean) * rs * g[d + i] + b[d + i];
        const ushort h = f2bf(o);
        yh[i] = (short)h;
        yl[i] = (short)f2bf(o - bf2f(h));
    }
    *(short8*)(Yh + base) = yh;
    *(short8*)(Yl + base) = yl;
}

__global__ __launch_bounds__(256) void sqnorm_pl_kernel(
    const ushort* __restrict__ Xh, const ushort* __restrict__ Xl,
    float* __restrict__ sq)
{
    const int lane = threadIdx.x & 63;
    const int row  = blockIdx.x * 4 + (threadIdx.x >> 6);
    const size_t base = (size_t)row * ND + lane * 8;
    short8 xh = *(const short8*)(Xh + base);
    short8 xl = *(const short8*)(Xl + base);
    float q = 0.f;
#pragma unroll
    for (int i = 0; i < 8; i++) {
        float v = bf2f((ushort)xh[i]) + bf2f((ushort)xl[i]);
        q += v * v;
    }
#pragma unroll
    for (int off = 32; off; off >>= 1) q += __shfl_down(q, off);
    if (lane == 0) sq[row] = q;
}

// ---------------------------------------------------------------------------
// Two-stage exact top-96: adaptive-range radix select.
// ---------------------------------------------------------------------------
__device__ __forceinline__ unsigned fkey(float f)
{
    unsigned u = __float_as_uint(f);
    return (u & 0x80000000u) ? ~u : (u | 0x80000000u);
}
__device__ __forceinline__ float inv_fkey(unsigned u)
{
    return __uint_as_float((u & 0x80000000u) ? (u & 0x7FFFFFFFu) : ~u);
}

struct SelState {
    unsigned lo;
    unsigned long long hi;   // exclusive
    int krem;
    int done;
    unsigned long long T;    // threshold
    int need;                // how many keys == T to take
};

template <int KPT>
__device__ __forceinline__ void adaptive_select(
    const unsigned (&key)[KPT], unsigned* hist, unsigned* wtot,
    SelState* st, int tid, int kwant)
{
    const int lane = tid & 63, wid = tid >> 6;

    unsigned mn = 0xFFFFFFFFu, mx = 0u;
#pragma unroll
    for (int j = 0; j < KPT; j++) {
        mn = min(mn, key[j]);
        mx = max(mx, key[j]);
    }
#pragma unroll
    for (int off = 32; off; off >>= 1) {
        mn = min(mn, (unsigned)__shfl_down((int)mn, off));
        mx = max(mx, (unsigned)__shfl_down((int)mx, off));
    }
    if (lane == 0) { hist[wid] = mn; hist[8 + wid] = mx; }
    if (tid == 0) st->done = 0;
    __syncthreads();
    if (tid == 0) {
        unsigned gmn = min(min(hist[0], hist[1]), min(hist[2], hist[3]));
        unsigned gmx = max(max(hist[8], hist[9]), max(hist[10], hist[11]));
        st->lo = gmn;
        st->hi = (unsigned long long)gmx + 1ull;
        st->krem = kwant;
    }
    __syncthreads();

    for (int iter = 0; iter < 6 && !st->done; iter++) {
        const unsigned lo = st->lo;
        const unsigned long long hi = st->hi;
        const int krem = st->krem;
        const unsigned long long span = hi - lo;
        int shift = 0;
        if (span > 256ull) {
            const int nb = 64 - __builtin_clzll(span - 1ull);
            shift = nb - 8;
        }
        hist[tid] = 0u;
        __syncthreads();
#pragma unroll
        for (int j = 0; j < KPT; j++) {
            const unsigned u = key[j];
            if (u >= lo && (unsigned long long)u < hi)
                atomicAdd(&hist[(u - lo) >> shift], 1u);
        }
        __syncthreads();
        const unsigned c = hist[tid];
        unsigned v = c;
#pragma unroll
        for (int off = 1; off < 64; off <<= 1) {
            const unsigned t = (unsigned)__shfl_up((int)v, off);
            if (lane >= off) v += t;
        }
        if (lane == 63) wtot[wid] = v;
        __syncthreads();
        unsigned pre = 0;
        for (int w = 0; w < 3; w++) pre += (w < wid) ? wtot[w] : 0u;
        const int incl = (int)(v + pre);
        const int excl = incl - (int)c;
        if (excl < krem && incl >= krem) {
            const unsigned long long binlo =
                (unsigned long long)lo + ((unsigned long long)tid << shift);
            if (shift == 0) {
                st->T = binlo;
                st->need = krem - excl;
                st->done = 1;
            } else if (incl == krem) {
                st->T = binlo + (1ull << shift);
                st->need = 0;
                st->done = 1;
            } else {
                st->lo = (unsigned)binlo;
                const unsigned long long nhi = binlo + (1ull << shift);
                st->hi = nhi < hi ? nhi : hi;
                st->krem = krem - excl;
            }
        }
        __syncthreads();
    }
}

__global__ __launch_bounds__(256) void topk_seg(
    const float* __restrict__ S, unsigned* __restrict__ K1key,
    int* __restrict__ K1idx)
{
    const int r = blockIdx.y, seg = blockIdx.x;
    const float* p = S + (size_t)r * NN + seg * TK_SEG;
    __shared__ unsigned hist[256];
    __shared__ unsigned wtot[4];
    __shared__ SelState st;
    __shared__ int cA, cB;
    const int tid = threadIdx.x;

    unsigned key[16];
#pragma unroll
    for (int j = 0; j < 16; j++) key[j] = fkey(p[tid + j * 256]);

    if (tid == 0) { cA = 0; cB = 0; }
    adaptive_select<16>(key, hist, wtot, &st, tid, NC);

    const unsigned long long T = st.T;
    const int need = st.need;
    const int cntLess = NC - need;
    const size_t obase = ((size_t)r * TK_SPLIT + seg) * NC;
#pragma unroll
    for (int j = 0; j < 16; j++) {
        const unsigned u = key[j];
        if ((unsigned long long)u < T) {
            const int pos = atomicAdd(&cA, 1);
            K1key[obase + pos] = u;
            K1idx[obase + pos] = seg * TK_SEG + tid + j * 256;
        } else if ((unsigned long long)u == T) {
            const int pos = atomicAdd(&cB, 1);
            if (pos < need) {
                K1key[obase + cntLess + pos] = u;
                K1idx[obase + cntLess + pos] = seg * TK_SEG + tid + j * 256;
            }
        }
    }
}

__global__ __launch_bounds__(256) void topk_merge(
    const unsigned* __restrict__ K1key, const int* __restrict__ K1idx,
    int* __restrict__ idx_out, float* __restrict__ val_out, int b0)
{
    const int r = blockIdx.x;
    const int b = b0 + r;
    __shared__ unsigned hist[256];
    __shared__ unsigned wtot[4];
    __shared__ SelState st;
    __shared__ int cA, cB;
    const int tid = threadIdx.x;
    const size_t ibase = (size_t)r * TK_CAND;

    unsigned key[6];
    int      kidx[6];
#pragma unroll
    for (int j = 0; j < 6; j++) {
        key[j]  = K1key[ibase + tid + j * 256];
        kidx[j] = K1idx[ibase + tid + j * 256];
    }

    if (tid == 0) { cA = 0; cB = 0; }
    adaptive_select<6>(key, hist, wtot, &st, tid, NC);

    const unsigned long long T = st.T;
    const int need = st.need;
    const int cntLess = NC - need;
#pragma unroll
    for (int j = 0; j < 6; j++) {
        const unsigned u = key[j];
        if ((unsigned long long)u < T) {
            const int pos = atomicAdd(&cA, 1);
            idx_out[b * NC + pos] = kidx[j];
            val_out[b * NC + pos] = inv_fkey(u);
        } else if ((unsigned long long)u == T) {
            const int pos = atomicAdd(&cB, 1);
            if (pos < need) {
                idx_out[b * NC + cntLess + pos] = kidx[j];
                val_out[b * NC + cntLess + pos] = inv_fkey(u);
            }
        }
    }
}

// ---------------------------------------------------------------------------
__global__ __launch_bounds__(128) void probs_kernel(
    const float* __restrict__ svals, float* __restrict__ probs)
{
    const int b = blockIdx.x;
    const int tid = threadIdx.x;
    __shared__ float red[128];
    const bool valid = tid < NC;
    float s = valid ? -svals[b * NC + tid] : -3.4e38f;
    red[tid] = s;
    __syncthreads();
#pragma unroll
    for (int off = 64; off; off >>= 1) {
        if (tid < off) red[tid] = fmaxf(red[tid], red[tid + off]);
        __syncthreads();
    }
    const float m = red[0];
    __syncthreads();
    float e = valid ? expf(s - m) : 0.f;
    red[tid] = e;
    __syncthreads();
#pragma unroll
    for (int off = 64; off; off >>= 1) {
        if (tid < off) red[tid] += red[tid + off];
        __syncthreads();
    }
    const float sum = red[0];
    if (valid) probs[b * NC + tid] = e / sum;
}

// ctx: xin given as planes (encoder-out x)
__global__ __launch_bounds__(256) void ctx_kernel(
    const float* __restrict__ VAL, const float* __restrict__ probs,
    const float* __restrict__ cand_y, const int* __restrict__ idx,
    const float* __restrict__ labW, const float* __restrict__ labb,
    const ushort* __restrict__ xinh, const ushort* __restrict__ xinl,
    float* __restrict__ xout, int b0)
{
    const int b_loc = blockIdx.x;
    const int b = b0 + b_loc;
    const int tid = threadIdx.x;
    __shared__ float pv[NC];
    __shared__ float red[256];
    float py_part = 0.f;
    if (tid < NC) {
        float p = probs[b * NC + tid];
        pv[tid] = p;
        py_part = p * cand_y[idx[b * NC + tid]];
    }
    red[tid] = py_part;
    __syncthreads();
#pragma unroll
    for (int off = 128; off; off >>= 1) {
        if (tid < off) red[tid] += red[tid + off];
        __syncthreads();
    }
    const float py = red[0];

    for (int d = tid; d < ND; d += 256) {
        const float* vp = VAL + (size_t)b_loc * NC * ND + d;
        float acc = 0.f;
#pragma unroll 8
        for (int c = 0; c < NC; c++) acc += pv[c] * vp[(size_t)c * ND];
        float ctx = acc + py * labW[d] + labb[d];
        const size_t o = (size_t)b * ND + d;
        xout[o] = bf2f(xinh[o]) + bf2f(xinl[o]) + ctx;
    }
}

__global__ __launch_bounds__(64) void head_kernel(
    const float* __restrict__ X, const float* __restrict__ hW,
    const float* __restrict__ hb, float* __restrict__ out)
{
    const int b = blockIdx.x;
    const int lane = threadIdx.x;
    const float* x = X + (size_t)b * ND;
    float acc = 0.f;
#pragma unroll
    for (int j = 0; j < 8; j++) {
        int d = lane + 64 * j;
        acc += x[d] * hW[d];
    }
#pragma unroll
    for (int off = 32; off; off >>= 1) acc += __shfl_down(acc, off);
    if (lane == 0) out[b] = acc + hb[0];
}

// ---------------------------------------------------------------------------
extern "C" void kernel_launch(void* const* d_in, const int* in_sizes, int n_in,
                              void* d_out, int out_size, void* d_ws, size_t ws_size,
                              hipStream_t stream)
{
    const float* x_num    = (const float*)d_in[0];
    const float* cand_num = (const float*)d_in[1];
    const float* cand_y   = (const float*)d_in[2];
    const float* lin_W    = (const float*)d_in[3];
    const float* lin_b    = (const float*)d_in[4];
    const float* e_W1     = (const float*)d_in[5];
    const float* e_b1     = (const float*)d_in[6];
    const float* e_W2     = (const float*)d_in[7];
    const float* e_b2     = (const float*)d_in[8];
    const float* mix_g    = (const float*)d_in[9];
    const float* mix_b    = (const float*)d_in[10];
    const float* K_W      = (const float*)d_in[11];
    const float* K_b      = (const float*)d_in[12];
    const float* lab_W    = (const float*)d_in[13];
    const float* lab_b    = (const float*)d_in[14];
    const float* T_W1     = (const float*)d_in[15];
    const float* T_b1     = (const float*)d_in[16];
    const float* T_W2     = (const float*)d_in[17];
    const float* p_ln_g   = (const float*)d_in[18];
    const float* p_ln_b   = (const float*)d_in[19];
    const float* p_W1     = (const float*)d_in[20];
    const float* p_b1     = (const float*)d_in[21];
    const float* p_W2     = (const float*)d_in[22];
    const float* p_b2     = (const float*)d_in[23];
    const float* h_ln_g   = (const float*)d_in[24];
    const float* h_ln_b   = (const float*)d_in[25];
    const float* h_W      = (const float*)d_in[26];
    const float* h_b      = (const float*)d_in[27];
    float* out = (float*)d_out;
    (void)in_sizes; (void)n_in; (void)out_size; (void)ws_size;

    // ---- workspace layout (~245 MB) ----
    size_t off = 0;
    auto ralloc = [&](size_t bytes) -> void* {
        void* p = (char*)d_ws + off;
        off += (bytes + 255) & ~(size_t)255;
        return p;
    };
    auto falloc = [&](size_t n) -> float*  { return (float*)ralloc(n * 4); };
    auto ualloc = [&](size_t n) -> ushort* { return (ushort*)ralloc(n * 2); };

    // bf16 plane weights [N][K]
    ushort* WP_lin_h = ualloc((size_t)ND * NF);
    ushort* WP_lin_l = ualloc((size_t)ND * NF);
    ushort* WP_e1_h  = ualloc((size_t)NDB * ND);
    ushort* WP_e1_l  = ualloc((size_t)NDB * ND);
    ushort* WP_e2_h  = ualloc((size_t)ND * NDB);
    ushort* WP_e2_l  = ualloc((size_t)ND * NDB);
    ushort* WP_kw_h  = ualloc((size_t)ND * ND);
    ushort* WP_kw_l  = ualloc((size_t)ND * ND);
    ushort* WP_t1_h  = ualloc((size_t)NDB * ND);
    ushort* WP_t1_l  = ualloc((size_t)NDB * ND);
    ushort* WP_t2_h  = ualloc((size_t)ND * NDB);
    ushort* WP_t2_l  = ualloc((size_t)ND * NDB);
    ushort* WP_p1_h  = ualloc((size_t)NDB * ND);
    ushort* WP_p1_l  = ualloc((size_t)NDB * ND);
    ushort* WP_p2_h  = ualloc((size_t)ND * NDB);
    ushort* WP_p2_l  = ualloc((size_t)ND * NDB);

    ushort* R_CKh = ualloc((size_t)NN * ND);
    ushort* R_CKl = ualloc((size_t)NN * ND);
    float*  R_sq  = falloc(NN);

    // x-path plane activations
    ushort* XNh = ualloc((size_t)NB * NF);
    ushort* XNl = ualloc((size_t)NB * NF);
    ushort* Hxh = ualloc((size_t)NB * ND);
    ushort* Hxl = ualloc((size_t)NB * ND);
    ushort* Txh = ualloc((size_t)NB * NDB);
    ushort* Txl = ualloc((size_t)NB * NDB);
    ushort* X2h = ualloc((size_t)NB * ND);
    ushort* X2l = ualloc((size_t)NB * ND);
    ushort* Gxh = ualloc((size_t)NB * ND);
    ushort* Gxl = ualloc((size_t)NB * ND);
    ushort* Lxh = ualloc((size_t)NB * ND);
    ushort* Lxl = ualloc((size_t)NB * ND);
    ushort* Tph = ualloc((size_t)NB * NDB);
    ushort* Tpl = ualloc((size_t)NB * NDB);
    ushort* R_kxh = ualloc((size_t)NB * ND);
    ushort* R_kxl = ualloc((size_t)NB * ND);

    int*    R_idx = (int*)ralloc((size_t)NB * NC * 4);
    float*  R_ssel= falloc((size_t)NB * NC);
    float*  R_prob= falloc((size_t)NB * NC);
    float*  R_xupd= falloc((size_t)NB * ND);
    float*  R_lnx = falloc((size_t)NB * ND);
    float*  R_x2  = falloc((size_t)NB * ND);
    float*  R_lnx2= falloc((size_t)NB * ND);
    unsigned* K1key = (unsigned*)ralloc((size_t)BB_C * TK_CAND * 4);
    int*      K1idx = (int*)ralloc((size_t)BB_C * TK_CAND * 4);
    char* SCR = (char*)ralloc((size_t)70 * 1024 * 1024);

    // ---- 0. weight prep (split-transpose to planes) ----
    auto sw = [&](const float* W, ushort* WTh, ushort* WTl, int K, int N) {
        split_wt_kernel<<<dim3((K * N + 255) / 256), dim3(256), 0, stream>>>(W, WTh, WTl, K, N);
    };
    sw(lin_W, WP_lin_h, WP_lin_l, NF, ND);
    sw(e_W1,  WP_e1_h,  WP_e1_l,  ND, NDB);
    sw(e_W2,  WP_e2_h,  WP_e2_l,  NDB, ND);
    sw(K_W,   WP_kw_h,  WP_kw_l,  ND, ND);
    sw(T_W1,  WP_t1_h,  WP_t1_l,  ND, NDB);
    sw(T_W2,  WP_t2_h,  WP_t2_l,  NDB, ND);
    sw(p_W1,  WP_p1_h,  WP_p1_l,  ND, NDB);
    sw(p_W2,  WP_p2_h,  WP_p2_l,  NDB, ND);

    auto gss = [&](const ushort* Ah, const ushort* Al, const ushort* Bh,
                   const ushort* Bl, const float* bias, const ushort* resh,
                   const ushort* resl, const float* sq, float* Sf,
                   ushort* Ch, ushort* Cl, int M, int Nn, int K, int relu) {
        gemm_ss<<<dim3(Nn / 128, M / 128), dim3(256), 0, stream>>>(
            Ah, Al, Bh, Bl, bias, resh, resl, sq, Sf, Ch, Cl, M, Nn, K, relu);
    };
    auto gsm = [&](const ushort* Ah, const ushort* Al, const ushort* Bh,
                   const ushort* Bl, const float* bias, const ushort* resh,
                   const ushort* resl, const float* resf, ushort* Ch,
                   ushort* Cl, float* outf, int M, int Nn, int K, int relu) {
        gemm_ss_small<<<dim3(Nn / 64, M / 64), dim3(256), 0, stream>>>(
            Ah, Al, Bh, Bl, bias, resh, resl, resf, Ch, Cl, outf, M, Nn, K, relu);
    };

    // ---- 1. candidate encode (chunked; plane operands, split-bf16 MFMA) ----
    {
        ushort* CNh = (ushort*)SCR;
        ushort* CNl = CNh + (size_t)CH_A * NF;
        ushort* Hh  = CNl + (size_t)CH_A * NF;
        ushort* Hl  = Hh  + (size_t)CH_A * ND;
        ushort* Th  = Hl  + (size_t)CH_A * ND;
        ushort* Tl  = Th  + (size_t)CH_A * NDB;
        ushort* H2h = Tl  + (size_t)CH_A * NDB;
        ushort* H2l = H2h + (size_t)CH_A * ND;
        ushort* Gh  = Th;   // overlay: T dead after e2
        ushort* Gl  = Tl;

        for (int n0 = 0; n0 < NN; n0 += CH_A) {
            split_pl_kernel<<<dim3((CH_A * NF + 255) / 256), dim3(256), 0, stream>>>(
                cand_num + (size_t)n0 * NF, CNh, CNl, CH_A * NF);
            gss(CNh, CNl, WP_lin_h, WP_lin_l, lin_b, nullptr, nullptr, nullptr,
                nullptr, Hh, Hl, CH_A, ND, NF, 0);
            gss(Hh, Hl, WP_e1_h, WP_e1_l, e_b1, nullptr, nullptr, nullptr,
                nullptr, Th, Tl, CH_A, NDB, ND, 1);
            gss(Th, Tl, WP_e2_h, WP_e2_l, e_b2, Hh, Hl, nullptr,
                nullptr, H2h, H2l, CH_A, ND, NDB, 0);
            ln_pl_kernel<<<dim3(CH_A / 4), dim3(256), 0, stream>>>(
                H2h, H2l, mix_g, mix_b, Gh, Gl);
            gss(Gh, Gl, WP_kw_h, WP_kw_l, K_b, nullptr, nullptr, nullptr,
                nullptr, R_CKh + (size_t)n0 * ND, R_CKl + (size_t)n0 * ND,
                CH_A, ND, ND, 0);
            sqnorm_pl_kernel<<<dim3(CH_A / 4), dim3(256), 0, stream>>>(
                R_CKh + (size_t)n0 * ND, R_CKl + (size_t)n0 * ND, R_sq + n0);
        }
    }

    // ---- 2. x encode (plane operands, 64x64-tile small GEMM) ----
    split_pl_kernel<<<dim3((NB * NF + 255) / 256), dim3(256), 0, stream>>>(
        x_num, XNh, XNl, NB * NF);
    gsm(XNh, XNl, WP_lin_h, WP_lin_l, lin_b, nullptr, nullptr, nullptr,
        Hxh, Hxl, nullptr, NB, ND, NF, 0);
    gsm(Hxh, Hxl, WP_e1_h, WP_e1_l, e_b1, nullptr, nullptr, nullptr,
        Txh, Txl, nullptr, NB, NDB, ND, 1);
    gsm(Txh, Txl, WP_e2_h, WP_e2_l, e_b2, Hxh, Hxl, nullptr,
        X2h, X2l, nullptr, NB, ND, NDB, 0);
    ln_pl_kernel<<<dim3(NB / 4), dim3(256), 0, stream>>>(
        X2h, X2l, mix_g, mix_b, Gxh, Gxl);
    gsm(Gxh, Gxl, WP_kw_h, WP_kw_l, K_b, nullptr, nullptr, nullptr,
        R_kxh, R_kxl, nullptr, NB, ND, ND, 0);

    // ---- 3. scores + two-stage top-96 + softmax ----
    for (int b0 = 0; b0 < NB; b0 += BB_C) {
        float* S = (float*)SCR;
        gss(R_kxh + (size_t)b0 * ND, R_kxl + (size_t)b0 * ND, R_CKh, R_CKl,
            nullptr, nullptr, nullptr, R_sq, S, nullptr, nullptr,
            BB_C, NN, ND, 0);
        topk_seg<<<dim3(TK_SPLIT, BB_C), dim3(256), 0, stream>>>(S, K1key, K1idx);
        topk_merge<<<dim3(BB_C), dim3(256), 0, stream>>>(K1key, K1idx,
                                                         R_idx, R_ssel, b0);
    }
    probs_kernel<<<dim3(NB), dim3(128), 0, stream>>>(R_ssel, R_prob);

    // ---- 4. values path (plain bf16 MFMA, diff fused) ----
    for (int b0 = 0; b0 < NB; b0 += BB_D) {
        ushort* TT = (ushort*)SCR;                                  // [M,1024] bf16
        float* VAL = (float*)(SCR + (size_t)BB_D * NC * NDB * 2);   // f32 after TT
        const int M = BB_D * NC;   // 12288
        gemm_diff_bf16<<<dim3(NDB / 128, M / 128), dim3(256), 0, stream>>>(
            R_kxh + (size_t)b0 * ND, R_kxl + (size_t)b0 * ND,
            R_CKh, R_CKl, R_idx + b0 * NC,
            WP_t1_h, T_b1, TT, M, NDB, ND);
        gemm_bf16_f32<<<dim3(ND / 128, M / 128), dim3(256), 0, stream>>>(
            TT, WP_t2_h, VAL, M, ND, NDB);
        ctx_kernel<<<dim3(BB_D), dim3(256), 0, stream>>>(
            VAL, R_prob, cand_y, R_idx, lab_W, lab_b, X2h, X2l, R_xupd, b0);
    }

    // ---- 5. predictor block + head ----
    ln_kernel<<<dim3(NB / 4), dim3(256), 0, stream>>>(R_xupd, p_ln_g, p_ln_b, R_lnx, 0);
    split_pl_kernel<<<dim3((NB * ND + 255) / 256), dim3(256), 0, stream>>>(
        R_lnx, Lxh, Lxl, NB * ND);
    gsm(Lxh, Lxl, WP_p1_h, WP_p1_l, p_b1, nullptr, nullptr, nullptr,
        Tph, Tpl, nullptr, NB, NDB, ND, 1);
    gsm(Tph, Tpl, WP_p2_h, WP_p2_l, p_b2, nullptr, nullptr, R_xupd,
        nullptr, nullptr, R_x2, NB, ND, NDB, 0);
    ln_kernel<<<dim3(NB / 4), dim3(256), 0, stream>>>(R_x2, h_ln_g, h_ln_b, R_lnx2, 1);
    head_kernel<<<dim3(NB), dim3(64), 0, stream>>>(R_lnx2, h_W, h_b, out);
}

// Round 11
// 2747.101 us; speedup vs baseline: 1.4291x; 1.1040x over previous
//
#include <hip/hip_runtime.h>

// Problem constants
#define NB   1024
#define NN   65536
#define NF   64
#define ND   512
#define NDB  1024
#define NC   96

// Chunking
#define CH_A 8192      // candidate-encode chunk rows
#define BB_C 256       // scores/topk chunk of B rows
#define BB_D 128       // values-path chunk of B rows

// top-k segmentation
#define TK_SPLIT 16
#define TK_SEG   (NN / TK_SPLIT)   // 4096
#define TK_CAND  (TK_SPLIT * NC)   // 1536

typedef unsigned short ushort;
typedef __attribute__((ext_vector_type(8))) short short8;
typedef __attribute__((ext_vector_type(4))) float floatx4;

__device__ __forceinline__ ushort f2bf(float f) {   // RNE f32->bf16
    unsigned u = __float_as_uint(f);
    u += 0x7fffu + ((u >> 16) & 1u);
    return (ushort)(u >> 16);
}
__device__ __forceinline__ float bf2f(ushort h) {
    return __uint_as_float(((unsigned)h) << 16);
}
// LDS plane: [m][k] bf16, k-stride 32, 16B-chunk XOR swizzle -> conflict-free
__device__ __forceinline__ int lds_off(int m, int c) {
    return m * 32 + (((c + (m >> 1)) & 3) << 3);
}

// async global->LDS 16B
__device__ __forceinline__ void gload16(const ushort* g, ushort* l)
{
    void* gv = (void*)g;
    void* lv = (void*)l;
    __builtin_amdgcn_global_load_lds(
        (__attribute__((address_space(1))) void*)gv,
        (__attribute__((address_space(3))) void*)lv, 16, 0, 0);
}

// ---------------------------------------------------------------------------
// Split-plane MFMA GEMM (f32-emulating, 3 MFMA), NT, 128x128 tile.
// Epilogue: scoresq ? Sf = scoresq[n]-2*acc : v=acc+bias(+res)(relu) -> planes
// ---------------------------------------------------------------------------
__global__ __launch_bounds__(256) void gemm_ss(
    const ushort* __restrict__ Ah_g, const ushort* __restrict__ Al_g,
    const ushort* __restrict__ Bh_g, const ushort* __restrict__ Bl_g,
    const float* __restrict__ bias,
    const ushort* __restrict__ resh, const ushort* __restrict__ resl,
    const float* __restrict__ scoresq, float* __restrict__ Sf,
    ushort* __restrict__ Ch, ushort* __restrict__ Cl,
    int M, int N, int K, int relu)
{
    __shared__ ushort Ah[128 * 32], Al[128 * 32];
    __shared__ ushort Bh[128 * 32], Bl[128 * 32];
    const int tid = threadIdx.x;
    const int lane = tid & 63, wid = tid >> 6;
    const int wm = (wid & 1) * 64, wn = (wid >> 1) * 64;
    const int lane15 = lane & 15, quad = lane >> 4;
    const int row0 = blockIdx.y * 128, col0 = blockIdx.x * 128;

    const int srow = tid >> 2;
    const int scl  = tid & 3;
    const int cp   = (scl - (srow >> 1)) & 3;
    const size_t ga0 = (size_t)(row0 + srow) * K + cp * 8;
    const size_t ga1 = (size_t)(row0 + 64 + srow) * K + cp * 8;
    const size_t gb0 = (size_t)(col0 + srow) * K + cp * 8;
    const size_t gb1 = (size_t)(col0 + 64 + srow) * K + cp * 8;
    const int l0 = tid * 8;
    const int l1 = 2048 + tid * 8;

    floatx4 acc[4][4];
#pragma unroll
    for (int i = 0; i < 4; i++)
#pragma unroll
        for (int j = 0; j < 4; j++) acc[i][j] = (floatx4){0.f, 0.f, 0.f, 0.f};

    for (int k0 = 0; k0 < K; k0 += 32) {
        __syncthreads();
        gload16(Ah_g + ga0 + k0, Ah + l0);
        gload16(Ah_g + ga1 + k0, Ah + l1);
        gload16(Al_g + ga0 + k0, Al + l0);
        gload16(Al_g + ga1 + k0, Al + l1);
        gload16(Bh_g + gb0 + k0, Bh + l0);
        gload16(Bh_g + gb1 + k0, Bh + l1);
        gload16(Bl_g + gb0 + k0, Bl + l0);
        gload16(Bl_g + gb1 + k0, Bl + l1);
        __syncthreads();

        short8 ah[4], al[4], bh[4], bl[4];
#pragma unroll
        for (int t = 0; t < 4; t++) {
            const int am = wm + t * 16 + lane15;
            const int bn = wn + t * 16 + lane15;
            ah[t] = *(const short8*)(Ah + lds_off(am, quad));
            al[t] = *(const short8*)(Al + lds_off(am, quad));
            bh[t] = *(const short8*)(Bh + lds_off(bn, quad));
            bl[t] = *(const short8*)(Bl + lds_off(bn, quad));
        }
#pragma unroll
        for (int i = 0; i < 4; i++)
#pragma unroll
            for (int j = 0; j < 4; j++) {
                acc[i][j] = __builtin_amdgcn_mfma_f32_16x16x32_bf16(ah[i], bh[j], acc[i][j], 0, 0, 0);
                acc[i][j] = __builtin_amdgcn_mfma_f32_16x16x32_bf16(ah[i], bl[j], acc[i][j], 0, 0, 0);
                acc[i][j] = __builtin_amdgcn_mfma_f32_16x16x32_bf16(al[i], bh[j], acc[i][j], 0, 0, 0);
            }
    }

    // C/D layout: col=lane&15, row=quad*4+reg  [m89]
#pragma unroll
    for (int i = 0; i < 4; i++)
#pragma unroll
        for (int j = 0; j < 4; j++) {
            const int gc = col0 + wn + j * 16 + lane15;
            const int rb = row0 + wm + i * 16 + quad * 4;
            const float bv = bias ? bias[gc] : 0.f;
            const float sv = scoresq ? scoresq[gc] : 0.f;
#pragma unroll
            for (int r = 0; r < 4; r++) {
                const size_t o = (size_t)(rb + r) * N + gc;
                float v = acc[i][j][r];
                if (scoresq) {
                    Sf[o] = sv - 2.f * v;
                } else {
                    v += bv;
                    if (resh) v += bf2f(resh[o]) + bf2f(resl[o]);
                    if (relu) v = fmaxf(v, 0.f);
                    ushort h = f2bf(v);
                    Ch[o] = h;
                    Cl[o] = f2bf(v - bf2f(h));
                }
            }
        }
}

// ---------------------------------------------------------------------------
// Split-plane GEMM, 128M x 64N tile (4 blocks/CU for N=1024 encode layers).
// acc[2][4] per wave (wm = wid*32). Bit-identical k-order to gemm_ss.
// ---------------------------------------------------------------------------
__global__ __launch_bounds__(256) void gemm_ss_n64(
    const ushort* __restrict__ Ah_g, const ushort* __restrict__ Al_g,
    const ushort* __restrict__ Bh_g, const ushort* __restrict__ Bl_g,
    const float* __restrict__ bias,
    const ushort* __restrict__ resh, const ushort* __restrict__ resl,
    ushort* __restrict__ Ch, ushort* __restrict__ Cl,
    int M, int N, int K, int relu)
{
    __shared__ ushort Ah[128 * 32], Al[128 * 32];
    __shared__ ushort Bh[64 * 32], Bl[64 * 32];
    const int tid = threadIdx.x;
    const int lane = tid & 63, wid = tid >> 6;
    const int wm = wid * 32;
    const int lane15 = lane & 15, quad = lane >> 4;
    const int row0 = blockIdx.y * 128, col0 = blockIdx.x * 64;

    const int srow = tid >> 2;
    const int scl  = tid & 3;
    const int cp   = (scl - (srow >> 1)) & 3;
    const size_t ga0 = (size_t)(row0 + srow) * K + cp * 8;
    const size_t ga1 = (size_t)(row0 + 64 + srow) * K + cp * 8;
    const size_t gb  = (size_t)(col0 + srow) * K + cp * 8;
    const int l0 = tid * 8;
    const int l1 = 2048 + tid * 8;

    floatx4 acc[2][4];
#pragma unroll
    for (int i = 0; i < 2; i++)
#pragma unroll
        for (int j = 0; j < 4; j++) acc[i][j] = (floatx4){0.f, 0.f, 0.f, 0.f};

    for (int k0 = 0; k0 < K; k0 += 32) {
        __syncthreads();
        gload16(Ah_g + ga0 + k0, Ah + l0);
        gload16(Ah_g + ga1 + k0, Ah + l1);
        gload16(Al_g + ga0 + k0, Al + l0);
        gload16(Al_g + ga1 + k0, Al + l1);
        gload16(Bh_g + gb + k0, Bh + l0);
        gload16(Bl_g + gb + k0, Bl + l0);
        __syncthreads();

        short8 ah[2], al[2], bh[4], bl[4];
#pragma unroll
        for (int t = 0; t < 2; t++) {
            const int am = wm + t * 16 + lane15;
            ah[t] = *(const short8*)(Ah + lds_off(am, quad));
            al[t] = *(const short8*)(Al + lds_off(am, quad));
        }
#pragma unroll
        for (int j = 0; j < 4; j++) {
            const int bn = j * 16 + lane15;
            bh[j] = *(const short8*)(Bh + lds_off(bn, quad));
            bl[j] = *(const short8*)(Bl + lds_off(bn, quad));
        }
#pragma unroll
        for (int i = 0; i < 2; i++)
#pragma unroll
            for (int j = 0; j < 4; j++) {
                acc[i][j] = __builtin_amdgcn_mfma_f32_16x16x32_bf16(ah[i], bh[j], acc[i][j], 0, 0, 0);
                acc[i][j] = __builtin_amdgcn_mfma_f32_16x16x32_bf16(ah[i], bl[j], acc[i][j], 0, 0, 0);
                acc[i][j] = __builtin_amdgcn_mfma_f32_16x16x32_bf16(al[i], bh[j], acc[i][j], 0, 0, 0);
            }
    }

#pragma unroll
    for (int i = 0; i < 2; i++)
#pragma unroll
        for (int j = 0; j < 4; j++) {
            const int gc = col0 + j * 16 + lane15;
            const int rb = row0 + wm + i * 16 + quad * 4;
            const float bv = bias ? bias[gc] : 0.f;
#pragma unroll
            for (int r = 0; r < 4; r++) {
                const size_t o = (size_t)(rb + r) * N + gc;
                float v = acc[i][j][r] + bv;
                if (resh) v += bf2f(resh[o]) + bf2f(resl[o]);
                if (relu) v = fmaxf(v, 0.f);
                ushort h = f2bf(v);
                Ch[o] = h;
                Cl[o] = f2bf(v - bf2f(h));
            }
        }
}

// ---------------------------------------------------------------------------
// Small-M split-plane GEMM: 64x64 tile. Flexible epilogue.
// ---------------------------------------------------------------------------
__global__ __launch_bounds__(256) void gemm_ss_small(
    const ushort* __restrict__ Ah_g, const ushort* __restrict__ Al_g,
    const ushort* __restrict__ Bh_g, const ushort* __restrict__ Bl_g,
    const float* __restrict__ bias,
    const ushort* __restrict__ resh, const ushort* __restrict__ resl,
    const float* __restrict__ resf,
    ushort* __restrict__ Ch, ushort* __restrict__ Cl,
    float* __restrict__ outf,
    int M, int N, int K, int relu)
{
    __shared__ ushort Ah[64 * 32], Al[64 * 32];
    __shared__ ushort Bh[64 * 32], Bl[64 * 32];
    const int tid = threadIdx.x;
    const int lane = tid & 63, wid = tid >> 6;
    const int wm = (wid & 1) * 32, wn = (wid >> 1) * 32;
    const int lane15 = lane & 15, quad = lane >> 4;
    const int row0 = blockIdx.y * 64, col0 = blockIdx.x * 64;

    const int srow = tid >> 2;          // 0..63
    const int scl  = tid & 3;
    const int cp   = (scl - (srow >> 1)) & 3;
    const size_t ga = (size_t)(row0 + srow) * K + cp * 8;
    const size_t gb = (size_t)(col0 + srow) * K + cp * 8;
    const int l = tid * 8;

    floatx4 acc[2][2];
#pragma unroll
    for (int i = 0; i < 2; i++)
#pragma unroll
        for (int j = 0; j < 2; j++) acc[i][j] = (floatx4){0.f, 0.f, 0.f, 0.f};

    for (int k0 = 0; k0 < K; k0 += 32) {
        __syncthreads();
        gload16(Ah_g + ga + k0, Ah + l);
        gload16(Al_g + ga + k0, Al + l);
        gload16(Bh_g + gb + k0, Bh + l);
        gload16(Bl_g + gb + k0, Bl + l);
        __syncthreads();

        short8 ah[2], al[2], bh[2], bl[2];
#pragma unroll
        for (int t = 0; t < 2; t++) {
            const int am = wm + t * 16 + lane15;
            const int bn = wn + t * 16 + lane15;
            ah[t] = *(const short8*)(Ah + lds_off(am, quad));
            al[t] = *(const short8*)(Al + lds_off(am, quad));
            bh[t] = *(const short8*)(Bh + lds_off(bn, quad));
            bl[t] = *(const short8*)(Bl + lds_off(bn, quad));
        }
#pragma unroll
        for (int i = 0; i < 2; i++)
#pragma unroll
            for (int j = 0; j < 2; j++) {
                acc[i][j] = __builtin_amdgcn_mfma_f32_16x16x32_bf16(ah[i], bh[j], acc[i][j], 0, 0, 0);
                acc[i][j] = __builtin_amdgcn_mfma_f32_16x16x32_bf16(ah[i], bl[j], acc[i][j], 0, 0, 0);
                acc[i][j] = __builtin_amdgcn_mfma_f32_16x16x32_bf16(al[i], bh[j], acc[i][j], 0, 0, 0);
            }
    }

#pragma unroll
    for (int i = 0; i < 2; i++)
#pragma unroll
        for (int j = 0; j < 2; j++) {
            const int gc = col0 + wn + j * 16 + lane15;
            const int rb = row0 + wm + i * 16 + quad * 4;
            const float bv = bias ? bias[gc] : 0.f;
#pragma unroll
            for (int r = 0; r < 4; r++) {
                const size_t o = (size_t)(rb + r) * N + gc;
                float v = acc[i][j][r] + bv;
                if (resh) v += bf2f(resh[o]) + bf2f(resl[o]);
                if (resf) v += resf[o];
                if (relu) v = fmaxf(v, 0.f);
                if (outf) outf[o] = v;
                if (Ch) {
                    ushort h = f2bf(v);
                    Ch[o] = h;
                    Cl[o] = f2bf(v - bf2f(h));
                }
            }
        }
}

// ---------------------------------------------------------------------------
// Values MLP layer 1: A row r = (kx planes)[r/96,:] - ck[idx[r],:](planes)
// B = t1 hi plane (global_load_lds). TT = bf16(relu(A @ B^T + bias))
// ---------------------------------------------------------------------------
__global__ __launch_bounds__(256) void gemm_diff_bf16(
    const ushort* __restrict__ kxh_g, const ushort* __restrict__ kxl_g,
    const ushort* __restrict__ ckh, const ushort* __restrict__ ckl,
    const int* __restrict__ idx, const ushort* __restrict__ BTh,
    const float* __restrict__ bias, ushort* __restrict__ TT,
    int M, int N, int K)
{
    __shared__ ushort Ah[128 * 32];
    __shared__ ushort Bh[128 * 32];
    const int tid = threadIdx.x;
    const int lane = tid & 63, wid = tid >> 6;
    const int wm = (wid & 1) * 64, wn = (wid >> 1) * 64;
    const int lane15 = lane & 15, quad = lane >> 4;
    const int row0 = blockIdx.y * 128, col0 = blockIdx.x * 128;
    const int sm = tid >> 1, scp = (tid & 1) * 2;

    const int r = row0 + sm;
    const int bidx = r / NC;
    const ushort* kxph = kxh_g + (size_t)bidx * ND + scp * 8;
    const ushort* kxpl = kxl_g + (size_t)bidx * ND + scp * 8;
    const ushort* chp  = ckh + (size_t)idx[r] * ND + scp * 8;
    const ushort* clp  = ckl + (size_t)idx[r] * ND + scp * 8;

    const int srow = tid >> 2;
    const int scl  = tid & 3;
    const int cp   = (scl - (srow >> 1)) & 3;
    const size_t gb0 = (size_t)(col0 + srow) * K + cp * 8;
    const size_t gb1 = (size_t)(col0 + 64 + srow) * K + cp * 8;
    const int l0 = tid * 8, l1 = 2048 + tid * 8;

    floatx4 acc[4][4];
#pragma unroll
    for (int i = 0; i < 4; i++)
#pragma unroll
        for (int j = 0; j < 4; j++) acc[i][j] = (floatx4){0.f, 0.f, 0.f, 0.f};

    for (int k0 = 0; k0 < K; k0 += 32) {
        short8 xh0 = *(const short8*)(kxph + k0);
        short8 xh1 = *(const short8*)(kxph + k0 + 8);
        short8 xl0 = *(const short8*)(kxpl + k0);
        short8 xl1 = *(const short8*)(kxpl + k0 + 8);
        short8 h0 = *(const short8*)(chp + k0);
        short8 h1 = *(const short8*)(chp + k0 + 8);
        short8 lo0 = *(const short8*)(clp + k0);
        short8 lo1 = *(const short8*)(clp + k0 + 8);
        short8 d0, d1;
#pragma unroll
        for (int i = 0; i < 8; i++) {
            float a0 = bf2f((ushort)xh0[i]) + bf2f((ushort)xl0[i]);
            float a1 = bf2f((ushort)xh1[i]) + bf2f((ushort)xl1[i]);
            float c0 = bf2f((ushort)h0[i]) + bf2f((ushort)lo0[i]);
            float c1 = bf2f((ushort)h1[i]) + bf2f((ushort)lo1[i]);
            d0[i] = (short)f2bf(a0 - c0);
            d1[i] = (short)f2bf(a1 - c1);
        }
        __syncthreads();
        gload16(BTh + gb0 + k0, Bh + l0);
        gload16(BTh + gb1 + k0, Bh + l1);
        *(short8*)(Ah + lds_off(sm, scp))     = d0;
        *(short8*)(Ah + lds_off(sm, scp + 1)) = d1;
        __syncthreads();

        short8 ah[4], bh[4];
#pragma unroll
        for (int t = 0; t < 4; t++) {
            ah[t] = *(const short8*)(Ah + lds_off(wm + t * 16 + lane15, quad));
            bh[t] = *(const short8*)(Bh + lds_off(wn + t * 16 + lane15, quad));
        }
#pragma unroll
        for (int i = 0; i < 4; i++)
#pragma unroll
            for (int j = 0; j < 4; j++)
                acc[i][j] = __builtin_amdgcn_mfma_f32_16x16x32_bf16(ah[i], bh[j], acc[i][j], 0, 0, 0);
    }

#pragma unroll
    for (int i = 0; i < 4; i++)
#pragma unroll
        for (int j = 0; j < 4; j++) {
            const int gc = col0 + wn + j * 16 + lane15;
            const int rb = row0 + wm + i * 16 + quad * 4;
            const float bv = bias[gc];
#pragma unroll
            for (int rr = 0; rr < 4; rr++) {
                const size_t o = (size_t)(rb + rr) * N + gc;
                TT[o] = f2bf(fmaxf(acc[i][j][rr] + bv, 0.f));
            }
        }
}

// ---------------------------------------------------------------------------
// Values MLP layer 2: A bf16 [M][K], B hi plane [N][K]: C(f32) = A @ B^T
// 128M x 64N tile (3 blocks/CU at N=512).
// ---------------------------------------------------------------------------
__global__ __launch_bounds__(256) void gemm_bf16_n64(
    const ushort* __restrict__ A, const ushort* __restrict__ BTh,
    float* __restrict__ C, int M, int N, int K)
{
    __shared__ ushort Ah[128 * 32];
    __shared__ ushort Bh[64 * 32];
    const int tid = threadIdx.x;
    const int lane = tid & 63, wid = tid >> 6;
    const int wm = wid * 32;
    const int lane15 = lane & 15, quad = lane >> 4;
    const int row0 = blockIdx.y * 128, col0 = blockIdx.x * 64;

    const int srow = tid >> 2;
    const int scl  = tid & 3;
    const int cp   = (scl - (srow >> 1)) & 3;
    const size_t ga0 = (size_t)(row0 + srow) * K + cp * 8;
    const size_t ga1 = (size_t)(row0 + 64 + srow) * K + cp * 8;
    const size_t gb  = (size_t)(col0 + srow) * K + cp * 8;
    const int l0 = tid * 8, l1 = 2048 + tid * 8;

    floatx4 acc[2][4];
#pragma unroll
    for (int i = 0; i < 2; i++)
#pragma unroll
        for (int j = 0; j < 4; j++) acc[i][j] = (floatx4){0.f, 0.f, 0.f, 0.f};

    for (int k0 = 0; k0 < K; k0 += 32) {
        __syncthreads();
        gload16(A + ga0 + k0, Ah + l0);
        gload16(A + ga1 + k0, Ah + l1);
        gload16(BTh + gb + k0, Bh + l0);
        __syncthreads();

        short8 ah[2], bh[4];
#pragma unroll
        for (int t = 0; t < 2; t++)
            ah[t] = *(const short8*)(Ah + lds_off(wm + t * 16 + lane15, quad));
#pragma unroll
        for (int j = 0; j < 4; j++)
            bh[j] = *(const short8*)(Bh + lds_off(j * 16 + lane15, quad));
#pragma unroll
        for (int i = 0; i < 2; i++)
#pragma unroll
            for (int j = 0; j < 4; j++)
                acc[i][j] = __builtin_amdgcn_mfma_f32_16x16x32_bf16(ah[i], bh[j], acc[i][j], 0, 0, 0);
    }

#pragma unroll
    for (int i = 0; i < 2; i++)
#pragma unroll
        for (int j = 0; j < 4; j++) {
            const int gc = col0 + j * 16 + lane15;
            const int rb = row0 + wm + i * 16 + quad * 4;
#pragma unroll
            for (int rr = 0; rr < 4; rr++)
                C[(size_t)(rb + rr) * N + gc] = acc[i][j][rr];
        }
}

// ---------------------------------------------------------------------------
// Prep kernels
// ---------------------------------------------------------------------------
__global__ __launch_bounds__(256) void split_wt_kernel(
    const float* __restrict__ W, ushort* __restrict__ WTh,
    ushort* __restrict__ WTl, int K, int N)
{
    const int o = blockIdx.x * 256 + threadIdx.x;
    if (o < K * N) {
        const int n = o / K, k = o - n * K;
        const float x = W[(size_t)k * N + n];
        const ushort h = f2bf(x);
        WTh[o] = h;
        WTl[o] = f2bf(x - bf2f(h));
    }
}

__global__ __launch_bounds__(256) void split_pl_kernel(
    const float* __restrict__ X, ushort* __restrict__ Xh,
    ushort* __restrict__ Xl, int n)
{
    const int i = blockIdx.x * 256 + threadIdx.x;
    if (i < n) {
        const float x = X[i];
        const ushort h = f2bf(x);
        Xh[i] = h;
        Xl[i] = f2bf(x - bf2f(h));
    }
}

// ---------------------------------------------------------------------------
// LayerNorm rows of 512, f32 in / f32 out
// ---------------------------------------------------------------------------
__global__ __launch_bounds__(256) void ln_kernel(
    const float* __restrict__ X, const float* __restrict__ g,
    const float* __restrict__ b, float* __restrict__ Y, int relu)
{
    const int lane = threadIdx.x & 63;
    const int row  = blockIdx.x * 4 + (threadIdx.x >> 6);
    const float* x = X + (size_t)row * ND;
    const int d = lane * 8;

    float4 v0 = *(const float4*)(x + d);
    float4 v1 = *(const float4*)(x + d + 4);
    float s = v0.x + v0.y + v0.z + v0.w + v1.x + v1.y + v1.z + v1.w;
    float q = v0.x*v0.x + v0.y*v0.y + v0.z*v0.z + v0.w*v0.w
            + v1.x*v1.x + v1.y*v1.y + v1.z*v1.z + v1.w*v1.w;
#pragma unroll
    for (int off = 32; off; off >>= 1) {
        s += __shfl_down(s, off);
        q += __shfl_down(q, off);
    }
    s = __shfl(s, 0); q = __shfl(q, 0);
    const float mean = s * (1.f / ND);
    const float var  = q * (1.f / ND) - mean * mean;
    const float rs   = rsqrtf(var + 1e-5f);

    float4 g0 = *(const float4*)(g + d);
    float4 g1 = *(const float4*)(g + d + 4);
    float4 b0 = *(const float4*)(b + d);
    float4 b1 = *(const float4*)(b + d + 4);
    float4 o0, o1;
    o0.x = (v0.x - mean) * rs * g0.x + b0.x;
    o0.y = (v0.y - mean) * rs * g0.y + b0.y;
    o0.z = (v0.z - mean) * rs * g0.z + b0.z;
    o0.w = (v0.w - mean) * rs * g0.w + b0.w;
    o1.x = (v1.x - mean) * rs * g1.x + b1.x;
    o1.y = (v1.y - mean) * rs * g1.y + b1.y;
    o1.z = (v1.z - mean) * rs * g1.z + b1.z;
    o1.w = (v1.w - mean) * rs * g1.w + b1.w;
    if (relu) {
        o0.x = fmaxf(o0.x, 0.f); o0.y = fmaxf(o0.y, 0.f);
        o0.z = fmaxf(o0.z, 0.f); o0.w = fmaxf(o0.w, 0.f);
        o1.x = fmaxf(o1.x, 0.f); o1.y = fmaxf(o1.y, 0.f);
        o1.z = fmaxf(o1.z, 0.f); o1.w = fmaxf(o1.w, 0.f);
    }
    float* y = Y + (size_t)row * ND;
    *(float4*)(y + d)     = o0;
    *(float4*)(y + d + 4) = o1;
}

// LayerNorm rows of 512, planes in / planes out
__global__ __launch_bounds__(256) void ln_pl_kernel(
    const ushort* __restrict__ Xh, const ushort* __restrict__ Xl,
    const float* __restrict__ g, const float* __restrict__ b,
    ushort* __restrict__ Yh, ushort* __restrict__ Yl)
{
    const int lane = threadIdx.x & 63;
    const int row  = blockIdx.x * 4 + (threadIdx.x >> 6);
    const int d = lane * 8;
    const size_t base = (size_t)row * ND + d;

    short8 xh = *(const short8*)(Xh + base);
    short8 xl = *(const short8*)(Xl + base);
    float v[8];
#pragma unroll
    for (int i = 0; i < 8; i++) v[i] = bf2f((ushort)xh[i]) + bf2f((ushort)xl[i]);

    float s = 0.f, q = 0.f;
#pragma unroll
    for (int i = 0; i < 8; i++) { s += v[i]; q += v[i] * v[i]; }
#pragma unroll
    for (int off = 32; off; off >>= 1) {
        s += __shfl_down(s, off);
        q += __shfl_down(q, off);
    }
    s = __shfl(s, 0); q = __shfl(q, 0);
    const float mean = s * (1.f / ND);
    const float var  = q * (1.f / ND) - mean * mean;
    const float rs   = rsqrtf(var + 1e-5f);

    short8 yh, yl;
#pragma unroll
    for (int i = 0; i < 8; i++) {
        const float o = (v[i] - mean) * rs * g[d + i] + b[d + i];
        const ushort h = f2bf(o);
        yh[i] = (short)h;
        yl[i] = (short)f2bf(o - bf2f(h));
    }
    *(short8*)(Yh + base) = yh;
    *(short8*)(Yl + base) = yl;
}

__global__ __launch_bounds__(256) void sqnorm_pl_kernel(
    const ushort* __restrict__ Xh, const ushort* __restrict__ Xl,
    float* __restrict__ sq)
{
    const int lane = threadIdx.x & 63;
    const int row  = blockIdx.x * 4 + (threadIdx.x >> 6);
    const size_t base = (size_t)row * ND + lane * 8;
    short8 xh = *(const short8*)(Xh + base);
    short8 xl = *(const short8*)(Xl + base);
    float q = 0.f;
#pragma unroll
    for (int i = 0; i < 8; i++) {
        float v = bf2f((ushort)xh[i]) + bf2f((ushort)xl[i]);
        q += v * v;
    }
#pragma unroll
    for (int off = 32; off; off >>= 1) q += __shfl_down(q, off);
    if (lane == 0) sq[row] = q;
}

// ---------------------------------------------------------------------------
// Two-stage exact top-96: adaptive-range radix select.
// ---------------------------------------------------------------------------
__device__ __forceinline__ unsigned fkey(float f)
{
    unsigned u = __float_as_uint(f);
    return (u & 0x80000000u) ? ~u : (u | 0x80000000u);
}
__device__ __forceinline__ float inv_fkey(unsigned u)
{
    return __uint_as_float((u & 0x80000000u) ? (u & 0x7FFFFFFFu) : ~u);
}

struct SelState {
    unsigned lo;
    unsigned long long hi;   // exclusive
    int krem;
    int done;
    unsigned long long T;    // threshold
    int need;                // how many keys == T to take
};

template <int KPT>
__device__ __forceinline__ void adaptive_select(
    const unsigned (&key)[KPT], unsigned* hist, unsigned* wtot,
    SelState* st, int tid, int kwant)
{
    const int lane = tid & 63, wid = tid >> 6;

    unsigned mn = 0xFFFFFFFFu, mx = 0u;
#pragma unroll
    for (int j = 0; j < KPT; j++) {
        mn = min(mn, key[j]);
        mx = max(mx, key[j]);
    }
#pragma unroll
    for (int off = 32; off; off >>= 1) {
        mn = min(mn, (unsigned)__shfl_down((int)mn, off));
        mx = max(mx, (unsigned)__shfl_down((int)mx, off));
    }
    if (lane == 0) { hist[wid] = mn; hist[8 + wid] = mx; }
    if (tid == 0) st->done = 0;
    __syncthreads();
    if (tid == 0) {
        unsigned gmn = min(min(hist[0], hist[1]), min(hist[2], hist[3]));
        unsigned gmx = max(max(hist[8], hist[9]), max(hist[10], hist[11]));
        st->lo = gmn;
        st->hi = (unsigned long long)gmx + 1ull;
        st->krem = kwant;
    }
    __syncthreads();

    for (int iter = 0; iter < 6 && !st->done; iter++) {
        const unsigned lo = st->lo;
        const unsigned long long hi = st->hi;
        const int krem = st->krem;
        const unsigned long long span = hi - lo;
        int shift = 0;
        if (span > 256ull) {
            const int nb = 64 - __builtin_clzll(span - 1ull);
            shift = nb - 8;
        }
        hist[tid] = 0u;
        __syncthreads();
#pragma unroll
        for (int j = 0; j < KPT; j++) {
            const unsigned u = key[j];
            if (u >= lo && (unsigned long long)u < hi)
                atomicAdd(&hist[(u - lo) >> shift], 1u);
        }
        __syncthreads();
        const unsigned c = hist[tid];
        unsigned v = c;
#pragma unroll
        for (int off = 1; off < 64; off <<= 1) {
            const unsigned t = (unsigned)__shfl_up((int)v, off);
            if (lane >= off) v += t;
        }
        if (lane == 63) wtot[wid] = v;
        __syncthreads();
        unsigned pre = 0;
        for (int w = 0; w < 3; w++) pre += (w < wid) ? wtot[w] : 0u;
        const int incl = (int)(v + pre);
        const int excl = incl - (int)c;
        if (excl < krem && incl >= krem) {
            const unsigned long long binlo =
                (unsigned long long)lo + ((unsigned long long)tid << shift);
            if (shift == 0) {
                st->T = binlo;
                st->need = krem - excl;
                st->done = 1;
            } else if (incl == krem) {
                st->T = binlo + (1ull << shift);
                st->need = 0;
                st->done = 1;
            } else {
                st->lo = (unsigned)binlo;
                const unsigned long long nhi = binlo + (1ull << shift);
                st->hi = nhi < hi ? nhi : hi;
                st->krem = krem - excl;
            }
        }
        __syncthreads();
    }
}

__global__ __launch_bounds__(256) void topk_seg(
    const float* __restrict__ S, unsigned* __restrict__ K1key,
    int* __restrict__ K1idx)
{
    const int r = blockIdx.y, seg = blockIdx.x;
    const float* p = S + (size_t)r * NN + seg * TK_SEG;
    __shared__ unsigned hist[256];
    __shared__ unsigned wtot[4];
    __shared__ SelState st;
    __shared__ int cA, cB;
    const int tid = threadIdx.x;

    unsigned key[16];
#pragma unroll
    for (int j = 0; j < 16; j++) key[j] = fkey(p[tid + j * 256]);

    if (tid == 0) { cA = 0; cB = 0; }
    adaptive_select<16>(key, hist, wtot, &st, tid, NC);

    const unsigned long long T = st.T;
    const int need = st.need;
    const int cntLess = NC - need;
    const size_t obase = ((size_t)r * TK_SPLIT + seg) * NC;
#pragma unroll
    for (int j = 0; j < 16; j++) {
        const unsigned u = key[j];
        if ((unsigned long long)u < T) {
            const int pos = atomicAdd(&cA, 1);
            K1key[obase + pos] = u;
            K1idx[obase + pos] = seg * TK_SEG + tid + j * 256;
        } else if ((unsigned long long)u == T) {
            const int pos = atomicAdd(&cB, 1);
            if (pos < need) {
                K1key[obase + cntLess + pos] = u;
                K1idx[obase + cntLess + pos] = seg * TK_SEG + tid + j * 256;
            }
        }
    }
}

__global__ __launch_bounds__(256) void topk_merge(
    const unsigned* __restrict__ K1key, const int* __restrict__ K1idx,
    int* __restrict__ idx_out, float* __restrict__ val_out, int b0)
{
    const int r = blockIdx.x;
    const int b = b0 + r;
    __shared__ unsigned hist[256];
    __shared__ unsigned wtot[4];
    __shared__ SelState st;
    __shared__ int cA, cB;
    const int tid = threadIdx.x;
    const size_t ibase = (size_t)r * TK_CAND;

    unsigned key[6];
    int      kidx[6];
#pragma unroll
    for (int j = 0; j < 6; j++) {
        key[j]  = K1key[ibase + tid + j * 256];
        kidx[j] = K1idx[ibase + tid + j * 256];
    }

    if (tid == 0) { cA = 0; cB = 0; }
    adaptive_select<6>(key, hist, wtot, &st, tid, NC);

    const unsigned long long T = st.T;
    const int need = st.need;
    const int cntLess = NC - need;
#pragma unroll
    for (int j = 0; j < 6; j++) {
        const unsigned u = key[j];
        if ((unsigned long long)u < T) {
            const int pos = atomicAdd(&cA, 1);
            idx_out[b * NC + pos] = kidx[j];
            val_out[b * NC + pos] = inv_fkey(u);
        } else if ((unsigned long long)u == T) {
            const int pos = atomicAdd(&cB, 1);
            if (pos < need) {
                idx_out[b * NC + cntLess + pos] = kidx[j];
                val_out[b * NC + cntLess + pos] = inv_fkey(u);
            }
        }
    }
}

// ---------------------------------------------------------------------------
__global__ __launch_bounds__(128) void probs_kernel(
    const float* __restrict__ svals, float* __restrict__ probs)
{
    const int b = blockIdx.x;
    const int tid = threadIdx.x;
    __shared__ float red[128];
    const bool valid = tid < NC;
    float s = valid ? -svals[b * NC + tid] : -3.4e38f;
    red[tid] = s;
    __syncthreads();
#pragma unroll
    for (int off = 64; off; off >>= 1) {
        if (tid < off) red[tid] = fmaxf(red[tid], red[tid + off]);
        __syncthreads();
    }
    const float m = red[0];
    __syncthreads();
    float e = valid ? expf(s - m) : 0.f;
    red[tid] = e;
    __syncthreads();
#pragma unroll
    for (int off = 64; off; off >>= 1) {
        if (tid < off) red[tid] += red[tid + off];
        __syncthreads();
    }
    const float sum = red[0];
    if (valid) probs[b * NC + tid] = e / sum;
}

// ctx: xin given as planes (encoder-out x)
__global__ __launch_bounds__(256) void ctx_kernel(
    const float* __restrict__ VAL, const float* __restrict__ probs,
    const float* __restrict__ cand_y, const int* __restrict__ idx,
    const float* __restrict__ labW, const float* __restrict__ labb,
    const ushort* __restrict__ xinh, const ushort* __restrict__ xinl,
    float* __restrict__ xout, int b0)
{
    const int b_loc = blockIdx.x;
    const int b = b0 + b_loc;
    const int tid = threadIdx.x;
    __shared__ float pv[NC];
    __shared__ float red[256];
    float py_part = 0.f;
    if (tid < NC) {
        float p = probs[b * NC + tid];
        pv[tid] = p;
        py_part = p * cand_y[idx[b * NC + tid]];
    }
    red[tid] = py_part;
    __syncthreads();
#pragma unroll
    for (int off = 128; off; off >>= 1) {
        if (tid < off) red[tid] += red[tid + off];
        __syncthreads();
    }
    const float py = red[0];

    for (int d = tid; d < ND; d += 256) {
        const float* vp = VAL + (size_t)b_loc * NC * ND + d;
        float acc = 0.f;
#pragma unroll 8
        for (int c = 0; c < NC; c++) acc += pv[c] * vp[(size_t)c * ND];
        float ctx = acc + py * labW[d] + labb[d];
        const size_t o = (size_t)b * ND + d;
        xout[o] = bf2f(xinh[o]) + bf2f(xinl[o]) + ctx;
    }
}

__global__ __launch_bounds__(64) void head_kernel(
    const float* __restrict__ X, const float* __restrict__ hW,
    const float* __restrict__ hb, float* __restrict__ out)
{
    const int b = blockIdx.x;
    const int lane = threadIdx.x;
    const float* x = X + (size_t)b * ND;
    float acc = 0.f;
#pragma unroll
    for (int j = 0; j < 8; j++) {
        int d = lane + 64 * j;
        acc += x[d] * hW[d];
    }
#pragma unroll
    for (int off = 32; off; off >>= 1) acc += __shfl_down(acc, off);
    if (lane == 0) out[b] = acc + hb[0];
}

// ---------------------------------------------------------------------------
extern "C" void kernel_launch(void* const* d_in, const int* in_sizes, int n_in,
                              void* d_out, int out_size, void* d_ws, size_t ws_size,
                              hipStream_t stream)
{
    const float* x_num    = (const float*)d_in[0];
    const float* cand_num = (const float*)d_in[1];
    const float* cand_y   = (const float*)d_in[2];
    const float* lin_W    = (const float*)d_in[3];
    const float* lin_b    = (const float*)d_in[4];
    const float* e_W1     = (const float*)d_in[5];
    const float* e_b1     = (const float*)d_in[6];
    const float* e_W2     = (const float*)d_in[7];
    const float* e_b2     = (const float*)d_in[8];
    const float* mix_g    = (const float*)d_in[9];
    const float* mix_b    = (const float*)d_in[10];
    const float* K_W      = (const float*)d_in[11];
    const float* K_b      = (const float*)d_in[12];
    const float* lab_W    = (const float*)d_in[13];
    const float* lab_b    = (const float*)d_in[14];
    const float* T_W1     = (const float*)d_in[15];
    const float* T_b1     = (const float*)d_in[16];
    const float* T_W2     = (const float*)d_in[17];
    const float* p_ln_g   = (const float*)d_in[18];
    const float* p_ln_b   = (const float*)d_in[19];
    const float* p_W1     = (const float*)d_in[20];
    const float* p_b1     = (const float*)d_in[21];
    const float* p_W2     = (const float*)d_in[22];
    const float* p_b2     = (const float*)d_in[23];
    const float* h_ln_g   = (const float*)d_in[24];
    const float* h_ln_b   = (const float*)d_in[25];
    const float* h_W      = (const float*)d_in[26];
    const float* h_b      = (const float*)d_in[27];
    float* out = (float*)d_out;
    (void)in_sizes; (void)n_in; (void)out_size; (void)ws_size;

    // ---- workspace layout (~245 MB) ----
    size_t off = 0;
    auto ralloc = [&](size_t bytes) -> void* {
        void* p = (char*)d_ws + off;
        off += (bytes + 255) & ~(size_t)255;
        return p;
    };
    auto falloc = [&](size_t n) -> float*  { return (float*)ralloc(n * 4); };
    auto ualloc = [&](size_t n) -> ushort* { return (ushort*)ralloc(n * 2); };

    // bf16 plane weights [N][K]
    ushort* WP_lin_h = ualloc((size_t)ND * NF);
    ushort* WP_lin_l = ualloc((size_t)ND * NF);
    ushort* WP_e1_h  = ualloc((size_t)NDB * ND);
    ushort* WP_e1_l  = ualloc((size_t)NDB * ND);
    ushort* WP_e2_h  = ualloc((size_t)ND * NDB);
    ushort* WP_e2_l  = ualloc((size_t)ND * NDB);
    ushort* WP_kw_h  = ualloc((size_t)ND * ND);
    ushort* WP_kw_l  = ualloc((size_t)ND * ND);
    ushort* WP_t1_h  = ualloc((size_t)NDB * ND);
    ushort* WP_t1_l  = ualloc((size_t)NDB * ND);
    ushort* WP_t2_h  = ualloc((size_t)ND * NDB);
    ushort* WP_t2_l  = ualloc((size_t)ND * NDB);
    ushort* WP_p1_h  = ualloc((size_t)NDB * ND);
    ushort* WP_p1_l  = ualloc((size_t)NDB * ND);
    ushort* WP_p2_h  = ualloc((size_t)ND * NDB);
    ushort* WP_p2_l  = ualloc((size_t)ND * NDB);

    ushort* R_CKh = ualloc((size_t)NN * ND);
    ushort* R_CKl = ualloc((size_t)NN * ND);
    float*  R_sq  = falloc(NN);

    // x-path plane activations
    ushort* XNh = ualloc((size_t)NB * NF);
    ushort* XNl = ualloc((size_t)NB * NF);
    ushort* Hxh = ualloc((size_t)NB * ND);
    ushort* Hxl = ualloc((size_t)NB * ND);
    ushort* Txh = ualloc((size_t)NB * NDB);
    ushort* Txl = ualloc((size_t)NB * NDB);
    ushort* X2h = ualloc((size_t)NB * ND);
    ushort* X2l = ualloc((size_t)NB * ND);
    ushort* Gxh = ualloc((size_t)NB * ND);
    ushort* Gxl = ualloc((size_t)NB * ND);
    ushort* Lxh = ualloc((size_t)NB * ND);
    ushort* Lxl = ualloc((size_t)NB * ND);
    ushort* Tph = ualloc((size_t)NB * NDB);
    ushort* Tpl = ualloc((size_t)NB * NDB);
    ushort* R_kxh = ualloc((size_t)NB * ND);
    ushort* R_kxl = ualloc((size_t)NB * ND);

    int*    R_idx = (int*)ralloc((size_t)NB * NC * 4);
    float*  R_ssel= falloc((size_t)NB * NC);
    float*  R_prob= falloc((size_t)NB * NC);
    float*  R_xupd= falloc((size_t)NB * ND);
    float*  R_lnx = falloc((size_t)NB * ND);
    float*  R_x2  = falloc((size_t)NB * ND);
    float*  R_lnx2= falloc((size_t)NB * ND);
    unsigned* K1key = (unsigned*)ralloc((size_t)BB_C * TK_CAND * 4);
    int*      K1idx = (int*)ralloc((size_t)BB_C * TK_CAND * 4);
    char* SCR = (char*)ralloc((size_t)70 * 1024 * 1024);

    // ---- 0. weight prep (split-transpose to planes) ----
    auto sw = [&](const float* W, ushort* WTh, ushort* WTl, int K, int N) {
        split_wt_kernel<<<dim3((K * N + 255) / 256), dim3(256), 0, stream>>>(W, WTh, WTl, K, N);
    };
    sw(lin_W, WP_lin_h, WP_lin_l, NF, ND);
    sw(e_W1,  WP_e1_h,  WP_e1_l,  ND, NDB);
    sw(e_W2,  WP_e2_h,  WP_e2_l,  NDB, ND);
    sw(K_W,   WP_kw_h,  WP_kw_l,  ND, ND);
    sw(T_W1,  WP_t1_h,  WP_t1_l,  ND, NDB);
    sw(T_W2,  WP_t2_h,  WP_t2_l,  NDB, ND);
    sw(p_W1,  WP_p1_h,  WP_p1_l,  ND, NDB);
    sw(p_W2,  WP_p2_h,  WP_p2_l,  NDB, ND);

    auto gss = [&](const ushort* Ah, const ushort* Al, const ushort* Bh,
                   const ushort* Bl, const float* bias, const ushort* resh,
                   const ushort* resl, const float* sq, float* Sf,
                   ushort* Ch, ushort* Cl, int M, int Nn, int K, int relu) {
        gemm_ss<<<dim3(Nn / 128, M / 128), dim3(256), 0, stream>>>(
            Ah, Al, Bh, Bl, bias, resh, resl, sq, Sf, Ch, Cl, M, Nn, K, relu);
    };
    auto gn64 = [&](const ushort* Ah, const ushort* Al, const ushort* Bh,
                    const ushort* Bl, const float* bias, const ushort* resh,
                    const ushort* resl, ushort* Ch, ushort* Cl,
                    int M, int Nn, int K, int relu) {
        gemm_ss_n64<<<dim3(Nn / 64, M / 128), dim3(256), 0, stream>>>(
            Ah, Al, Bh, Bl, bias, resh, resl, Ch, Cl, M, Nn, K, relu);
    };
    auto gsm = [&](const ushort* Ah, const ushort* Al, const ushort* Bh,
                   const ushort* Bl, const float* bias, const ushort* resh,
                   const ushort* resl, const float* resf, ushort* Ch,
                   ushort* Cl, float* outf, int M, int Nn, int K, int relu) {
        gemm_ss_small<<<dim3(Nn / 64, M / 64), dim3(256), 0, stream>>>(
            Ah, Al, Bh, Bl, bias, resh, resl, resf, Ch, Cl, outf, M, Nn, K, relu);
    };

    // ---- 1. candidate encode (chunked; occupancy-tuned tiles) ----
    {
        ushort* CNh = (ushort*)SCR;
        ushort* CNl = CNh + (size_t)CH_A * NF;
        ushort* Hh  = CNl + (size_t)CH_A * NF;
        ushort* Hl  = Hh  + (size_t)CH_A * ND;
        ushort* Th  = Hl  + (size_t)CH_A * ND;
        ushort* Tl  = Th  + (size_t)CH_A * NDB;
        ushort* H2h = Tl  + (size_t)CH_A * NDB;
        ushort* H2l = H2h + (size_t)CH_A * ND;
        ushort* Gh  = Th;   // overlay: T dead after e2
        ushort* Gl  = Tl;

        for (int n0 = 0; n0 < NN; n0 += CH_A) {
            split_pl_kernel<<<dim3((CH_A * NF + 255) / 256), dim3(256), 0, stream>>>(
                cand_num + (size_t)n0 * NF, CNh, CNl, CH_A * NF);
            // lin: N=512 -> 64x64 tile, grid (8,128)=1024 blocks
            gsm(CNh, CNl, WP_lin_h, WP_lin_l, lin_b, nullptr, nullptr, nullptr,
                Hh, Hl, nullptr, CH_A, ND, NF, 0);
            // e1: N=1024 -> 128x64 tile, grid (16,64)=1024 blocks
            gn64(Hh, Hl, WP_e1_h, WP_e1_l, e_b1, nullptr, nullptr,
                 Th, Tl, CH_A, NDB, ND, 1);
            // e2: N=512 -> 64x64 tile, grid (8,128)=1024 blocks (+residual)
            gsm(Th, Tl, WP_e2_h, WP_e2_l, e_b2, Hh, Hl, nullptr,
                H2h, H2l, nullptr, CH_A, ND, NDB, 0);
            ln_pl_kernel<<<dim3(CH_A / 4), dim3(256), 0, stream>>>(
                H2h, H2l, mix_g, mix_b, Gh, Gl);
            // kw: N=512 -> 64x64 tile
            gsm(Gh, Gl, WP_kw_h, WP_kw_l, K_b, nullptr, nullptr, nullptr,
                R_CKh + (size_t)n0 * ND, R_CKl + (size_t)n0 * ND, nullptr,
                CH_A, ND, ND, 0);
            sqnorm_pl_kernel<<<dim3(CH_A / 4), dim3(256), 0, stream>>>(
                R_CKh + (size_t)n0 * ND, R_CKl + (size_t)n0 * ND, R_sq + n0);
        }
    }

    // ---- 2. x encode (plane operands, 64x64-tile small GEMM) ----
    split_pl_kernel<<<dim3((NB * NF + 255) / 256), dim3(256), 0, stream>>>(
        x_num, XNh, XNl, NB * NF);
    gsm(XNh, XNl, WP_lin_h, WP_lin_l, lin_b, nullptr, nullptr, nullptr,
        Hxh, Hxl, nullptr, NB, ND, NF, 0);
    gsm(Hxh, Hxl, WP_e1_h, WP_e1_l, e_b1, nullptr, nullptr, nullptr,
        Txh, Txl, nullptr, NB, NDB, ND, 1);
    gsm(Txh, Txl, WP_e2_h, WP_e2_l, e_b2, Hxh, Hxl, nullptr,
        X2h, X2l, nullptr, NB, ND, NDB, 0);
    ln_pl_kernel<<<dim3(NB / 4), dim3(256), 0, stream>>>(
        X2h, X2l, mix_g, mix_b, Gxh, Gxl);
    gsm(Gxh, Gxl, WP_kw_h, WP_kw_l, K_b, nullptr, nullptr, nullptr,
        R_kxh, R_kxl, nullptr, NB, ND, ND, 0);

    // ---- 3. scores + two-stage top-96 + softmax ----
    for (int b0 = 0; b0 < NB; b0 += BB_C) {
        float* S = (float*)SCR;
        gss(R_kxh + (size_t)b0 * ND, R_kxl + (size_t)b0 * ND, R_CKh, R_CKl,
            nullptr, nullptr, nullptr, R_sq, S, nullptr, nullptr,
            BB_C, NN, ND, 0);
        topk_seg<<<dim3(TK_SPLIT, BB_C), dim3(256), 0, stream>>>(S, K1key, K1idx);
        topk_merge<<<dim3(BB_C), dim3(256), 0, stream>>>(K1key, K1idx,
                                                         R_idx, R_ssel, b0);
    }
    probs_kernel<<<dim3(NB), dim3(128), 0, stream>>>(R_ssel, R_prob);

    // ---- 4. values path (plain bf16 MFMA, diff fused) ----
    for (int b0 = 0; b0 < NB; b0 += BB_D) {
        ushort* TT = (ushort*)SCR;                                  // [M,1024] bf16
        float* VAL = (float*)(SCR + (size_t)BB_D * NC * NDB * 2);   // f32 after TT
        const int M = BB_D * NC;   // 12288
        gemm_diff_bf16<<<dim3(NDB / 128, M / 128), dim3(256), 0, stream>>>(
            R_kxh + (size_t)b0 * ND, R_kxl + (size_t)b0 * ND,
            R_CKh, R_CKl, R_idx + b0 * NC,
            WP_t1_h, T_b1, TT, M, NDB, ND);
        gemm_bf16_n64<<<dim3(ND / 64, M / 128), dim3(256), 0, stream>>>(
            TT, WP_t2_h, VAL, M, ND, NDB);
        ctx_kernel<<<dim3(BB_D), dim3(256), 0, stream>>>(
            VAL, R_prob, cand_y, R_idx, lab_W, lab_b, X2h, X2l, R_xupd, b0);
    }

    // ---- 5. predictor block + head ----
    ln_kernel<<<dim3(NB / 4), dim3(256), 0, stream>>>(R_xupd, p_ln_g, p_ln_b, R_lnx, 0);
    split_pl_kernel<<<dim3((NB * ND + 255) / 256), dim3(256), 0, stream>>>(
        R_lnx, Lxh, Lxl, NB * ND);
    gsm(Lxh, Lxl, WP_p1_h, WP_p1_l, p_b1, nullptr, nullptr, nullptr,
        Tph, Tpl, nullptr, NB, NDB, ND, 1);
    gsm(Tph, Tpl, WP_p2_h, WP_p2_l, p_b2, nullptr, nullptr, R_xupd,
        nullptr, nullptr, R_x2, NB, ND, NDB, 0);
    ln_kernel<<<dim3(NB / 4), dim3(256), 0, stream>>>(R_x2, h_ln_g, h_ln_b, R_lnx2, 1);
    head_kernel<<<dim3(NB), dim3(64), 0, stream>>>(R_lnx2, h_W, h_b, out);
}

// Round 12
// 2648.165 us; speedup vs baseline: 1.4825x; 1.0374x over previous
//
#include <hip/hip_runtime.h>

// Problem constants
#define NB   1024
#define NN   65536
#define NF   64
#define ND   512
#define NDB  1024
#define NC   96

// Chunking
#define CH_A 8192      // candidate-encode chunk rows
#define BB_C 256       // scores/topk chunk of B rows
#define BB_D 128       // values-path chunk of B rows

// top-k segmentation
#define TK_SPLIT 16
#define TK_SEG   (NN / TK_SPLIT)   // 4096
#define TK_CAND  (TK_SPLIT * NC)   // 1536

typedef unsigned short ushort;
typedef __attribute__((ext_vector_type(8))) short short8;
typedef __attribute__((ext_vector_type(4))) float floatx4;

__device__ __forceinline__ ushort f2bf(float f) {   // RNE f32->bf16
    unsigned u = __float_as_uint(f);
    u += 0x7fffu + ((u >> 16) & 1u);
    return (ushort)(u >> 16);
}
__device__ __forceinline__ float bf2f(ushort h) {
    return __uint_as_float(((unsigned)h) << 16);
}
// LDS plane: [m][k] bf16, k-stride 32, 16B-chunk XOR swizzle -> conflict-free
__device__ __forceinline__ int lds_off(int m, int c) {
    return m * 32 + (((c + (m >> 1)) & 3) << 3);
}

// async global->LDS 16B
__device__ __forceinline__ void gload16(const ushort* g, ushort* l)
{
    void* gv = (void*)g;
    void* lv = (void*)l;
    __builtin_amdgcn_global_load_lds(
        (__attribute__((address_space(1))) void*)gv,
        (__attribute__((address_space(3))) void*)lv, 16, 0, 0);
}

// ---------------------------------------------------------------------------
// Split-plane MFMA GEMM (f32-emulating, 3 MFMA), NT, 128x128 tile.
// SCORES kernel. Block roles swapped (x=row-tile, y=col-tile) so the 2
// row-tiles sharing a CK col-tile are dispatch-adjacent -> same XCD, L2 hit.
// ---------------------------------------------------------------------------
__global__ __launch_bounds__(256) void gemm_ss(
    const ushort* __restrict__ Ah_g, const ushort* __restrict__ Al_g,
    const ushort* __restrict__ Bh_g, const ushort* __restrict__ Bl_g,
    const float* __restrict__ scoresq, float* __restrict__ Sf,
    int M, int N, int K)
{
    __shared__ ushort Ah[128 * 32], Al[128 * 32];
    __shared__ ushort Bh[128 * 32], Bl[128 * 32];
    const int tid = threadIdx.x;
    const int lane = tid & 63, wid = tid >> 6;
    const int wm = (wid & 1) * 64, wn = (wid >> 1) * 64;
    const int lane15 = lane & 15, quad = lane >> 4;
    const int row0 = blockIdx.x * 128, col0 = blockIdx.y * 128;

    const int srow = tid >> 2;
    const int scl  = tid & 3;
    const int cp   = (scl - (srow >> 1)) & 3;
    const size_t ga0 = (size_t)(row0 + srow) * K + cp * 8;
    const size_t ga1 = (size_t)(row0 + 64 + srow) * K + cp * 8;
    const size_t gb0 = (size_t)(col0 + srow) * K + cp * 8;
    const size_t gb1 = (size_t)(col0 + 64 + srow) * K + cp * 8;
    const int l0 = tid * 8;
    const int l1 = 2048 + tid * 8;

    floatx4 acc[4][4];
#pragma unroll
    for (int i = 0; i < 4; i++)
#pragma unroll
        for (int j = 0; j < 4; j++) acc[i][j] = (floatx4){0.f, 0.f, 0.f, 0.f};

    for (int k0 = 0; k0 < K; k0 += 32) {
        __syncthreads();
        gload16(Ah_g + ga0 + k0, Ah + l0);
        gload16(Ah_g + ga1 + k0, Ah + l1);
        gload16(Al_g + ga0 + k0, Al + l0);
        gload16(Al_g + ga1 + k0, Al + l1);
        gload16(Bh_g + gb0 + k0, Bh + l0);
        gload16(Bh_g + gb1 + k0, Bh + l1);
        gload16(Bl_g + gb0 + k0, Bl + l0);
        gload16(Bl_g + gb1 + k0, Bl + l1);
        __syncthreads();

        short8 ah[4], al[4], bh[4], bl[4];
#pragma unroll
        for (int t = 0; t < 4; t++) {
            const int am = wm + t * 16 + lane15;
            const int bn = wn + t * 16 + lane15;
            ah[t] = *(const short8*)(Ah + lds_off(am, quad));
            al[t] = *(const short8*)(Al + lds_off(am, quad));
            bh[t] = *(const short8*)(Bh + lds_off(bn, quad));
            bl[t] = *(const short8*)(Bl + lds_off(bn, quad));
        }
#pragma unroll
        for (int i = 0; i < 4; i++)
#pragma unroll
            for (int j = 0; j < 4; j++) {
                acc[i][j] = __builtin_amdgcn_mfma_f32_16x16x32_bf16(ah[i], bh[j], acc[i][j], 0, 0, 0);
                acc[i][j] = __builtin_amdgcn_mfma_f32_16x16x32_bf16(ah[i], bl[j], acc[i][j], 0, 0, 0);
                acc[i][j] = __builtin_amdgcn_mfma_f32_16x16x32_bf16(al[i], bh[j], acc[i][j], 0, 0, 0);
            }
    }

    // C/D layout: col=lane&15, row=quad*4+reg  [m89]
#pragma unroll
    for (int i = 0; i < 4; i++)
#pragma unroll
        for (int j = 0; j < 4; j++) {
            const int gc = col0 + wn + j * 16 + lane15;
            const int rb = row0 + wm + i * 16 + quad * 4;
            const float sv = scoresq[gc];
#pragma unroll
            for (int r = 0; r < 4; r++) {
                const size_t o = (size_t)(rb + r) * N + gc;
                Sf[o] = sv - 2.f * acc[i][j][r];
            }
        }
}

// ---------------------------------------------------------------------------
// Split-plane GEMM, 128M x 64N tile, BK=64 (two 32-k sub-tiles per barrier).
// A sub stride 4096, B sub stride 2048. 48 KB LDS.
// ---------------------------------------------------------------------------
__global__ __launch_bounds__(256) void gemm_ss_n64(
    const ushort* __restrict__ Ah_g, const ushort* __restrict__ Al_g,
    const ushort* __restrict__ Bh_g, const ushort* __restrict__ Bl_g,
    const float* __restrict__ bias,
    const ushort* __restrict__ resh, const ushort* __restrict__ resl,
    ushort* __restrict__ Ch, ushort* __restrict__ Cl,
    int M, int N, int K, int relu)
{
    __shared__ ushort Ah[128 * 64], Al[128 * 64];
    __shared__ ushort Bh[64 * 64], Bl[64 * 64];
    const int tid = threadIdx.x;
    const int lane = tid & 63, wid = tid >> 6;
    const int wm = wid * 32;
    const int lane15 = lane & 15, quad = lane >> 4;
    const int row0 = blockIdx.y * 128, col0 = blockIdx.x * 64;

    const int srow = tid >> 2;
    const int scl  = tid & 3;
    const int cp   = (scl - (srow >> 1)) & 3;
    const size_t ga0 = (size_t)(row0 + srow) * K + cp * 8;
    const size_t ga1 = (size_t)(row0 + 64 + srow) * K + cp * 8;
    const size_t gb  = (size_t)(col0 + srow) * K + cp * 8;
    const int l0 = tid * 8;
    const int l1 = 2048 + tid * 8;

    floatx4 acc[2][4];
#pragma unroll
    for (int i = 0; i < 2; i++)
#pragma unroll
        for (int j = 0; j < 4; j++) acc[i][j] = (floatx4){0.f, 0.f, 0.f, 0.f};

    for (int k0 = 0; k0 < K; k0 += 64) {
        __syncthreads();
        gload16(Ah_g + ga0 + k0,      Ah + l0);
        gload16(Ah_g + ga1 + k0,      Ah + l1);
        gload16(Ah_g + ga0 + k0 + 32, Ah + 4096 + l0);
        gload16(Ah_g + ga1 + k0 + 32, Ah + 4096 + l1);
        gload16(Al_g + ga0 + k0,      Al + l0);
        gload16(Al_g + ga1 + k0,      Al + l1);
        gload16(Al_g + ga0 + k0 + 32, Al + 4096 + l0);
        gload16(Al_g + ga1 + k0 + 32, Al + 4096 + l1);
        gload16(Bh_g + gb + k0,       Bh + l0);
        gload16(Bh_g + gb + k0 + 32,  Bh + 2048 + l0);
        gload16(Bl_g + gb + k0,       Bl + l0);
        gload16(Bl_g + gb + k0 + 32,  Bl + 2048 + l0);
        __syncthreads();

#pragma unroll
        for (int kk = 0; kk < 2; kk++) {
            const int ao = kk * 4096, bo = kk * 2048;
            short8 ah[2], al[2], bh[4], bl[4];
#pragma unroll
            for (int t = 0; t < 2; t++) {
                const int am = wm + t * 16 + lane15;
                ah[t] = *(const short8*)(Ah + ao + lds_off(am, quad));
                al[t] = *(const short8*)(Al + ao + lds_off(am, quad));
            }
#pragma unroll
            for (int j = 0; j < 4; j++) {
                const int bn = j * 16 + lane15;
                bh[j] = *(const short8*)(Bh + bo + lds_off(bn, quad));
                bl[j] = *(const short8*)(Bl + bo + lds_off(bn, quad));
            }
#pragma unroll
            for (int i = 0; i < 2; i++)
#pragma unroll
                for (int j = 0; j < 4; j++) {
                    acc[i][j] = __builtin_amdgcn_mfma_f32_16x16x32_bf16(ah[i], bh[j], acc[i][j], 0, 0, 0);
                    acc[i][j] = __builtin_amdgcn_mfma_f32_16x16x32_bf16(ah[i], bl[j], acc[i][j], 0, 0, 0);
                    acc[i][j] = __builtin_amdgcn_mfma_f32_16x16x32_bf16(al[i], bh[j], acc[i][j], 0, 0, 0);
                }
        }
    }

#pragma unroll
    for (int i = 0; i < 2; i++)
#pragma unroll
        for (int j = 0; j < 4; j++) {
            const int gc = col0 + j * 16 + lane15;
            const int rb = row0 + wm + i * 16 + quad * 4;
            const float bv = bias ? bias[gc] : 0.f;
#pragma unroll
            for (int r = 0; r < 4; r++) {
                const size_t o = (size_t)(rb + r) * N + gc;
                float v = acc[i][j][r] + bv;
                if (resh) v += bf2f(resh[o]) + bf2f(resl[o]);
                if (relu) v = fmaxf(v, 0.f);
                ushort h = f2bf(v);
                Ch[o] = h;
                Cl[o] = f2bf(v - bf2f(h));
            }
        }
}

// ---------------------------------------------------------------------------
// Small-M split-plane GEMM: 64x64 tile, BK=64. Flexible epilogue. 32 KB LDS.
// ---------------------------------------------------------------------------
__global__ __launch_bounds__(256) void gemm_ss_small(
    const ushort* __restrict__ Ah_g, const ushort* __restrict__ Al_g,
    const ushort* __restrict__ Bh_g, const ushort* __restrict__ Bl_g,
    const float* __restrict__ bias,
    const ushort* __restrict__ resh, const ushort* __restrict__ resl,
    const float* __restrict__ resf,
    ushort* __restrict__ Ch, ushort* __restrict__ Cl,
    float* __restrict__ outf,
    int M, int N, int K, int relu)
{
    __shared__ ushort Ah[64 * 64], Al[64 * 64];
    __shared__ ushort Bh[64 * 64], Bl[64 * 64];
    const int tid = threadIdx.x;
    const int lane = tid & 63, wid = tid >> 6;
    const int wm = (wid & 1) * 32, wn = (wid >> 1) * 32;
    const int lane15 = lane & 15, quad = lane >> 4;
    const int row0 = blockIdx.y * 64, col0 = blockIdx.x * 64;

    const int srow = tid >> 2;          // 0..63
    const int scl  = tid & 3;
    const int cp   = (scl - (srow >> 1)) & 3;
    const size_t ga = (size_t)(row0 + srow) * K + cp * 8;
    const size_t gb = (size_t)(col0 + srow) * K + cp * 8;
    const int l = tid * 8;

    floatx4 acc[2][2];
#pragma unroll
    for (int i = 0; i < 2; i++)
#pragma unroll
        for (int j = 0; j < 2; j++) acc[i][j] = (floatx4){0.f, 0.f, 0.f, 0.f};

    for (int k0 = 0; k0 < K; k0 += 64) {
        __syncthreads();
        gload16(Ah_g + ga + k0,      Ah + l);
        gload16(Ah_g + ga + k0 + 32, Ah + 2048 + l);
        gload16(Al_g + ga + k0,      Al + l);
        gload16(Al_g + ga + k0 + 32, Al + 2048 + l);
        gload16(Bh_g + gb + k0,      Bh + l);
        gload16(Bh_g + gb + k0 + 32, Bh + 2048 + l);
        gload16(Bl_g + gb + k0,      Bl + l);
        gload16(Bl_g + gb + k0 + 32, Bl + 2048 + l);
        __syncthreads();

#pragma unroll
        for (int kk = 0; kk < 2; kk++) {
            const int so = kk * 2048;
            short8 ah[2], al[2], bh[2], bl[2];
#pragma unroll
            for (int t = 0; t < 2; t++) {
                const int am = wm + t * 16 + lane15;
                const int bn = wn + t * 16 + lane15;
                ah[t] = *(const short8*)(Ah + so + lds_off(am, quad));
                al[t] = *(const short8*)(Al + so + lds_off(am, quad));
                bh[t] = *(const short8*)(Bh + so + lds_off(bn, quad));
                bl[t] = *(const short8*)(Bl + so + lds_off(bn, quad));
            }
#pragma unroll
            for (int i = 0; i < 2; i++)
#pragma unroll
                for (int j = 0; j < 2; j++) {
                    acc[i][j] = __builtin_amdgcn_mfma_f32_16x16x32_bf16(ah[i], bh[j], acc[i][j], 0, 0, 0);
                    acc[i][j] = __builtin_amdgcn_mfma_f32_16x16x32_bf16(ah[i], bl[j], acc[i][j], 0, 0, 0);
                    acc[i][j] = __builtin_amdgcn_mfma_f32_16x16x32_bf16(al[i], bh[j], acc[i][j], 0, 0, 0);
                }
        }
    }

#pragma unroll
    for (int i = 0; i < 2; i++)
#pragma unroll
        for (int j = 0; j < 2; j++) {
            const int gc = col0 + wn + j * 16 + lane15;
            const int rb = row0 + wm + i * 16 + quad * 4;
            const float bv = bias ? bias[gc] : 0.f;
#pragma unroll
            for (int r = 0; r < 4; r++) {
                const size_t o = (size_t)(rb + r) * N + gc;
                float v = acc[i][j][r] + bv;
                if (resh) v += bf2f(resh[o]) + bf2f(resl[o]);
                if (resf) v += resf[o];
                if (relu) v = fmaxf(v, 0.f);
                if (outf) outf[o] = v;
                if (Ch) {
                    ushort h = f2bf(v);
                    Ch[o] = h;
                    Cl[o] = f2bf(v - bf2f(h));
                }
            }
        }
}

// ---------------------------------------------------------------------------
// Values MLP layer 1: A row r = (kx planes)[r/96,:] - ck[idx[r],:](planes)
// B = t1 hi plane (global_load_lds). TT = bf16(relu(A @ B^T + bias))
// ---------------------------------------------------------------------------
__global__ __launch_bounds__(256) void gemm_diff_bf16(
    const ushort* __restrict__ kxh_g, const ushort* __restrict__ kxl_g,
    const ushort* __restrict__ ckh, const ushort* __restrict__ ckl,
    const int* __restrict__ idx, const ushort* __restrict__ BTh,
    const float* __restrict__ bias, ushort* __restrict__ TT,
    int M, int N, int K)
{
    __shared__ ushort Ah[128 * 32];
    __shared__ ushort Bh[128 * 32];
    const int tid = threadIdx.x;
    const int lane = tid & 63, wid = tid >> 6;
    const int wm = (wid & 1) * 64, wn = (wid >> 1) * 64;
    const int lane15 = lane & 15, quad = lane >> 4;
    const int row0 = blockIdx.y * 128, col0 = blockIdx.x * 128;
    const int sm = tid >> 1, scp = (tid & 1) * 2;

    const int r = row0 + sm;
    const int bidx = r / NC;
    const ushort* kxph = kxh_g + (size_t)bidx * ND + scp * 8;
    const ushort* kxpl = kxl_g + (size_t)bidx * ND + scp * 8;
    const ushort* chp  = ckh + (size_t)idx[r] * ND + scp * 8;
    const ushort* clp  = ckl + (size_t)idx[r] * ND + scp * 8;

    const int srow = tid >> 2;
    const int scl  = tid & 3;
    const int cp   = (scl - (srow >> 1)) & 3;
    const size_t gb0 = (size_t)(col0 + srow) * K + cp * 8;
    const size_t gb1 = (size_t)(col0 + 64 + srow) * K + cp * 8;
    const int l0 = tid * 8, l1 = 2048 + tid * 8;

    floatx4 acc[4][4];
#pragma unroll
    for (int i = 0; i < 4; i++)
#pragma unroll
        for (int j = 0; j < 4; j++) acc[i][j] = (floatx4){0.f, 0.f, 0.f, 0.f};

    for (int k0 = 0; k0 < K; k0 += 32) {
        short8 xh0 = *(const short8*)(kxph + k0);
        short8 xh1 = *(const short8*)(kxph + k0 + 8);
        short8 xl0 = *(const short8*)(kxpl + k0);
        short8 xl1 = *(const short8*)(kxpl + k0 + 8);
        short8 h0 = *(const short8*)(chp + k0);
        short8 h1 = *(const short8*)(chp + k0 + 8);
        short8 lo0 = *(const short8*)(clp + k0);
        short8 lo1 = *(const short8*)(clp + k0 + 8);
        short8 d0, d1;
#pragma unroll
        for (int i = 0; i < 8; i++) {
            float a0 = bf2f((ushort)xh0[i]) + bf2f((ushort)xl0[i]);
            float a1 = bf2f((ushort)xh1[i]) + bf2f((ushort)xl1[i]);
            float c0 = bf2f((ushort)h0[i]) + bf2f((ushort)lo0[i]);
            float c1 = bf2f((ushort)h1[i]) + bf2f((ushort)lo1[i]);
            d0[i] = (short)f2bf(a0 - c0);
            d1[i] = (short)f2bf(a1 - c1);
        }
        __syncthreads();
        gload16(BTh + gb0 + k0, Bh + l0);
        gload16(BTh + gb1 + k0, Bh + l1);
        *(short8*)(Ah + lds_off(sm, scp))     = d0;
        *(short8*)(Ah + lds_off(sm, scp + 1)) = d1;
        __syncthreads();

        short8 ah[4], bh[4];
#pragma unroll
        for (int t = 0; t < 4; t++) {
            ah[t] = *(const short8*)(Ah + lds_off(wm + t * 16 + lane15, quad));
            bh[t] = *(const short8*)(Bh + lds_off(wn + t * 16 + lane15, quad));
        }
#pragma unroll
        for (int i = 0; i < 4; i++)
#pragma unroll
            for (int j = 0; j < 4; j++)
                acc[i][j] = __builtin_amdgcn_mfma_f32_16x16x32_bf16(ah[i], bh[j], acc[i][j], 0, 0, 0);
    }

#pragma unroll
    for (int i = 0; i < 4; i++)
#pragma unroll
        for (int j = 0; j < 4; j++) {
            const int gc = col0 + wn + j * 16 + lane15;
            const int rb = row0 + wm + i * 16 + quad * 4;
            const float bv = bias[gc];
#pragma unroll
            for (int rr = 0; rr < 4; rr++) {
                const size_t o = (size_t)(rb + rr) * N + gc;
                TT[o] = f2bf(fmaxf(acc[i][j][rr] + bv, 0.f));
            }
        }
}

// ---------------------------------------------------------------------------
// Values MLP layer 2: A bf16 [M][K], B hi plane [N][K]: C(f32) = A @ B^T
// 128M x 64N tile, BK=64. 24 KB LDS.
// ---------------------------------------------------------------------------
__global__ __launch_bounds__(256) void gemm_bf16_n64(
    const ushort* __restrict__ A, const ushort* __restrict__ BTh,
    float* __restrict__ C, int M, int N, int K)
{
    __shared__ ushort Ah[128 * 64];
    __shared__ ushort Bh[64 * 64];
    const int tid = threadIdx.x;
    const int lane = tid & 63, wid = tid >> 6;
    const int wm = wid * 32;
    const int lane15 = lane & 15, quad = lane >> 4;
    const int row0 = blockIdx.y * 128, col0 = blockIdx.x * 64;

    const int srow = tid >> 2;
    const int scl  = tid & 3;
    const int cp   = (scl - (srow >> 1)) & 3;
    const size_t ga0 = (size_t)(row0 + srow) * K + cp * 8;
    const size_t ga1 = (size_t)(row0 + 64 + srow) * K + cp * 8;
    const size_t gb  = (size_t)(col0 + srow) * K + cp * 8;
    const int l0 = tid * 8, l1 = 2048 + tid * 8;

    floatx4 acc[2][4];
#pragma unroll
    for (int i = 0; i < 2; i++)
#pragma unroll
        for (int j = 0; j < 4; j++) acc[i][j] = (floatx4){0.f, 0.f, 0.f, 0.f};

    for (int k0 = 0; k0 < K; k0 += 64) {
        __syncthreads();
        gload16(A + ga0 + k0,      Ah + l0);
        gload16(A + ga1 + k0,      Ah + l1);
        gload16(A + ga0 + k0 + 32, Ah + 4096 + l0);
        gload16(A + ga1 + k0 + 32, Ah + 4096 + l1);
        gload16(BTh + gb + k0,      Bh + l0);
        gload16(BTh + gb + k0 + 32, Bh + 2048 + l0);
        __syncthreads();

#pragma unroll
        for (int kk = 0; kk < 2; kk++) {
            const int ao = kk * 4096, bo = kk * 2048;
            short8 ah[2], bh[4];
#pragma unroll
            for (int t = 0; t < 2; t++)
                ah[t] = *(const short8*)(Ah + ao + lds_off(wm + t * 16 + lane15, quad));
#pragma unroll
            for (int j = 0; j < 4; j++)
                bh[j] = *(const short8*)(Bh + bo + lds_off(j * 16 + lane15, quad));
#pragma unroll
            for (int i = 0; i < 2; i++)
#pragma unroll
                for (int j = 0; j < 4; j++)
                    acc[i][j] = __builtin_amdgcn_mfma_f32_16x16x32_bf16(ah[i], bh[j], acc[i][j], 0, 0, 0);
        }
    }

#pragma unroll
    for (int i = 0; i < 2; i++)
#pragma unroll
        for (int j = 0; j < 4; j++) {
            const int gc = col0 + j * 16 + lane15;
            const int rb = row0 + wm + i * 16 + quad * 4;
#pragma unroll
            for (int rr = 0; rr < 4; rr++)
                C[(size_t)(rb + rr) * N + gc] = acc[i][j][rr];
        }
}

// ---------------------------------------------------------------------------
// Prep kernels
// ---------------------------------------------------------------------------
__global__ __launch_bounds__(256) void split_wt_kernel(
    const float* __restrict__ W, ushort* __restrict__ WTh,
    ushort* __restrict__ WTl, int K, int N)
{
    const int o = blockIdx.x * 256 + threadIdx.x;
    if (o < K * N) {
        const int n = o / K, k = o - n * K;
        const float x = W[(size_t)k * N + n];
        const ushort h = f2bf(x);
        WTh[o] = h;
        WTl[o] = f2bf(x - bf2f(h));
    }
}

__global__ __launch_bounds__(256) void split_pl_kernel(
    const float* __restrict__ X, ushort* __restrict__ Xh,
    ushort* __restrict__ Xl, int n)
{
    const int i = blockIdx.x * 256 + threadIdx.x;
    if (i < n) {
        const float x = X[i];
        const ushort h = f2bf(x);
        Xh[i] = h;
        Xl[i] = f2bf(x - bf2f(h));
    }
}

// ---------------------------------------------------------------------------
// LayerNorm rows of 512, f32 in / f32 out
// ---------------------------------------------------------------------------
__global__ __launch_bounds__(256) void ln_kernel(
    const float* __restrict__ X, const float* __restrict__ g,
    const float* __restrict__ b, float* __restrict__ Y, int relu)
{
    const int lane = threadIdx.x & 63;
    const int row  = blockIdx.x * 4 + (threadIdx.x >> 6);
    const float* x = X + (size_t)row * ND;
    const int d = lane * 8;

    float4 v0 = *(const float4*)(x + d);
    float4 v1 = *(const float4*)(x + d + 4);
    float s = v0.x + v0.y + v0.z + v0.w + v1.x + v1.y + v1.z + v1.w;
    float q = v0.x*v0.x + v0.y*v0.y + v0.z*v0.z + v0.w*v0.w
            + v1.x*v1.x + v1.y*v1.y + v1.z*v1.z + v1.w*v1.w;
#pragma unroll
    for (int off = 32; off; off >>= 1) {
        s += __shfl_down(s, off);
        q += __shfl_down(q, off);
    }
    s = __shfl(s, 0); q = __shfl(q, 0);
    const float mean = s * (1.f / ND);
    const float var  = q * (1.f / ND) - mean * mean;
    const float rs   = rsqrtf(var + 1e-5f);

    float4 g0 = *(const float4*)(g + d);
    float4 g1 = *(const float4*)(g + d + 4);
    float4 b0 = *(const float4*)(b + d);
    float4 b1 = *(const float4*)(b + d + 4);
    float4 o0, o1;
    o0.x = (v0.x - mean) * rs * g0.x + b0.x;
    o0.y = (v0.y - mean) * rs * g0.y + b0.y;
    o0.z = (v0.z - mean) * rs * g0.z + b0.z;
    o0.w = (v0.w - mean) * rs * g0.w + b0.w;
    o1.x = (v1.x - mean) * rs * g1.x + b1.x;
    o1.y = (v1.y - mean) * rs * g1.y + b1.y;
    o1.z = (v1.z - mean) * rs * g1.z + b1.z;
    o1.w = (v1.w - mean) * rs * g1.w + b1.w;
    if (relu) {
        o0.x = fmaxf(o0.x, 0.f); o0.y = fmaxf(o0.y, 0.f);
        o0.z = fmaxf(o0.z, 0.f); o0.w = fmaxf(o0.w, 0.f);
        o1.x = fmaxf(o1.x, 0.f); o1.y = fmaxf(o1.y, 0.f);
        o1.w = fmaxf(o1.w, 0.f); o1.z = fmaxf(o1.z, 0.f);
    }
    float* y = Y + (size_t)row * ND;
    *(float4*)(y + d)     = o0;
    *(float4*)(y + d + 4) = o1;
}

// LayerNorm rows of 512, planes in / planes out
__global__ __launch_bounds__(256) void ln_pl_kernel(
    const ushort* __restrict__ Xh, const ushort* __restrict__ Xl,
    const float* __restrict__ g, const float* __restrict__ b,
    ushort* __restrict__ Yh, ushort* __restrict__ Yl)
{
    const int lane = threadIdx.x & 63;
    const int row  = blockIdx.x * 4 + (threadIdx.x >> 6);
    const int d = lane * 8;
    const size_t base = (size_t)row * ND + d;

    short8 xh = *(const short8*)(Xh + base);
    short8 xl = *(const short8*)(Xl + base);
    float v[8];
#pragma unroll
    for (int i = 0; i < 8; i++) v[i] = bf2f((ushort)xh[i]) + bf2f((ushort)xl[i]);

    float s = 0.f, q = 0.f;
#pragma unroll
    for (int i = 0; i < 8; i++) { s += v[i]; q += v[i] * v[i]; }
#pragma unroll
    for (int off = 32; off; off >>= 1) {
        s += __shfl_down(s, off);
        q += __shfl_down(q, off);
    }
    s = __shfl(s, 0); q = __shfl(q, 0);
    const float mean = s * (1.f / ND);
    const float var  = q * (1.f / ND) - mean * mean;
    const float rs   = rsqrtf(var + 1e-5f);

    short8 yh, yl;
#pragma unroll
    for (int i = 0; i < 8; i++) {
        const float o = (v[i] - mean) * rs * g[d + i] + b[d + i];
        const ushort h = f2bf(o);
        yh[i] = (short)h;
        yl[i] = (short)f2bf(o - bf2f(h));
    }
    *(short8*)(Yh + base) = yh;
    *(short8*)(Yl + base) = yl;
}

__global__ __launch_bounds__(256) void sqnorm_pl_kernel(
    const ushort* __restrict__ Xh, const ushort* __restrict__ Xl,
    float* __restrict__ sq)
{
    const int lane = threadIdx.x & 63;
    const int row  = blockIdx.x * 4 + (threadIdx.x >> 6);
    const size_t base = (size_t)row * ND + lane * 8;
    short8 xh = *(const short8*)(Xh + base);
    short8 xl = *(const short8*)(Xl + base);
    float q = 0.f;
#pragma unroll
    for (int i = 0; i < 8; i++) {
        float v = bf2f((ushort)xh[i]) + bf2f((ushort)xl[i]);
        q += v * v;
    }
#pragma unroll
    for (int off = 32; off; off >>= 1) q += __shfl_down(q, off);
    if (lane == 0) sq[row] = q;
}

// ---------------------------------------------------------------------------
// Two-stage exact top-96: adaptive-range radix select.
// ---------------------------------------------------------------------------
__device__ __forceinline__ unsigned fkey(float f)
{
    unsigned u = __float_as_uint(f);
    return (u & 0x80000000u) ? ~u : (u | 0x80000000u);
}
__device__ __forceinline__ float inv_fkey(unsigned u)
{
    return __uint_as_float((u & 0x80000000u) ? (u & 0x7FFFFFFFu) : ~u);
}

struct SelState {
    unsigned lo;
    unsigned long long hi;   // exclusive
    int krem;
    int done;
    unsigned long long T;    // threshold
    int need;                // how many keys == T to take
};

template <int KPT>
__device__ __forceinline__ void adaptive_select(
    const unsigned (&key)[KPT], unsigned* hist, unsigned* wtot,
    SelState* st, int tid, int kwant)
{
    const int lane = tid & 63, wid = tid >> 6;

    unsigned mn = 0xFFFFFFFFu, mx = 0u;
#pragma unroll
    for (int j = 0; j < KPT; j++) {
        mn = min(mn, key[j]);
        mx = max(mx, key[j]);
    }
#pragma unroll
    for (int off = 32; off; off >>= 1) {
        mn = min(mn, (unsigned)__shfl_down((int)mn, off));
        mx = max(mx, (unsigned)__shfl_down((int)mx, off));
    }
    if (lane == 0) { hist[wid] = mn; hist[8 + wid] = mx; }
    if (tid == 0) st->done = 0;
    __syncthreads();
    if (tid == 0) {
        unsigned gmn = min(min(hist[0], hist[1]), min(hist[2], hist[3]));
        unsigned gmx = max(max(hist[8], hist[9]), max(hist[10], hist[11]));
        st->lo = gmn;
        st->hi = (unsigned long long)gmx + 1ull;
        st->krem = kwant;
    }
    __syncthreads();

    for (int iter = 0; iter < 6 && !st->done; iter++) {
        const unsigned lo = st->lo;
        const unsigned long long hi = st->hi;
        const int krem = st->krem;
        const unsigned long long span = hi - lo;
        int shift = 0;
        if (span > 256ull) {
            const int nb = 64 - __builtin_clzll(span - 1ull);
            shift = nb - 8;
        }
        hist[tid] = 0u;
        __syncthreads();
#pragma unroll
        for (int j = 0; j < KPT; j++) {
            const unsigned u = key[j];
            if (u >= lo && (unsigned long long)u < hi)
                atomicAdd(&hist[(u - lo) >> shift], 1u);
        }
        __syncthreads();
        const unsigned c = hist[tid];
        unsigned v = c;
#pragma unroll
        for (int off = 1; off < 64; off <<= 1) {
            const unsigned t = (unsigned)__shfl_up((int)v, off);
            if (lane >= off) v += t;
        }
        if (lane == 63) wtot[wid] = v;
        __syncthreads();
        unsigned pre = 0;
        for (int w = 0; w < 3; w++) pre += (w < wid) ? wtot[w] : 0u;
        const int incl = (int)(v + pre);
        const int excl = incl - (int)c;
        if (excl < krem && incl >= krem) {
            const unsigned long long binlo =
                (unsigned long long)lo + ((unsigned long long)tid << shift);
            if (shift == 0) {
                st->T = binlo;
                st->need = krem - excl;
                st->done = 1;
            } else if (incl == krem) {
                st->T = binlo + (1ull << shift);
                st->need = 0;
                st->done = 1;
            } else {
                st->lo = (unsigned)binlo;
                const unsigned long long nhi = binlo + (1ull << shift);
                st->hi = nhi < hi ? nhi : hi;
                st->krem = krem - excl;
            }
        }
        __syncthreads();
    }
}

__global__ __launch_bounds__(256) void topk_seg(
    const float* __restrict__ S, unsigned* __restrict__ K1key,
    int* __restrict__ K1idx)
{
    const int r = blockIdx.y, seg = blockIdx.x;
    const float* p = S + (size_t)r * NN + seg * TK_SEG;
    __shared__ unsigned hist[256];
    __shared__ unsigned wtot[4];
    __shared__ SelState st;
    __shared__ int cA, cB;
    const int tid = threadIdx.x;

    unsigned key[16];
#pragma unroll
    for (int j = 0; j < 16; j++) key[j] = fkey(p[tid + j * 256]);

    if (tid == 0) { cA = 0; cB = 0; }
    adaptive_select<16>(key, hist, wtot, &st, tid, NC);

    const unsigned long long T = st.T;
    const int need = st.need;
    const int cntLess = NC - need;
    const size_t obase = ((size_t)r * TK_SPLIT + seg) * NC;
#pragma unroll
    for (int j = 0; j < 16; j++) {
        const unsigned u = key[j];
        if ((unsigned long long)u < T) {
            const int pos = atomicAdd(&cA, 1);
            K1key[obase + pos] = u;
            K1idx[obase + pos] = seg * TK_SEG + tid + j * 256;
        } else if ((unsigned long long)u == T) {
            const int pos = atomicAdd(&cB, 1);
            if (pos < need) {
                K1key[obase + cntLess + pos] = u;
                K1idx[obase + cntLess + pos] = seg * TK_SEG + tid + j * 256;
            }
        }
    }
}

__global__ __launch_bounds__(256) void topk_merge(
    const unsigned* __restrict__ K1key, const int* __restrict__ K1idx,
    int* __restrict__ idx_out, float* __restrict__ val_out, int b0)
{
    const int r = blockIdx.x;
    const int b = b0 + r;
    __shared__ unsigned hist[256];
    __shared__ unsigned wtot[4];
    __shared__ SelState st;
    __shared__ int cA, cB;
    const int tid = threadIdx.x;
    const size_t ibase = (size_t)r * TK_CAND;

    unsigned key[6];
    int      kidx[6];
#pragma unroll
    for (int j = 0; j < 6; j++) {
        key[j]  = K1key[ibase + tid + j * 256];
        kidx[j] = K1idx[ibase + tid + j * 256];
    }

    if (tid == 0) { cA = 0; cB = 0; }
    adaptive_select<6>(key, hist, wtot, &st, tid, NC);

    const unsigned long long T = st.T;
    const int need = st.need;
    const int cntLess = NC - need;
#pragma unroll
    for (int j = 0; j < 6; j++) {
        const unsigned u = key[j];
        if ((unsigned long long)u < T) {
            const int pos = atomicAdd(&cA, 1);
            idx_out[b * NC + pos] = kidx[j];
            val_out[b * NC + pos] = inv_fkey(u);
        } else if ((unsigned long long)u == T) {
            const int pos = atomicAdd(&cB, 1);
            if (pos < need) {
                idx_out[b * NC + cntLess + pos] = kidx[j];
                val_out[b * NC + cntLess + pos] = inv_fkey(u);
            }
        }
    }
}

// ---------------------------------------------------------------------------
__global__ __launch_bounds__(128) void probs_kernel(
    const float* __restrict__ svals, float* __restrict__ probs)
{
    const int b = blockIdx.x;
    const int tid = threadIdx.x;
    __shared__ float red[128];
    const bool valid = tid < NC;
    float s = valid ? -svals[b * NC + tid] : -3.4e38f;
    red[tid] = s;
    __syncthreads();
#pragma unroll
    for (int off = 64; off; off >>= 1) {
        if (tid < off) red[tid] = fmaxf(red[tid], red[tid + off]);
        __syncthreads();
    }
    const float m = red[0];
    __syncthreads();
    float e = valid ? expf(s - m) : 0.f;
    red[tid] = e;
    __syncthreads();
#pragma unroll
    for (int off = 64; off; off >>= 1) {
        if (tid < off) red[tid] += red[tid + off];
        __syncthreads();
    }
    const float sum = red[0];
    if (valid) probs[b * NC + tid] = e / sum;
}

// ctx: xin given as planes (encoder-out x)
__global__ __launch_bounds__(256) void ctx_kernel(
    const float* __restrict__ VAL, const float* __restrict__ probs,
    const float* __restrict__ cand_y, const int* __restrict__ idx,
    const float* __restrict__ labW, const float* __restrict__ labb,
    const ushort* __restrict__ xinh, const ushort* __restrict__ xinl,
    float* __restrict__ xout, int b0)
{
    const int b_loc = blockIdx.x;
    const int b = b0 + b_loc;
    const int tid = threadIdx.x;
    __shared__ float pv[NC];
    __shared__ float red[256];
    float py_part = 0.f;
    if (tid < NC) {
        float p = probs[b * NC + tid];
        pv[tid] = p;
        py_part = p * cand_y[idx[b * NC + tid]];
    }
    red[tid] = py_part;
    __syncthreads();
#pragma unroll
    for (int off = 128; off; off >>= 1) {
        if (tid < off) red[tid] += red[tid + off];
        __syncthreads();
    }
    const float py = red[0];

    for (int d = tid; d < ND; d += 256) {
        const float* vp = VAL + (size_t)b_loc * NC * ND + d;
        float acc = 0.f;
#pragma unroll 8
        for (int c = 0; c < NC; c++) acc += pv[c] * vp[(size_t)c * ND];
        float ctx = acc + py * labW[d] + labb[d];
        const size_t o = (size_t)b * ND + d;
        xout[o] = bf2f(xinh[o]) + bf2f(xinl[o]) + ctx;
    }
}

__global__ __launch_bounds__(64) void head_kernel(
    const float* __restrict__ X, const float* __restrict__ hW,
    const float* __restrict__ hb, float* __restrict__ out)
{
    const int b = blockIdx.x;
    const int lane = threadIdx.x;
    const float* x = X + (size_t)b * ND;
    float acc = 0.f;
#pragma unroll
    for (int j = 0; j < 8; j++) {
        int d = lane + 64 * j;
        acc += x[d] * hW[d];
    }
#pragma unroll
    for (int off = 32; off; off >>= 1) acc += __shfl_down(acc, off);
    if (lane == 0) out[b] = acc + hb[0];
}

// ---------------------------------------------------------------------------
extern "C" void kernel_launch(void* const* d_in, const int* in_sizes, int n_in,
                              void* d_out, int out_size, void* d_ws, size_t ws_size,
                              hipStream_t stream)
{
    const float* x_num    = (const float*)d_in[0];
    const float* cand_num = (const float*)d_in[1];
    const float* cand_y   = (const float*)d_in[2];
    const float* lin_W    = (const float*)d_in[3];
    const float* lin_b    = (const float*)d_in[4];
    const float* e_W1     = (const float*)d_in[5];
    const float* e_b1     = (const float*)d_in[6];
    const float* e_W2     = (const float*)d_in[7];
    const float* e_b2     = (const float*)d_in[8];
    const float* mix_g    = (const float*)d_in[9];
    const float* mix_b    = (const float*)d_in[10];
    const float* K_W      = (const float*)d_in[11];
    const float* K_b      = (const float*)d_in[12];
    const float* lab_W    = (const float*)d_in[13];
    const float* lab_b    = (const float*)d_in[14];
    const float* T_W1     = (const float*)d_in[15];
    const float* T_b1     = (const float*)d_in[16];
    const float* T_W2     = (const float*)d_in[17];
    const float* p_ln_g   = (const float*)d_in[18];
    const float* p_ln_b   = (const float*)d_in[19];
    const float* p_W1     = (const float*)d_in[20];
    const float* p_b1     = (const float*)d_in[21];
    const float* p_W2     = (const float*)d_in[22];
    const float* p_b2     = (const float*)d_in[23];
    const float* h_ln_g   = (const float*)d_in[24];
    const float* h_ln_b   = (const float*)d_in[25];
    const float* h_W      = (const float*)d_in[26];
    const float* h_b      = (const float*)d_in[27];
    float* out = (float*)d_out;
    (void)in_sizes; (void)n_in; (void)out_size; (void)ws_size;

    // ---- workspace layout (~245 MB) ----
    size_t off = 0;
    auto ralloc = [&](size_t bytes) -> void* {
        void* p = (char*)d_ws + off;
        off += (bytes + 255) & ~(size_t)255;
        return p;
    };
    auto falloc = [&](size_t n) -> float*  { return (float*)ralloc(n * 4); };
    auto ualloc = [&](size_t n) -> ushort* { return (ushort*)ralloc(n * 2); };

    // bf16 plane weights [N][K]
    ushort* WP_lin_h = ualloc((size_t)ND * NF);
    ushort* WP_lin_l = ualloc((size_t)ND * NF);
    ushort* WP_e1_h  = ualloc((size_t)NDB * ND);
    ushort* WP_e1_l  = ualloc((size_t)NDB * ND);
    ushort* WP_e2_h  = ualloc((size_t)ND * NDB);
    ushort* WP_e2_l  = ualloc((size_t)ND * NDB);
    ushort* WP_kw_h  = ualloc((size_t)ND * ND);
    ushort* WP_kw_l  = ualloc((size_t)ND * ND);
    ushort* WP_t1_h  = ualloc((size_t)NDB * ND);
    ushort* WP_t1_l  = ualloc((size_t)NDB * ND);
    ushort* WP_t2_h  = ualloc((size_t)ND * NDB);
    ushort* WP_t2_l  = ualloc((size_t)ND * NDB);
    ushort* WP_p1_h  = ualloc((size_t)NDB * ND);
    ushort* WP_p1_l  = ualloc((size_t)NDB * ND);
    ushort* WP_p2_h  = ualloc((size_t)ND * NDB);
    ushort* WP_p2_l  = ualloc((size_t)ND * NDB);

    ushort* R_CKh = ualloc((size_t)NN * ND);
    ushort* R_CKl = ualloc((size_t)NN * ND);
    float*  R_sq  = falloc(NN);

    // x-path plane activations
    ushort* XNh = ualloc((size_t)NB * NF);
    ushort* XNl = ualloc((size_t)NB * NF);
    ushort* Hxh = ualloc((size_t)NB * ND);
    ushort* Hxl = ualloc((size_t)NB * ND);
    ushort* Txh = ualloc((size_t)NB * NDB);
    ushort* Txl = ualloc((size_t)NB * NDB);
    ushort* X2h = ualloc((size_t)NB * ND);
    ushort* X2l = ualloc((size_t)NB * ND);
    ushort* Gxh = ualloc((size_t)NB * ND);
    ushort* Gxl = ualloc((size_t)NB * ND);
    ushort* Lxh = ualloc((size_t)NB * ND);
    ushort* Lxl = ualloc((size_t)NB * ND);
    ushort* Tph = ualloc((size_t)NB * NDB);
    ushort* Tpl = ualloc((size_t)NB * NDB);
    ushort* R_kxh = ualloc((size_t)NB * ND);
    ushort* R_kxl = ualloc((size_t)NB * ND);

    int*    R_idx = (int*)ralloc((size_t)NB * NC * 4);
    float*  R_ssel= falloc((size_t)NB * NC);
    float*  R_prob= falloc((size_t)NB * NC);
    float*  R_xupd= falloc((size_t)NB * ND);
    float*  R_lnx = falloc((size_t)NB * ND);
    float*  R_x2  = falloc((size_t)NB * ND);
    float*  R_lnx2= falloc((size_t)NB * ND);
    unsigned* K1key = (unsigned*)ralloc((size_t)BB_C * TK_CAND * 4);
    int*      K1idx = (int*)ralloc((size_t)BB_C * TK_CAND * 4);
    char* SCR = (char*)ralloc((size_t)70 * 1024 * 1024);

    // ---- 0. weight prep (split-transpose to planes) ----
    auto sw = [&](const float* W, ushort* WTh, ushort* WTl, int K, int N) {
        split_wt_kernel<<<dim3((K * N + 255) / 256), dim3(256), 0, stream>>>(W, WTh, WTl, K, N);
    };
    sw(lin_W, WP_lin_h, WP_lin_l, NF, ND);
    sw(e_W1,  WP_e1_h,  WP_e1_l,  ND, NDB);
    sw(e_W2,  WP_e2_h,  WP_e2_l,  NDB, ND);
    sw(K_W,   WP_kw_h,  WP_kw_l,  ND, ND);
    sw(T_W1,  WP_t1_h,  WP_t1_l,  ND, NDB);
    sw(T_W2,  WP_t2_h,  WP_t2_l,  NDB, ND);
    sw(p_W1,  WP_p1_h,  WP_p1_l,  ND, NDB);
    sw(p_W2,  WP_p2_h,  WP_p2_l,  NDB, ND);

    auto gn64 = [&](const ushort* Ah, const ushort* Al, const ushort* Bh,
                    const ushort* Bl, const float* bias, const ushort* resh,
                    const ushort* resl, ushort* Ch, ushort* Cl,
                    int M, int Nn, int K, int relu) {
        gemm_ss_n64<<<dim3(Nn / 64, M / 128), dim3(256), 0, stream>>>(
            Ah, Al, Bh, Bl, bias, resh, resl, Ch, Cl, M, Nn, K, relu);
    };
    auto gsm = [&](const ushort* Ah, const ushort* Al, const ushort* Bh,
                   const ushort* Bl, const float* bias, const ushort* resh,
                   const ushort* resl, const float* resf, ushort* Ch,
                   ushort* Cl, float* outf, int M, int Nn, int K, int relu) {
        gemm_ss_small<<<dim3(Nn / 64, M / 64), dim3(256), 0, stream>>>(
            Ah, Al, Bh, Bl, bias, resh, resl, resf, Ch, Cl, outf, M, Nn, K, relu);
    };

    // ---- 1. candidate encode (chunked; occupancy-tuned tiles, BK=64) ----
    {
        ushort* CNh = (ushort*)SCR;
        ushort* CNl = CNh + (size_t)CH_A * NF;
        ushort* Hh  = CNl + (size_t)CH_A * NF;
        ushort* Hl  = Hh  + (size_t)CH_A * ND;
        ushort* Th  = Hl  + (size_t)CH_A * ND;
        ushort* Tl  = Th  + (size_t)CH_A * NDB;
        ushort* H2h = Tl  + (size_t)CH_A * NDB;
        ushort* H2l = H2h + (size_t)CH_A * ND;
        ushort* Gh  = Th;   // overlay: T dead after e2
        ushort* Gl  = Tl;

        for (int n0 = 0; n0 < NN; n0 += CH_A) {
            split_pl_kernel<<<dim3((CH_A * NF + 255) / 256), dim3(256), 0, stream>>>(
                cand_num + (size_t)n0 * NF, CNh, CNl, CH_A * NF);
            gsm(CNh, CNl, WP_lin_h, WP_lin_l, lin_b, nullptr, nullptr, nullptr,
                Hh, Hl, nullptr, CH_A, ND, NF, 0);
            gn64(Hh, Hl, WP_e1_h, WP_e1_l, e_b1, nullptr, nullptr,
                 Th, Tl, CH_A, NDB, ND, 1);
            gsm(Th, Tl, WP_e2_h, WP_e2_l, e_b2, Hh, Hl, nullptr,
                H2h, H2l, nullptr, CH_A, ND, NDB, 0);
            ln_pl_kernel<<<dim3(CH_A / 4), dim3(256), 0, stream>>>(
                H2h, H2l, mix_g, mix_b, Gh, Gl);
            gsm(Gh, Gl, WP_kw_h, WP_kw_l, K_b, nullptr, nullptr, nullptr,
                R_CKh + (size_t)n0 * ND, R_CKl + (size_t)n0 * ND, nullptr,
                CH_A, ND, ND, 0);
            sqnorm_pl_kernel<<<dim3(CH_A / 4), dim3(256), 0, stream>>>(
                R_CKh + (size_t)n0 * ND, R_CKl + (size_t)n0 * ND, R_sq + n0);
        }
    }

    // ---- 2. x encode (plane operands, 64x64-tile small GEMM) ----
    split_pl_kernel<<<dim3((NB * NF + 255) / 256), dim3(256), 0, stream>>>(
        x_num, XNh, XNl, NB * NF);
    gsm(XNh, XNl, WP_lin_h, WP_lin_l, lin_b, nullptr, nullptr, nullptr,
        Hxh, Hxl, nullptr, NB, ND, NF, 0);
    gsm(Hxh, Hxl, WP_e1_h, WP_e1_l, e_b1, nullptr, nullptr, nullptr,
        Txh, Txl, nullptr, NB, NDB, ND, 1);
    gsm(Txh, Txl, WP_e2_h, WP_e2_l, e_b2, Hxh, Hxl, nullptr,
        X2h, X2l, nullptr, NB, ND, NDB, 0);
    ln_pl_kernel<<<dim3(NB / 4), dim3(256), 0, stream>>>(
        X2h, X2l, mix_g, mix_b, Gxh, Gxl);
    gsm(Gxh, Gxl, WP_kw_h, WP_kw_l, K_b, nullptr, nullptr, nullptr,
        R_kxh, R_kxl, nullptr, NB, ND, ND, 0);

    // ---- 3. scores (L2-swizzled grid) + two-stage top-96 + softmax ----
    for (int b0 = 0; b0 < NB; b0 += BB_C) {
        float* S = (float*)SCR;
        gemm_ss<<<dim3(BB_C / 128, NN / 128), dim3(256), 0, stream>>>(
            R_kxh + (size_t)b0 * ND, R_kxl + (size_t)b0 * ND, R_CKh, R_CKl,
            R_sq, S, BB_C, NN, ND);
        topk_seg<<<dim3(TK_SPLIT, BB_C), dim3(256), 0, stream>>>(S, K1key, K1idx);
        topk_merge<<<dim3(BB_C), dim3(256), 0, stream>>>(K1key, K1idx,
                                                         R_idx, R_ssel, b0);
    }
    probs_kernel<<<dim3(NB), dim3(128), 0, stream>>>(R_ssel, R_prob);

    // ---- 4. values path (plain bf16 MFMA, diff fused) ----
    for (int b0 = 0; b0 < NB; b0 += BB_D) {
        ushort* TT = (ushort*)SCR;                                  // [M,1024] bf16
        float* VAL = (float*)(SCR + (size_t)BB_D * NC * NDB * 2);   // f32 after TT
        const int M = BB_D * NC;   // 12288
        gemm_diff_bf16<<<dim3(NDB / 128, M / 128), dim3(256), 0, stream>>>(
            R_kxh + (size_t)b0 * ND, R_kxl + (size_t)b0 * ND,
            R_CKh, R_CKl, R_idx + b0 * NC,
            WP_t1_h, T_b1, TT, M, NDB, ND);
        gemm_bf16_n64<<<dim3(ND / 64, M / 128), dim3(256), 0, stream>>>(
            TT, WP_t2_h, VAL, M, ND, NDB);
        ctx_kernel<<<dim3(BB_D), dim3(256), 0, stream>>>(
            VAL, R_prob, cand_y, R_idx, lab_W, lab_b, X2h, X2l, R_xupd, b0);
    }

    // ---- 5. predictor block + head ----
    ln_kernel<<<dim3(NB / 4), dim3(256), 0, stream>>>(R_xupd, p_ln_g, p_ln_b, R_lnx, 0);
    split_pl_kernel<<<dim3((NB * ND + 255) / 256), dim3(256), 0, stream>>>(
        R_lnx, Lxh, Lxl, NB * ND);
    gsm(Lxh, Lxl, WP_p1_h, WP_p1_l, p_b1, nullptr, nullptr, nullptr,
        Tph, Tpl, nullptr, NB, NDB, ND, 1);
    gsm(Tph, Tpl, WP_p2_h, WP_p2_l, p_b2, nullptr, nullptr, R_xupd,
        nullptr, nullptr, R_x2, NB, ND, NDB, 0);
    ln_kernel<<<dim3(NB / 4), dim3(256), 0, stream>>>(R_x2, h_ln_g, h_ln_b, R_lnx2, 1);
    head_kernel<<<dim3(NB), dim3(64), 0, stream>>>(R_lnx2, h_W, h_b, out);
}

// Round 14
// 2628.244 us; speedup vs baseline: 1.4937x; 1.0076x over previous
//
#include <hip/hip_runtime.h>

// Problem constants
#define NB   1024
#define NN   65536
#define NF   64
#define ND   512
#define NDB  1024
#define NC   96

// Chunking
#define CH_A 8192      // candidate-encode chunk rows
#define BB_C 256       // scores/topk chunk of B rows
#define BB_D 128       // values-path chunk of B rows

// top-k segmentation
#define TK_SPLIT 16
#define TK_SEG   (NN / TK_SPLIT)   // 4096
#define TK_CAND  (TK_SPLIT * NC)   // 1536

typedef unsigned short ushort;
typedef __attribute__((ext_vector_type(8))) short short8;
typedef __attribute__((ext_vector_type(4))) float floatx4;

__device__ __forceinline__ ushort f2bf(float f) {   // RNE f32->bf16
    unsigned u = __float_as_uint(f);
    u += 0x7fffu + ((u >> 16) & 1u);
    return (ushort)(u >> 16);
}
__device__ __forceinline__ float bf2f(ushort h) {
    return __uint_as_float(((unsigned)h) << 16);
}
// LDS plane: [m][k] bf16, k-stride 32, 16B-chunk XOR swizzle -> conflict-free
__device__ __forceinline__ int lds_off(int m, int c) {
    return m * 32 + (((c + (m >> 1)) & 3) << 3);
}

// async global->LDS 16B
__device__ __forceinline__ void gload16(const ushort* g, ushort* l)
{
    void* gv = (void*)g;
    void* lv = (void*)l;
    __builtin_amdgcn_global_load_lds(
        (__attribute__((address_space(1))) void*)gv,
        (__attribute__((address_space(3))) void*)lv, 16, 0, 0);
}

// ---------------------------------------------------------------------------
// Split-plane MFMA GEMM (f32-emulating, 3 MFMA), NT, 128x128 tile.
// SCORES kernel. Grid (x=col, y=row): col-tiles sweep with fixed row-tile,
// L3 absorbs the second row-tile pass (measured r11: FETCH = 1x CK read).
// ---------------------------------------------------------------------------
__global__ __launch_bounds__(256) void gemm_ss(
    const ushort* __restrict__ Ah_g, const ushort* __restrict__ Al_g,
    const ushort* __restrict__ Bh_g, const ushort* __restrict__ Bl_g,
    const float* __restrict__ scoresq, float* __restrict__ Sf,
    int M, int N, int K)
{
    __shared__ ushort Ah[128 * 32], Al[128 * 32];
    __shared__ ushort Bh[128 * 32], Bl[128 * 32];
    const int tid = threadIdx.x;
    const int lane = tid & 63, wid = tid >> 6;
    const int wm = (wid & 1) * 64, wn = (wid >> 1) * 64;
    const int lane15 = lane & 15, quad = lane >> 4;
    const int row0 = blockIdx.y * 128, col0 = blockIdx.x * 128;

    const int srow = tid >> 2;
    const int scl  = tid & 3;
    const int cp   = (scl - (srow >> 1)) & 3;
    const size_t ga0 = (size_t)(row0 + srow) * K + cp * 8;
    const size_t ga1 = (size_t)(row0 + 64 + srow) * K + cp * 8;
    const size_t gb0 = (size_t)(col0 + srow) * K + cp * 8;
    const size_t gb1 = (size_t)(col0 + 64 + srow) * K + cp * 8;
    const int l0 = tid * 8;
    const int l1 = 2048 + tid * 8;

    floatx4 acc[4][4];
#pragma unroll
    for (int i = 0; i < 4; i++)
#pragma unroll
        for (int j = 0; j < 4; j++) acc[i][j] = (floatx4){0.f, 0.f, 0.f, 0.f};

    for (int k0 = 0; k0 < K; k0 += 32) {
        __syncthreads();
        gload16(Ah_g + ga0 + k0, Ah + l0);
        gload16(Ah_g + ga1 + k0, Ah + l1);
        gload16(Al_g + ga0 + k0, Al + l0);
        gload16(Al_g + ga1 + k0, Al + l1);
        gload16(Bh_g + gb0 + k0, Bh + l0);
        gload16(Bh_g + gb1 + k0, Bh + l1);
        gload16(Bl_g + gb0 + k0, Bl + l0);
        gload16(Bl_g + gb1 + k0, Bl + l1);
        __syncthreads();

        short8 ah[4], al[4], bh[4], bl[4];
#pragma unroll
        for (int t = 0; t < 4; t++) {
            const int am = wm + t * 16 + lane15;
            const int bn = wn + t * 16 + lane15;
            ah[t] = *(const short8*)(Ah + lds_off(am, quad));
            al[t] = *(const short8*)(Al + lds_off(am, quad));
            bh[t] = *(const short8*)(Bh + lds_off(bn, quad));
            bl[t] = *(const short8*)(Bl + lds_off(bn, quad));
        }
#pragma unroll
        for (int i = 0; i < 4; i++)
#pragma unroll
            for (int j = 0; j < 4; j++) {
                acc[i][j] = __builtin_amdgcn_mfma_f32_16x16x32_bf16(ah[i], bh[j], acc[i][j], 0, 0, 0);
                acc[i][j] = __builtin_amdgcn_mfma_f32_16x16x32_bf16(ah[i], bl[j], acc[i][j], 0, 0, 0);
                acc[i][j] = __builtin_amdgcn_mfma_f32_16x16x32_bf16(al[i], bh[j], acc[i][j], 0, 0, 0);
            }
    }

    // C/D layout: col=lane&15, row=quad*4+reg  [m89]
#pragma unroll
    for (int i = 0; i < 4; i++)
#pragma unroll
        for (int j = 0; j < 4; j++) {
            const int gc = col0 + wn + j * 16 + lane15;
            const int rb = row0 + wm + i * 16 + quad * 4;
            const float sv = scoresq[gc];
#pragma unroll
            for (int r = 0; r < 4; r++) {
                const size_t o = (size_t)(rb + r) * N + gc;
                Sf[o] = sv - 2.f * acc[i][j][r];
            }
        }
}

// ---------------------------------------------------------------------------
// Split-plane GEMM, 128M x 64N tile, BK=64. Full 3-MFMA (B-lo required:
// dropping it measured absmax 0.047 > 0.042 in r13 -- do not re-try).
// ---------------------------------------------------------------------------
__global__ __launch_bounds__(256) void gemm_ss_n64(
    const ushort* __restrict__ Ah_g, const ushort* __restrict__ Al_g,
    const ushort* __restrict__ Bh_g, const ushort* __restrict__ Bl_g,
    const float* __restrict__ bias,
    const ushort* __restrict__ resh, const ushort* __restrict__ resl,
    ushort* __restrict__ Ch, ushort* __restrict__ Cl,
    int M, int N, int K, int relu)
{
    __shared__ ushort Ah[128 * 64], Al[128 * 64];
    __shared__ ushort Bh[64 * 64], Bl[64 * 64];
    const int tid = threadIdx.x;
    const int lane = tid & 63, wid = tid >> 6;
    const int wm = wid * 32;
    const int lane15 = lane & 15, quad = lane >> 4;
    const int row0 = blockIdx.y * 128, col0 = blockIdx.x * 64;

    const int srow = tid >> 2;
    const int scl  = tid & 3;
    const int cp   = (scl - (srow >> 1)) & 3;
    const size_t ga0 = (size_t)(row0 + srow) * K + cp * 8;
    const size_t ga1 = (size_t)(row0 + 64 + srow) * K + cp * 8;
    const size_t gb  = (size_t)(col0 + srow) * K + cp * 8;
    const int l0 = tid * 8;
    const int l1 = 2048 + tid * 8;

    floatx4 acc[2][4];
#pragma unroll
    for (int i = 0; i < 2; i++)
#pragma unroll
        for (int j = 0; j < 4; j++) acc[i][j] = (floatx4){0.f, 0.f, 0.f, 0.f};

    for (int k0 = 0; k0 < K; k0 += 64) {
        __syncthreads();
        gload16(Ah_g + ga0 + k0,      Ah + l0);
        gload16(Ah_g + ga1 + k0,      Ah + l1);
        gload16(Ah_g + ga0 + k0 + 32, Ah + 4096 + l0);
        gload16(Ah_g + ga1 + k0 + 32, Ah + 4096 + l1);
        gload16(Al_g + ga0 + k0,      Al + l0);
        gload16(Al_g + ga1 + k0,      Al + l1);
        gload16(Al_g + ga0 + k0 + 32, Al + 4096 + l0);
        gload16(Al_g + ga1 + k0 + 32, Al + 4096 + l1);
        gload16(Bh_g + gb + k0,       Bh + l0);
        gload16(Bh_g + gb + k0 + 32,  Bh + 2048 + l0);
        gload16(Bl_g + gb + k0,       Bl + l0);
        gload16(Bl_g + gb + k0 + 32,  Bl + 2048 + l0);
        __syncthreads();

#pragma unroll
        for (int kk = 0; kk < 2; kk++) {
            const int ao = kk * 4096, bo = kk * 2048;
            short8 ah[2], al[2], bh[4], bl[4];
#pragma unroll
            for (int t = 0; t < 2; t++) {
                const int am = wm + t * 16 + lane15;
                ah[t] = *(const short8*)(Ah + ao + lds_off(am, quad));
                al[t] = *(const short8*)(Al + ao + lds_off(am, quad));
            }
#pragma unroll
            for (int j = 0; j < 4; j++) {
                const int bn = j * 16 + lane15;
                bh[j] = *(const short8*)(Bh + bo + lds_off(bn, quad));
                bl[j] = *(const short8*)(Bl + bo + lds_off(bn, quad));
            }
#pragma unroll
            for (int i = 0; i < 2; i++)
#pragma unroll
                for (int j = 0; j < 4; j++) {
                    acc[i][j] = __builtin_amdgcn_mfma_f32_16x16x32_bf16(ah[i], bh[j], acc[i][j], 0, 0, 0);
                    acc[i][j] = __builtin_amdgcn_mfma_f32_16x16x32_bf16(ah[i], bl[j], acc[i][j], 0, 0, 0);
                    acc[i][j] = __builtin_amdgcn_mfma_f32_16x16x32_bf16(al[i], bh[j], acc[i][j], 0, 0, 0);
                }
        }
    }

#pragma unroll
    for (int i = 0; i < 2; i++)
#pragma unroll
        for (int j = 0; j < 4; j++) {
            const int gc = col0 + j * 16 + lane15;
            const int rb = row0 + wm + i * 16 + quad * 4;
            const float bv = bias ? bias[gc] : 0.f;
#pragma unroll
            for (int r = 0; r < 4; r++) {
                const size_t o = (size_t)(rb + r) * N + gc;
                float v = acc[i][j][r] + bv;
                if (resh) v += bf2f(resh[o]) + bf2f(resl[o]);
                if (relu) v = fmaxf(v, 0.f);
                ushort h = f2bf(v);
                Ch[o] = h;
                Cl[o] = f2bf(v - bf2f(h));
            }
        }
}

// ---------------------------------------------------------------------------
// Small-M split-plane GEMM: 64x64 tile, BK=64, full 3-MFMA. Flexible epi.
// ---------------------------------------------------------------------------
__global__ __launch_bounds__(256) void gemm_ss_small(
    const ushort* __restrict__ Ah_g, const ushort* __restrict__ Al_g,
    const ushort* __restrict__ Bh_g, const ushort* __restrict__ Bl_g,
    const float* __restrict__ bias,
    const ushort* __restrict__ resh, const ushort* __restrict__ resl,
    const float* __restrict__ resf,
    ushort* __restrict__ Ch, ushort* __restrict__ Cl,
    float* __restrict__ outf,
    int M, int N, int K, int relu)
{
    __shared__ ushort Ah[64 * 64], Al[64 * 64];
    __shared__ ushort Bh[64 * 64], Bl[64 * 64];
    const int tid = threadIdx.x;
    const int lane = tid & 63, wid = tid >> 6;
    const int wm = (wid & 1) * 32, wn = (wid >> 1) * 32;
    const int lane15 = lane & 15, quad = lane >> 4;
    const int row0 = blockIdx.y * 64, col0 = blockIdx.x * 64;

    const int srow = tid >> 2;          // 0..63
    const int scl  = tid & 3;
    const int cp   = (scl - (srow >> 1)) & 3;
    const size_t ga = (size_t)(row0 + srow) * K + cp * 8;
    const size_t gb = (size_t)(col0 + srow) * K + cp * 8;
    const int l = tid * 8;

    floatx4 acc[2][2];
#pragma unroll
    for (int i = 0; i < 2; i++)
#pragma unroll
        for (int j = 0; j < 2; j++) acc[i][j] = (floatx4){0.f, 0.f, 0.f, 0.f};

    for (int k0 = 0; k0 < K; k0 += 64) {
        __syncthreads();
        gload16(Ah_g + ga + k0,      Ah + l);
        gload16(Ah_g + ga + k0 + 32, Ah + 2048 + l);
        gload16(Al_g + ga + k0,      Al + l);
        gload16(Al_g + ga + k0 + 32, Al + 2048 + l);
        gload16(Bh_g + gb + k0,      Bh + l);
        gload16(Bh_g + gb + k0 + 32, Bh + 2048 + l);
        gload16(Bl_g + gb + k0,      Bl + l);
        gload16(Bl_g + gb + k0 + 32, Bl + 2048 + l);
        __syncthreads();

#pragma unroll
        for (int kk = 0; kk < 2; kk++) {
            const int so = kk * 2048;
            short8 ah[2], al[2], bh[2], bl[2];
#pragma unroll
            for (int t = 0; t < 2; t++) {
                const int am = wm + t * 16 + lane15;
                const int bn = wn + t * 16 + lane15;
                ah[t] = *(const short8*)(Ah + so + lds_off(am, quad));
                al[t] = *(const short8*)(Al + so + lds_off(am, quad));
                bh[t] = *(const short8*)(Bh + so + lds_off(bn, quad));
                bl[t] = *(const short8*)(Bl + so + lds_off(bn, quad));
            }
#pragma unroll
            for (int i = 0; i < 2; i++)
#pragma unroll
                for (int j = 0; j < 2; j++) {
                    acc[i][j] = __builtin_amdgcn_mfma_f32_16x16x32_bf16(ah[i], bh[j], acc[i][j], 0, 0, 0);
                    acc[i][j] = __builtin_amdgcn_mfma_f32_16x16x32_bf16(ah[i], bl[j], acc[i][j], 0, 0, 0);
                    acc[i][j] = __builtin_amdgcn_mfma_f32_16x16x32_bf16(al[i], bh[j], acc[i][j], 0, 0, 0);
                }
        }
    }

#pragma unroll
    for (int i = 0; i < 2; i++)
#pragma unroll
        for (int j = 0; j < 2; j++) {
            const int gc = col0 + wn + j * 16 + lane15;
            const int rb = row0 + wm + i * 16 + quad * 4;
            const float bv = bias ? bias[gc] : 0.f;
#pragma unroll
            for (int r = 0; r < 4; r++) {
                const size_t o = (size_t)(rb + r) * N + gc;
                float v = acc[i][j][r] + bv;
                if (resh) v += bf2f(resh[o]) + bf2f(resl[o]);
                if (resf) v += resf[o];
                if (relu) v = fmaxf(v, 0.f);
                if (outf) outf[o] = v;
                if (Ch) {
                    ushort h = f2bf(v);
                    Ch[o] = h;
                    Cl[o] = f2bf(v - bf2f(h));
                }
            }
        }
}

// ---------------------------------------------------------------------------
// Values MLP layer 1: A row r = (kx planes)[r/96,:] - ck[idx[r],:](planes)
// B = t1 hi plane (global_load_lds). TT = bf16(relu(A @ B^T + bias))
// ---------------------------------------------------------------------------
__global__ __launch_bounds__(256) void gemm_diff_bf16(
    const ushort* __restrict__ kxh_g, const ushort* __restrict__ kxl_g,
    const ushort* __restrict__ ckh, const ushort* __restrict__ ckl,
    const int* __restrict__ idx, const ushort* __restrict__ BTh,
    const float* __restrict__ bias, ushort* __restrict__ TT,
    int M, int N, int K)
{
    __shared__ ushort Ah[128 * 32];
    __shared__ ushort Bh[128 * 32];
    const int tid = threadIdx.x;
    const int lane = tid & 63, wid = tid >> 6;
    const int wm = (wid & 1) * 64, wn = (wid >> 1) * 64;
    const int lane15 = lane & 15, quad = lane >> 4;
    const int row0 = blockIdx.y * 128, col0 = blockIdx.x * 128;
    const int sm = tid >> 1, scp = (tid & 1) * 2;

    const int r = row0 + sm;
    const int bidx = r / NC;
    const ushort* kxph = kxh_g + (size_t)bidx * ND + scp * 8;
    const ushort* kxpl = kxl_g + (size_t)bidx * ND + scp * 8;
    const ushort* chp  = ckh + (size_t)idx[r] * ND + scp * 8;
    const ushort* clp  = ckl + (size_t)idx[r] * ND + scp * 8;

    const int srow = tid >> 2;
    const int scl  = tid & 3;
    const int cp   = (scl - (srow >> 1)) & 3;
    const size_t gb0 = (size_t)(col0 + srow) * K + cp * 8;
    const size_t gb1 = (size_t)(col0 + 64 + srow) * K + cp * 8;
    const int l0 = tid * 8, l1 = 2048 + tid * 8;

    floatx4 acc[4][4];
#pragma unroll
    for (int i = 0; i < 4; i++)
#pragma unroll
        for (int j = 0; j < 4; j++) acc[i][j] = (floatx4){0.f, 0.f, 0.f, 0.f};

    for (int k0 = 0; k0 < K; k0 += 32) {
        short8 xh0 = *(const short8*)(kxph + k0);
        short8 xh1 = *(const short8*)(kxph + k0 + 8);
        short8 xl0 = *(const short8*)(kxpl + k0);
        short8 xl1 = *(const short8*)(kxpl + k0 + 8);
        short8 h0 = *(const short8*)(chp + k0);
        short8 h1 = *(const short8*)(chp + k0 + 8);
        short8 lo0 = *(const short8*)(clp + k0);
        short8 lo1 = *(const short8*)(clp + k0 + 8);
        short8 d0, d1;
#pragma unroll
        for (int i = 0; i < 8; i++) {
            float a0 = bf2f((ushort)xh0[i]) + bf2f((ushort)xl0[i]);
            float a1 = bf2f((ushort)xh1[i]) + bf2f((ushort)xl1[i]);
            float c0 = bf2f((ushort)h0[i]) + bf2f((ushort)lo0[i]);
            float c1 = bf2f((ushort)h1[i]) + bf2f((ushort)lo1[i]);
            d0[i] = (short)f2bf(a0 - c0);
            d1[i] = (short)f2bf(a1 - c1);
        }
        __syncthreads();
        gload16(BTh + gb0 + k0, Bh + l0);
        gload16(BTh + gb1 + k0, Bh + l1);
        *(short8*)(Ah + lds_off(sm, scp))     = d0;
        *(short8*)(Ah + lds_off(sm, scp + 1)) = d1;
        __syncthreads();

        short8 ah[4], bh[4];
#pragma unroll
        for (int t = 0; t < 4; t++) {
            ah[t] = *(const short8*)(Ah + lds_off(wm + t * 16 + lane15, quad));
            bh[t] = *(const short8*)(Bh + lds_off(wn + t * 16 + lane15, quad));
        }
#pragma unroll
        for (int i = 0; i < 4; i++)
#pragma unroll
            for (int j = 0; j < 4; j++)
                acc[i][j] = __builtin_amdgcn_mfma_f32_16x16x32_bf16(ah[i], bh[j], acc[i][j], 0, 0, 0);
    }

#pragma unroll
    for (int i = 0; i < 4; i++)
#pragma unroll
        for (int j = 0; j < 4; j++) {
            const int gc = col0 + wn + j * 16 + lane15;
            const int rb = row0 + wm + i * 16 + quad * 4;
            const float bv = bias[gc];
#pragma unroll
            for (int rr = 0; rr < 4; rr++) {
                const size_t o = (size_t)(rb + rr) * N + gc;
                TT[o] = f2bf(fmaxf(acc[i][j][rr] + bv, 0.f));
            }
        }
}

// ---------------------------------------------------------------------------
// Values MLP layer 2: A bf16 [M][K], B hi plane [N][K]: C(f32) = A @ B^T
// 128M x 64N tile, BK=64.
// ---------------------------------------------------------------------------
__global__ __launch_bounds__(256) void gemm_bf16_n64(
    const ushort* __restrict__ A, const ushort* __restrict__ BTh,
    float* __restrict__ C, int M, int N, int K)
{
    __shared__ ushort Ah[128 * 64];
    __shared__ ushort Bh[64 * 64];
    const int tid = threadIdx.x;
    const int lane = tid & 63, wid = tid >> 6;
    const int wm = wid * 32;
    const int lane15 = lane & 15, quad = lane >> 4;
    const int row0 = blockIdx.y * 128, col0 = blockIdx.x * 64;

    const int srow = tid >> 2;
    const int scl  = tid & 3;
    const int cp   = (scl - (srow >> 1)) & 3;
    const size_t ga0 = (size_t)(row0 + srow) * K + cp * 8;
    const size_t ga1 = (size_t)(row0 + 64 + srow) * K + cp * 8;
    const size_t gb  = (size_t)(col0 + srow) * K + cp * 8;
    const int l0 = tid * 8, l1 = 2048 + tid * 8;

    floatx4 acc[2][4];
#pragma unroll
    for (int i = 0; i < 2; i++)
#pragma unroll
        for (int j = 0; j < 4; j++) acc[i][j] = (floatx4){0.f, 0.f, 0.f, 0.f};

    for (int k0 = 0; k0 < K; k0 += 64) {
        __syncthreads();
        gload16(A + ga0 + k0,      Ah + l0);
        gload16(A + ga1 + k0,      Ah + l1);
        gload16(A + ga0 + k0 + 32, Ah + 4096 + l0);
        gload16(A + ga1 + k0 + 32, Ah + 4096 + l1);
        gload16(BTh + gb + k0,      Bh + l0);
        gload16(BTh + gb + k0 + 32, Bh + 2048 + l0);
        __syncthreads();

#pragma unroll
        for (int kk = 0; kk < 2; kk++) {
            const int ao = kk * 4096, bo = kk * 2048;
            short8 ah[2], bh[4];
#pragma unroll
            for (int t = 0; t < 2; t++)
                ah[t] = *(const short8*)(Ah + ao + lds_off(wm + t * 16 + lane15, quad));
#pragma unroll
            for (int j = 0; j < 4; j++)
                bh[j] = *(const short8*)(Bh + bo + lds_off(j * 16 + lane15, quad));
#pragma unroll
            for (int i = 0; i < 2; i++)
#pragma unroll
                for (int j = 0; j < 4; j++)
                    acc[i][j] = __builtin_amdgcn_mfma_f32_16x16x32_bf16(ah[i], bh[j], acc[i][j], 0, 0, 0);
        }
    }

#pragma unroll
    for (int i = 0; i < 2; i++)
#pragma unroll
        for (int j = 0; j < 4; j++) {
            const int gc = col0 + j * 16 + lane15;
            const int rb = row0 + wm + i * 16 + quad * 4;
#pragma unroll
            for (int rr = 0; rr < 4; rr++)
                C[(size_t)(rb + rr) * N + gc] = acc[i][j][rr];
        }
}

// ---------------------------------------------------------------------------
// Prep kernels
// ---------------------------------------------------------------------------
__global__ __launch_bounds__(256) void split_wt_kernel(
    const float* __restrict__ W, ushort* __restrict__ WTh,
    ushort* __restrict__ WTl, int K, int N)
{
    const int o = blockIdx.x * 256 + threadIdx.x;
    if (o < K * N) {
        const int n = o / K, k = o - n * K;
        const float x = W[(size_t)k * N + n];
        const ushort h = f2bf(x);
        WTh[o] = h;
        WTl[o] = f2bf(x - bf2f(h));
    }
}

__global__ __launch_bounds__(256) void split_pl_kernel(
    const float* __restrict__ X, ushort* __restrict__ Xh,
    ushort* __restrict__ Xl, int n)
{
    const int i = blockIdx.x * 256 + threadIdx.x;
    if (i < n) {
        const float x = X[i];
        const ushort h = f2bf(x);
        Xh[i] = h;
        Xl[i] = f2bf(x - bf2f(h));
    }
}

// ---------------------------------------------------------------------------
// LayerNorm rows of 512, f32 in / f32 out
// ---------------------------------------------------------------------------
__global__ __launch_bounds__(256) void ln_kernel(
    const float* __restrict__ X, const float* __restrict__ g,
    const float* __restrict__ b, float* __restrict__ Y, int relu)
{
    const int lane = threadIdx.x & 63;
    const int row  = blockIdx.x * 4 + (threadIdx.x >> 6);
    const float* x = X + (size_t)row * ND;
    const int d = lane * 8;

    float4 v0 = *(const float4*)(x + d);
    float4 v1 = *(const float4*)(x + d + 4);
    float s = v0.x + v0.y + v0.z + v0.w + v1.x + v1.y + v1.z + v1.w;
    float q = v0.x*v0.x + v0.y*v0.y + v0.z*v0.z + v0.w*v0.w
            + v1.x*v1.x + v1.y*v1.y + v1.z*v1.z + v1.w*v1.w;
#pragma unroll
    for (int off = 32; off; off >>= 1) {
        s += __shfl_down(s, off);
        q += __shfl_down(q, off);
    }
    s = __shfl(s, 0); q = __shfl(q, 0);
    const float mean = s * (1.f / ND);
    const float var  = q * (1.f / ND) - mean * mean;
    const float rs   = rsqrtf(var + 1e-5f);

    float4 g0 = *(const float4*)(g + d);
    float4 g1 = *(const float4*)(g + d + 4);
    float4 b0 = *(const float4*)(b + d);
    float4 b1 = *(const float4*)(b + d + 4);
    float4 o0, o1;
    o0.x = (v0.x - mean) * rs * g0.x + b0.x;
    o0.y = (v0.y - mean) * rs * g0.y + b0.y;
    o0.z = (v0.z - mean) * rs * g0.z + b0.z;
    o0.w = (v0.w - mean) * rs * g0.w + b0.w;
    o1.x = (v1.x - mean) * rs * g1.x + b1.x;
    o1.y = (v1.y - mean) * rs * g1.y + b1.y;
    o1.z = (v1.z - mean) * rs * g1.z + b1.z;
    o1.w = (v1.w - mean) * rs * g1.w + b1.w;
    if (relu) {
        o0.x = fmaxf(o0.x, 0.f); o0.y = fmaxf(o0.y, 0.f);
        o0.z = fmaxf(o0.z, 0.f); o0.w = fmaxf(o0.w, 0.f);
        o1.x = fmaxf(o1.x, 0.f); o1.y = fmaxf(o1.y, 0.f);
        o1.z = fmaxf(o1.z, 0.f); o1.w = fmaxf(o1.w, 0.f);
    }
    float* y = Y + (size_t)row * ND;
    *(float4*)(y + d)     = o0;
    *(float4*)(y + d + 4) = o1;
}

// LayerNorm rows of 512, planes in / planes out
__global__ __launch_bounds__(256) void ln_pl_kernel(
    const ushort* __restrict__ Xh, const ushort* __restrict__ Xl,
    const float* __restrict__ g, const float* __restrict__ b,
    ushort* __restrict__ Yh, ushort* __restrict__ Yl)
{
    const int lane = threadIdx.x & 63;
    const int row  = blockIdx.x * 4 + (threadIdx.x >> 6);
    const int d = lane * 8;
    const size_t base = (size_t)row * ND + d;

    short8 xh = *(const short8*)(Xh + base);
    short8 xl = *(const short8*)(Xl + base);
    float v[8];
#pragma unroll
    for (int i = 0; i < 8; i++) v[i] = bf2f((ushort)xh[i]) + bf2f((ushort)xl[i]);

    float s = 0.f, q = 0.f;
#pragma unroll
    for (int i = 0; i < 8; i++) { s += v[i]; q += v[i] * v[i]; }
#pragma unroll
    for (int off = 32; off; off >>= 1) {
        s += __shfl_down(s, off);
        q += __shfl_down(q, off);
    }
    s = __shfl(s, 0); q = __shfl(q, 0);
    const float mean = s * (1.f / ND);
    const float var  = q * (1.f / ND) - mean * mean;
    const float rs   = rsqrtf(var + 1e-5f);

    short8 yh, yl;
#pragma unroll
    for (int i = 0; i < 8; i++) {
        const float o = (v[i] - mean) * rs * g[d + i] + b[d + i];
        const ushort h = f2bf(o);
        yh[i] = (short)h;
        yl[i] = (short)f2bf(o - bf2f(h));
    }
    *(short8*)(Yh + base) = yh;
    *(short8*)(Yl + base) = yl;
}

__global__ __launch_bounds__(256) void sqnorm_pl_kernel(
    const ushort* __restrict__ Xh, const ushort* __restrict__ Xl,
    float* __restrict__ sq)
{
    const int lane = threadIdx.x & 63;
    const int row  = blockIdx.x * 4 + (threadIdx.x >> 6);
    const size_t base = (size_t)row * ND + lane * 8;
    short8 xh = *(const short8*)(Xh + base);
    short8 xl = *(const short8*)(Xl + base);
    float q = 0.f;
#pragma unroll
    for (int i = 0; i < 8; i++) {
        float v = bf2f((ushort)xh[i]) + bf2f((ushort)xl[i]);
        q += v * v;
    }
#pragma unroll
    for (int off = 32; off; off >>= 1) q += __shfl_down(q, off);
    if (lane == 0) sq[row] = q;
}

// ---------------------------------------------------------------------------
// Two-stage exact top-96: adaptive-range radix select.
// ---------------------------------------------------------------------------
__device__ __forceinline__ unsigned fkey(float f)
{
    unsigned u = __float_as_uint(f);
    return (u & 0x80000000u) ? ~u : (u | 0x80000000u);
}
__device__ __forceinline__ float inv_fkey(unsigned u)
{
    return __uint_as_float((u & 0x80000000u) ? (u & 0x7FFFFFFFu) : ~u);
}

struct SelState {
    unsigned lo;
    unsigned long long hi;   // exclusive
    int krem;
    int done;
    unsigned long long T;    // threshold
    int need;                // how many keys == T to take
};

template <int KPT>
__device__ __forceinline__ void adaptive_select(
    const unsigned (&key)[KPT], unsigned* hist, unsigned* wtot,
    SelState* st, int tid, int kwant)
{
    const int lane = tid & 63, wid = tid >> 6;

    unsigned mn = 0xFFFFFFFFu, mx = 0u;
#pragma unroll
    for (int j = 0; j < KPT; j++) {
        mn = min(mn, key[j]);
        mx = max(mx, key[j]);
    }
#pragma unroll
    for (int off = 32; off; off >>= 1) {
        mn = min(mn, (unsigned)__shfl_down((int)mn, off));
        mx = max(mx, (unsigned)__shfl_down((int)mx, off));
    }
    if (lane == 0) { hist[wid] = mn; hist[8 + wid] = mx; }
    if (tid == 0) st->done = 0;
    __syncthreads();
    if (tid == 0) {
        unsigned gmn = min(min(hist[0], hist[1]), min(hist[2], hist[3]));
        unsigned gmx = max(max(hist[8], hist[9]), max(hist[10], hist[11]));
        st->lo = gmn;
        st->hi = (unsigned long long)gmx + 1ull;
        st->krem = kwant;
    }
    __syncthreads();

    for (int iter = 0; iter < 6 && !st->done; iter++) {
        const unsigned lo = st->lo;
        const unsigned long long hi = st->hi;
        const int krem = st->krem;
        const unsigned long long span = hi - lo;
        int shift = 0;
        if (span > 256ull) {
            const int nb = 64 - __builtin_clzll(span - 1ull);
            shift = nb - 8;
        }
        hist[tid] = 0u;
        __syncthreads();
#pragma unroll
        for (int j = 0; j < KPT; j++) {
            const unsigned u = key[j];
            if (u >= lo && (unsigned long long)u < hi)
                atomicAdd(&hist[(u - lo) >> shift], 1u);
        }
        __syncthreads();
        const unsigned c = hist[tid];
        unsigned v = c;
#pragma unroll
        for (int off = 1; off < 64; off <<= 1) {
            const unsigned t = (unsigned)__shfl_up((int)v, off);
            if (lane >= off) v += t;
        }
        if (lane == 63) wtot[wid] = v;
        __syncthreads();
        unsigned pre = 0;
        for (int w = 0; w < 3; w++) pre += (w < wid) ? wtot[w] : 0u;
        const int incl = (int)(v + pre);
        const int excl = incl - (int)c;
        if (excl < krem && incl >= krem) {
            const unsigned long long binlo =
                (unsigned long long)lo + ((unsigned long long)tid << shift);
            if (shift == 0) {
                st->T = binlo;
                st->need = krem - excl;
                st->done = 1;
            } else if (incl == krem) {
                st->T = binlo + (1ull << shift);
                st->need = 0;
                st->done = 1;
            } else {
                st->lo = (unsigned)binlo;
                const unsigned long long nhi = binlo + (1ull << shift);
                st->hi = nhi < hi ? nhi : hi;
                st->krem = krem - excl;
            }
        }
        __syncthreads();
    }
}

__global__ __launch_bounds__(256) void topk_seg(
    const float* __restrict__ S, unsigned* __restrict__ K1key,
    int* __restrict__ K1idx)
{
    const int r = blockIdx.y, seg = blockIdx.x;
    const float* p = S + (size_t)r * NN + seg * TK_SEG;
    __shared__ unsigned hist[256];
    __shared__ unsigned wtot[4];
    __shared__ SelState st;
    __shared__ int cA, cB;
    const int tid = threadIdx.x;

    unsigned key[16];
#pragma unroll
    for (int j = 0; j < 16; j++) key[j] = fkey(p[tid + j * 256]);

    if (tid == 0) { cA = 0; cB = 0; }
    adaptive_select<16>(key, hist, wtot, &st, tid, NC);

    const unsigned long long T = st.T;
    const int need = st.need;
    const int cntLess = NC - need;
    const size_t obase = ((size_t)r * TK_SPLIT + seg) * NC;
#pragma unroll
    for (int j = 0; j < 16; j++) {
        const unsigned u = key[j];
        if ((unsigned long long)u < T) {
            const int pos = atomicAdd(&cA, 1);
            K1key[obase + pos] = u;
            K1idx[obase + pos] = seg * TK_SEG + tid + j * 256;
        } else if ((unsigned long long)u == T) {
            const int pos = atomicAdd(&cB, 1);
            if (pos < need) {
                K1key[obase + cntLess + pos] = u;
                K1idx[obase + cntLess + pos] = seg * TK_SEG + tid + j * 256;
            }
        }
    }
}

__global__ __launch_bounds__(256) void topk_merge(
    const unsigned* __restrict__ K1key, const int* __restrict__ K1idx,
    int* __restrict__ idx_out, float* __restrict__ val_out, int b0)
{
    const int r = blockIdx.x;
    const int b = b0 + r;
    __shared__ unsigned hist[256];
    __shared__ unsigned wtot[4];
    __shared__ SelState st;
    __shared__ int cA, cB;
    const int tid = threadIdx.x;
    const size_t ibase = (size_t)r * TK_CAND;

    unsigned key[6];
    int      kidx[6];
#pragma unroll
    for (int j = 0; j < 6; j++) {
        key[j]  = K1key[ibase + tid + j * 256];
        kidx[j] = K1idx[ibase + tid + j * 256];
    }

    if (tid == 0) { cA = 0; cB = 0; }
    adaptive_select<6>(key, hist, wtot, &st, tid, NC);

    const unsigned long long T = st.T;
    const int need = st.need;
    const int cntLess = NC - need;
#pragma unroll
    for (int j = 0; j < 6; j++) {
        const unsigned u = key[j];
        if ((unsigned long long)u < T) {
            const int pos = atomicAdd(&cA, 1);
            idx_out[b * NC + pos] = kidx[j];
            val_out[b * NC + pos] = inv_fkey(u);
        } else if ((unsigned long long)u == T) {
            const int pos = atomicAdd(&cB, 1);
            if (pos < need) {
                idx_out[b * NC + cntLess + pos] = kidx[j];
                val_out[b * NC + cntLess + pos] = inv_fkey(u);
            }
        }
    }
}

// ---------------------------------------------------------------------------
__global__ __launch_bounds__(128) void probs_kernel(
    const float* __restrict__ svals, float* __restrict__ probs)
{
    const int b = blockIdx.x;
    const int tid = threadIdx.x;
    __shared__ float red[128];
    const bool valid = tid < NC;
    float s = valid ? -svals[b * NC + tid] : -3.4e38f;
    red[tid] = s;
    __syncthreads();
#pragma unroll
    for (int off = 64; off; off >>= 1) {
        if (tid < off) red[tid] = fmaxf(red[tid], red[tid + off]);
        __syncthreads();
    }
    const float m = red[0];
    __syncthreads();
    float e = valid ? expf(s - m) : 0.f;
    red[tid] = e;
    __syncthreads();
#pragma unroll
    for (int off = 64; off; off >>= 1) {
        if (tid < off) red[tid] += red[tid + off];
        __syncthreads();
    }
    const float sum = red[0];
    if (valid) probs[b * NC + tid] = e / sum;
}

// ctx: xin given as planes (encoder-out x)
__global__ __launch_bounds__(256) void ctx_kernel(
    const float* __restrict__ VAL, const float* __restrict__ probs,
    const float* __restrict__ cand_y, const int* __restrict__ idx,
    const float* __restrict__ labW, const float* __restrict__ labb,
    const ushort* __restrict__ xinh, const ushort* __restrict__ xinl,
    float* __restrict__ xout, int b0)
{
    const int b_loc = blockIdx.x;
    const int b = b0 + b_loc;
    const int tid = threadIdx.x;
    __shared__ float pv[NC];
    __shared__ float red[256];
    float py_part = 0.f;
    if (tid < NC) {
        float p = probs[b * NC + tid];
        pv[tid] = p;
        py_part = p * cand_y[idx[b * NC + tid]];
    }
    red[tid] = py_part;
    __syncthreads();
#pragma unroll
    for (int off = 128; off; off >>= 1) {
        if (tid < off) red[tid] += red[tid + off];
        __syncthreads();
    }
    const float py = red[0];

    for (int d = tid; d < ND; d += 256) {
        const float* vp = VAL + (size_t)b_loc * NC * ND + d;
        float acc = 0.f;
#pragma unroll 8
        for (int c = 0; c < NC; c++) acc += pv[c] * vp[(size_t)c * ND];
        float ctx = acc + py * labW[d] + labb[d];
        const size_t o = (size_t)b * ND + d;
        xout[o] = bf2f(xinh[o]) + bf2f(xinl[o]) + ctx;
    }
}

__global__ __launch_bounds__(64) void head_kernel(
    const float* __restrict__ X, const float* __restrict__ hW,
    const float* __restrict__ hb, float* __restrict__ out)
{
    const int b = blockIdx.x;
    const int lane = threadIdx.x;
    const float* x = X + (size_t)b * ND;
    float acc = 0.f;
#pragma unroll
    for (int j = 0; j < 8; j++) {
        int d = lane + 64 * j;
        acc += x[d] * hW[d];
    }
#pragma unroll
    for (int off = 32; off; off >>= 1) acc += __shfl_down(acc, off);
    if (lane == 0) out[b] = acc + hb[0];
}

// ---------------------------------------------------------------------------
extern "C" void kernel_launch(void* const* d_in, const int* in_sizes, int n_in,
                              void* d_out, int out_size, void* d_ws, size_t ws_size,
                              hipStream_t stream)
{
    const float* x_num    = (const float*)d_in[0];
    const float* cand_num = (const float*)d_in[1];
    const float* cand_y   = (const float*)d_in[2];
    const float* lin_W    = (const float*)d_in[3];
    const float* lin_b    = (const float*)d_in[4];
    const float* e_W1     = (const float*)d_in[5];
    const float* e_b1     = (const float*)d_in[6];
    const float* e_W2     = (const float*)d_in[7];
    const float* e_b2     = (const float*)d_in[8];
    const float* mix_g    = (const float*)d_in[9];
    const float* mix_b    = (const float*)d_in[10];
    const float* K_W      = (const float*)d_in[11];
    const float* K_b      = (const float*)d_in[12];
    const float* lab_W    = (const float*)d_in[13];
    const float* lab_b    = (const float*)d_in[14];
    const float* T_W1     = (const float*)d_in[15];
    const float* T_b1     = (const float*)d_in[16];
    const float* T_W2     = (const float*)d_in[17];
    const float* p_ln_g   = (const float*)d_in[18];
    const float* p_ln_b   = (const float*)d_in[19];
    const float* p_W1     = (const float*)d_in[20];
    const float* p_b1     = (const float*)d_in[21];
    const float* p_W2     = (const float*)d_in[22];
    const float* p_b2     = (const float*)d_in[23];
    const float* h_ln_g   = (const float*)d_in[24];
    const float* h_ln_b   = (const float*)d_in[25];
    const float* h_W      = (const float*)d_in[26];
    const float* h_b      = (const float*)d_in[27];
    float* out = (float*)d_out;
    (void)in_sizes; (void)n_in; (void)out_size; (void)ws_size;

    // ---- workspace layout (~245 MB) ----
    size_t off = 0;
    auto ralloc = [&](size_t bytes) -> void* {
        void* p = (char*)d_ws + off;
        off += (bytes + 255) & ~(size_t)255;
        return p;
    };
    auto falloc = [&](size_t n) -> float*  { return (float*)ralloc(n * 4); };
    auto ualloc = [&](size_t n) -> ushort* { return (ushort*)ralloc(n * 2); };

    // bf16 plane weights [N][K]
    ushort* WP_lin_h = ualloc((size_t)ND * NF);
    ushort* WP_lin_l = ualloc((size_t)ND * NF);
    ushort* WP_e1_h  = ualloc((size_t)NDB * ND);
    ushort* WP_e1_l  = ualloc((size_t)NDB * ND);
    ushort* WP_e2_h  = ualloc((size_t)ND * NDB);
    ushort* WP_e2_l  = ualloc((size_t)ND * NDB);
    ushort* WP_kw_h  = ualloc((size_t)ND * ND);
    ushort* WP_kw_l  = ualloc((size_t)ND * ND);
    ushort* WP_t1_h  = ualloc((size_t)NDB * ND);
    ushort* WP_t1_l  = ualloc((size_t)NDB * ND);
    ushort* WP_t2_h  = ualloc((size_t)ND * NDB);
    ushort* WP_t2_l  = ualloc((size_t)ND * NDB);
    ushort* WP_p1_h  = ualloc((size_t)NDB * ND);
    ushort* WP_p1_l  = ualloc((size_t)NDB * ND);
    ushort* WP_p2_h  = ualloc((size_t)ND * NDB);
    ushort* WP_p2_l  = ualloc((size_t)ND * NDB);

    ushort* R_CKh = ualloc((size_t)NN * ND);
    ushort* R_CKl = ualloc((size_t)NN * ND);
    float*  R_sq  = falloc(NN);

    // x-path plane activations
    ushort* XNh = ualloc((size_t)NB * NF);
    ushort* XNl = ualloc((size_t)NB * NF);
    ushort* Hxh = ualloc((size_t)NB * ND);
    ushort* Hxl = ualloc((size_t)NB * ND);
    ushort* Txh = ualloc((size_t)NB * NDB);
    ushort* Txl = ualloc((size_t)NB * NDB);
    ushort* X2h = ualloc((size_t)NB * ND);
    ushort* X2l = ualloc((size_t)NB * ND);
    ushort* Gxh = ualloc((size_t)NB * ND);
    ushort* Gxl = ualloc((size_t)NB * ND);
    ushort* Lxh = ualloc((size_t)NB * ND);
    ushort* Lxl = ualloc((size_t)NB * ND);
    ushort* Tph = ualloc((size_t)NB * NDB);
    ushort* Tpl = ualloc((size_t)NB * NDB);
    ushort* R_kxh = ualloc((size_t)NB * ND);
    ushort* R_kxl = ualloc((size_t)NB * ND);

    int*    R_idx = (int*)ralloc((size_t)NB * NC * 4);
    float*  R_ssel= falloc((size_t)NB * NC);
    float*  R_prob= falloc((size_t)NB * NC);
    float*  R_xupd= falloc((size_t)NB * ND);
    float*  R_lnx = falloc((size_t)NB * ND);
    float*  R_x2  = falloc((size_t)NB * ND);
    float*  R_lnx2= falloc((size_t)NB * ND);
    unsigned* K1key = (unsigned*)ralloc((size_t)BB_C * TK_CAND * 4);
    int*      K1idx = (int*)ralloc((size_t)BB_C * TK_CAND * 4);
    char* SCR = (char*)ralloc((size_t)70 * 1024 * 1024);

    // ---- 0. weight prep (split-transpose to planes) ----
    auto sw = [&](const float* W, ushort* WTh, ushort* WTl, int K, int N) {
        split_wt_kernel<<<dim3((K * N + 255) / 256), dim3(256), 0, stream>>>(W, WTh, WTl, K, N);
    };
    sw(lin_W, WP_lin_h, WP_lin_l, NF, ND);
    sw(e_W1,  WP_e1_h,  WP_e1_l,  ND, NDB);
    sw(e_W2,  WP_e2_h,  WP_e2_l,  NDB, ND);
    sw(K_W,   WP_kw_h,  WP_kw_l,  ND, ND);
    sw(T_W1,  WP_t1_h,  WP_t1_l,  ND, NDB);
    sw(T_W2,  WP_t2_h,  WP_t2_l,  NDB, ND);
    sw(p_W1,  WP_p1_h,  WP_p1_l,  ND, NDB);
    sw(p_W2,  WP_p2_h,  WP_p2_l,  NDB, ND);

    auto gn64 = [&](const ushort* Ah, const ushort* Al, const ushort* Bh,
                    const ushort* Bl, const float* bias, const ushort* resh,
                    const ushort* resl, ushort* Ch, ushort* Cl,
                    int M, int Nn, int K, int relu) {
        gemm_ss_n64<<<dim3(Nn / 64, M / 128), dim3(256), 0, stream>>>(
            Ah, Al, Bh, Bl, bias, resh, resl, Ch, Cl, M, Nn, K, relu);
    };
    auto gsm = [&](const ushort* Ah, const ushort* Al, const ushort* Bh,
                   const ushort* Bl, const float* bias, const ushort* resh,
                   const ushort* resl, const float* resf, ushort* Ch,
                   ushort* Cl, float* outf, int M, int Nn, int K, int relu) {
        gemm_ss_small<<<dim3(Nn / 64, M / 64), dim3(256), 0, stream>>>(
            Ah, Al, Bh, Bl, bias, resh, resl, resf, Ch, Cl, outf, M, Nn, K, relu);
    };

    // ---- 1. candidate encode (chunked; full 3-MFMA, BK=64) ----
    {
        ushort* CNh = (ushort*)SCR;
        ushort* CNl = CNh + (size_t)CH_A * NF;
        ushort* Hh  = CNl + (size_t)CH_A * NF;
        ushort* Hl  = Hh  + (size_t)CH_A * ND;
        ushort* Th  = Hl  + (size_t)CH_A * ND;
        ushort* Tl  = Th  + (size_t)CH_A * NDB;
        ushort* H2h = Tl  + (size_t)CH_A * NDB;
        ushort* H2l = H2h + (size_t)CH_A * ND;
        ushort* Gh  = Th;   // overlay: T dead after e2
        ushort* Gl  = Tl;

        for (int n0 = 0; n0 < NN; n0 += CH_A) {
            split_pl_kernel<<<dim3((CH_A * NF + 255) / 256), dim3(256), 0, stream>>>(
                cand_num + (size_t)n0 * NF, CNh, CNl, CH_A * NF);
            gsm(CNh, CNl, WP_lin_h, WP_lin_l, lin_b, nullptr, nullptr, nullptr,
                Hh, Hl, nullptr, CH_A, ND, NF, 0);
            gn64(Hh, Hl, WP_e1_h, WP_e1_l, e_b1, nullptr, nullptr,
                 Th, Tl, CH_A, NDB, ND, 1);
            gsm(Th, Tl, WP_e2_h, WP_e2_l, e_b2, Hh, Hl, nullptr,
                H2h, H2l, nullptr, CH_A, ND, NDB, 0);
            ln_pl_kernel<<<dim3(CH_A / 4), dim3(256), 0, stream>>>(
                H2h, H2l, mix_g, mix_b, Gh, Gl);
            gsm(Gh, Gl, WP_kw_h, WP_kw_l, K_b, nullptr, nullptr, nullptr,
                R_CKh + (size_t)n0 * ND, R_CKl + (size_t)n0 * ND, nullptr,
                CH_A, ND, ND, 0);
            sqnorm_pl_kernel<<<dim3(CH_A / 4), dim3(256), 0, stream>>>(
                R_CKh + (size_t)n0 * ND, R_CKl + (size_t)n0 * ND, R_sq + n0);
        }
    }

    // ---- 2. x encode (full 3-MFMA) ----
    split_pl_kernel<<<dim3((NB * NF + 255) / 256), dim3(256), 0, stream>>>(
        x_num, XNh, XNl, NB * NF);
    gsm(XNh, XNl, WP_lin_h, WP_lin_l, lin_b, nullptr, nullptr, nullptr,
        Hxh, Hxl, nullptr, NB, ND, NF, 0);
    gsm(Hxh, Hxl, WP_e1_h, WP_e1_l, e_b1, nullptr, nullptr, nullptr,
        Txh, Txl, nullptr, NB, NDB, ND, 1);
    gsm(Txh, Txl, WP_e2_h, WP_e2_l, e_b2, Hxh, Hxl, nullptr,
        X2h, X2l, nullptr, NB, ND, NDB, 0);
    ln_pl_kernel<<<dim3(NB / 4), dim3(256), 0, stream>>>(
        X2h, X2l, mix_g, mix_b, Gxh, Gxl);
    gsm(Gxh, Gxl, WP_kw_h, WP_kw_l, K_b, nullptr, nullptr, nullptr,
        R_kxh, R_kxl, nullptr, NB, ND, ND, 0);

    // ---- 3. scores (3-MFMA) + two-stage top-96 + softmax ----
    for (int b0 = 0; b0 < NB; b0 += BB_C) {
        float* S = (float*)SCR;
        gemm_ss<<<dim3(NN / 128, BB_C / 128), dim3(256), 0, stream>>>(
            R_kxh + (size_t)b0 * ND, R_kxl + (size_t)b0 * ND, R_CKh, R_CKl,
            R_sq, S, BB_C, NN, ND);
        topk_seg<<<dim3(TK_SPLIT, BB_C), dim3(256), 0, stream>>>(S, K1key, K1idx);
        topk_merge<<<dim3(BB_C), dim3(256), 0, stream>>>(K1key, K1idx,
                                                         R_idx, R_ssel, b0);
    }
    probs_kernel<<<dim3(NB), dim3(128), 0, stream>>>(R_ssel, R_prob);

    // ---- 4. values path (plain bf16 MFMA, diff fused) ----
    for (int b0 = 0; b0 < NB; b0 += BB_D) {
        ushort* TT = (ushort*)SCR;                                  // [M,1024] bf16
        float* VAL = (float*)(SCR + (size_t)BB_D * NC * NDB * 2);   // f32 after TT
        const int M = BB_D * NC;   // 12288
        gemm_diff_bf16<<<dim3(NDB / 128, M / 128), dim3(256), 0, stream>>>(
            R_kxh + (size_t)b0 * ND, R_kxl + (size_t)b0 * ND,
            R_CKh, R_CKl, R_idx + b0 * NC,
            WP_t1_h, T_b1, TT, M, NDB, ND);
        gemm_bf16_n64<<<dim3(ND / 64, M / 128), dim3(256), 0, stream>>>(
            TT, WP_t2_h, VAL, M, ND, NDB);
        ctx_kernel<<<dim3(BB_D), dim3(256), 0, stream>>>(
            VAL, R_prob, cand_y, R_idx, lab_W, lab_b, X2h, X2l, R_xupd, b0);
    }

    // ---- 5. predictor block + head (full 3-MFMA) ----
    ln_kernel<<<dim3(NB / 4), dim3(256), 0, stream>>>(R_xupd, p_ln_g, p_ln_b, R_lnx, 0);
    split_pl_kernel<<<dim3((NB * ND + 255) / 256), dim3(256), 0, stream>>>(
        R_lnx, Lxh, Lxl, NB * ND);
    gsm(Lxh, Lxl, WP_p1_h, WP_p1_l, p_b1, nullptr, nullptr, nullptr,
        Tph, Tpl, nullptr, NB, NDB, ND, 1);
    gsm(Tph, Tpl, WP_p2_h, WP_p2_l, p_b2, nullptr, nullptr, R_xupd,
        nullptr, nullptr, R_x2, NB, ND, NDB, 0);
    ln_kernel<<<dim3(NB / 4), dim3(256), 0, stream>>>(R_x2, h_ln_g, h_ln_b, R_lnx2, 1);
    head_kernel<<<dim3(NB), dim3(64), 0, stream>>>(R_lnx2, h_W, h_b, out);
}